// Round 7
// baseline (364.935 us; speedup 1.0000x reference)
//
#include <hip/hip_runtime.h>
#include <hip/hip_bf16.h>

typedef __hip_bfloat16 bf16;
typedef __attribute__((ext_vector_type(8))) __bf16 bf16x8;
typedef __attribute__((ext_vector_type(4))) __bf16 bf16x4;
typedef __attribute__((ext_vector_type(4))) float f32x4;

constexpr int S_LEN = 2048;
constexpr int HID   = 2560;
constexpr int NH    = 40;
constexpr int QL    = 768;
constexpr int KVL   = 256;
constexpr int RD    = 32;
constexpr int ND    = 64;
constexpr int VD    = 64;
constexpr int QHD   = 96;                 // NOPE_D + ROPE_D
constexpr int QB_N  = NH * QHD;           // 3840
constexpr int KVB_N = NH * (ND + VD);     // 5120
constexpr int CKV_N = KVL + RD;           // 288
constexpr int AB_N  = QL + CKV_N;         // 1056 (fused qa|kva output cols)

#define MFMA16(a, b, c) __builtin_amdgcn_mfma_f32_16x16x32_bf16((a), (b), (c), 0, 0, 0)

// position_ids may arrive as int32 or int64; values are 0..2047 so sniff layout.
__device__ __forceinline__ int get_pos(const int* pos, int s) {
  bool is64 = (pos[1] == 0 && pos[2] == 1);
  return is64 ? pos[2 * s] : pos[s];
}

// ---------------- prep ----------------

__global__ void cast_f32_bf16(const float* __restrict__ src, bf16* __restrict__ dst, int n4) {
  int i = blockIdx.x * blockDim.x + threadIdx.x;
  if (i >= n4) return;
  float4 v = reinterpret_cast<const float4*>(src)[i];
  struct { bf16 a, b, c, d; } pk;
  pk.a = __float2bfloat16(v.x); pk.b = __float2bfloat16(v.y);
  pk.c = __float2bfloat16(v.z); pk.d = __float2bfloat16(v.w);
  reinterpret_cast<uint2*>(dst)[i] = *reinterpret_cast<uint2*>(&pk);
}

// src [K][N] f32 -> dst [N][K] bf16  (B^T layout for the GEMMs)
__global__ void transpose_cast(const float* __restrict__ src, bf16* __restrict__ dst, int K, int N) {
  __shared__ float tile[32][33];
  int nb = blockIdx.x * 32, kb = blockIdx.y * 32;
  int x = threadIdx.x, y = threadIdx.y; // (32,8)
#pragma unroll
  for (int j = 0; j < 4; ++j) {
    int k = kb + y + j * 8, n = nb + x;
    tile[y + j * 8][x] = (k < K && n < N) ? src[(size_t)k * N + n] : 0.f;
  }
  __syncthreads();
#pragma unroll
  for (int j = 0; j < 4; ++j) {
    int n = nb + y + j * 8, k = kb + x;
    if (n < N && k < K) dst[(size_t)n * K + k] = __float2bfloat16(tile[x][y + j * 8]);
  }
}

// ---------------- GEMMs ----------------

// Generic GEMM: C[M][N] = A[M][K] * B^T[N][K], f32 or bf16 out
template<bool OBF16, bool NEDGE>
__global__ __launch_bounds__(256) void gemm_bt(const bf16* __restrict__ A,
                                               const bf16* __restrict__ B,
                                               void* __restrict__ Cv,
                                               int M, int N, int K) {
  constexpr int BM = 128, BN = 128, BK = 64;
  __shared__ __bf16 ldsA[BM * BK];
  __shared__ __bf16 ldsB[BN * BK];
  const int t = threadIdx.x;
  const int l = t & 63, w = t >> 6;
  const int lr = l & 15, lk = l >> 4;
  const int wr = w >> 1, wc = w & 1;
  const int rowbase = blockIdx.y * BM;
  const int colbase = blockIdx.x * BN;

  f32x4 acc[4][4];
#pragma unroll
  for (int m = 0; m < 4; ++m)
#pragma unroll
    for (int n = 0; n < 4; ++n) acc[m][n] = f32x4{0.f, 0.f, 0.f, 0.f};

  const int kiters = K / BK;
  for (int kt = 0; kt < kiters; ++kt) {
    const int kb = kt * BK;
#pragma unroll
    for (int it = 0; it < 4; ++it) {
      const int r  = it * 32 + w * 8 + (l >> 3);
      const int c8 = ((l & 7) * 8) ^ ((r & 7) << 3);
      const bf16* ga = A + (size_t)(rowbase + r) * K + kb + c8;
      __builtin_amdgcn_global_load_lds((const __attribute__((address_space(1))) void*)ga,
          (__attribute__((address_space(3))) void*)(ldsA + it * 2048 + w * 512), 16, 0, 0);
      int nrow = colbase + r;
      if (NEDGE) nrow = (nrow < N) ? nrow : (N - 1);
      const bf16* gb = B + (size_t)nrow * K + kb + c8;
      __builtin_amdgcn_global_load_lds((const __attribute__((address_space(1))) void*)gb,
          (__attribute__((address_space(3))) void*)(ldsB + it * 2048 + w * 512), 16, 0, 0);
    }
    __syncthreads();
#pragma unroll
    for (int kk = 0; kk < 2; ++kk) {
      bf16x8 af[4], bfr[4];
#pragma unroll
      for (int m = 0; m < 4; ++m) {
        const int row = wr * 64 + m * 16 + lr;
        const int ce  = (kk * 32 + lk * 8) ^ ((row & 7) << 3);
        af[m] = *(const bf16x8*)(ldsA + row * BK + ce);
      }
#pragma unroll
      for (int n = 0; n < 4; ++n) {
        const int row = wc * 64 + n * 16 + lr;
        const int ce  = (kk * 32 + lk * 8) ^ ((row & 7) << 3);
        bfr[n] = *(const bf16x8*)(ldsB + row * BK + ce);
      }
#pragma unroll
      for (int m = 0; m < 4; ++m)
#pragma unroll
        for (int n = 0; n < 4; ++n)
          acc[m][n] = MFMA16(af[m], bfr[n], acc[m][n]);
    }
    __syncthreads();
  }

#pragma unroll
  for (int m = 0; m < 4; ++m)
#pragma unroll
    for (int n = 0; n < 4; ++n) {
      const int col = colbase + wc * 64 + n * 16 + lr;
      if (NEDGE && col >= N) continue;
#pragma unroll
      for (int i = 0; i < 4; ++i) {
        const int row = rowbase + wr * 64 + m * 16 + lk * 4 + i;
        if (OBF16) ((bf16*)Cv)[(size_t)row * N + col] = __float2bfloat16(acc[m][n][i]);
        else       ((float*)Cv)[(size_t)row * N + col] = acc[m][n][i];
      }
    }
}

// Fused qa|kva GEMM: C[2048][1056] = hid_bf * wabT^T, BN=64 tiles.
__global__ __launch_bounds__(256) void gemm_qakva(const bf16* __restrict__ A,
                                                  const bf16* __restrict__ B,
                                                  float* __restrict__ q_out,
                                                  float* __restrict__ ckv_out) {
  constexpr int BM = 128, BK = 64, K = HID, N = AB_N;
  __shared__ __bf16 ldsA[BM * BK];
  __shared__ __bf16 ldsB[64 * BK];
  const int t = threadIdx.x;
  const int l = t & 63, w = t >> 6;
  const int lr = l & 15, lk = l >> 4;
  const int rowbase = blockIdx.y * BM;
  const int colbase = blockIdx.x * 64;

  f32x4 acc[2][4];
#pragma unroll
  for (int m = 0; m < 2; ++m)
#pragma unroll
    for (int n = 0; n < 4; ++n) acc[m][n] = f32x4{0.f, 0.f, 0.f, 0.f};

  for (int kt = 0; kt < K / BK; ++kt) {
    const int kb = kt * BK;
#pragma unroll
    for (int it = 0; it < 4; ++it) {
      const int r  = it * 32 + w * 8 + (l >> 3);
      const int c8 = ((l & 7) * 8) ^ ((r & 7) << 3);
      const bf16* ga = A + (size_t)(rowbase + r) * K + kb + c8;
      __builtin_amdgcn_global_load_lds((const __attribute__((address_space(1))) void*)ga,
          (__attribute__((address_space(3))) void*)(ldsA + it * 2048 + w * 512), 16, 0, 0);
      if (it < 2) {
        int nrow = colbase + r;
        nrow = (nrow < N) ? nrow : (N - 1);
        const bf16* gb = B + (size_t)nrow * K + kb + c8;
        __builtin_amdgcn_global_load_lds((const __attribute__((address_space(1))) void*)gb,
            (__attribute__((address_space(3))) void*)(ldsB + it * 2048 + w * 512), 16, 0, 0);
      }
    }
    __syncthreads();
#pragma unroll
    for (int kk = 0; kk < 2; ++kk) {
      bf16x8 af[2], bfr[4];
#pragma unroll
      for (int m = 0; m < 2; ++m) {
        const int row = w * 32 + m * 16 + lr;
        const int ce  = (kk * 32 + lk * 8) ^ ((row & 7) << 3);
        af[m] = *(const bf16x8*)(ldsA + row * BK + ce);
      }
#pragma unroll
      for (int n = 0; n < 4; ++n) {
        const int row = n * 16 + lr;
        const int ce  = (kk * 32 + lk * 8) ^ ((row & 7) << 3);
        bfr[n] = *(const bf16x8*)(ldsB + row * BK + ce);
      }
#pragma unroll
      for (int m = 0; m < 2; ++m)
#pragma unroll
        for (int n = 0; n < 4; ++n)
          acc[m][n] = MFMA16(af[m], bfr[n], acc[m][n]);
    }
    __syncthreads();
  }

#pragma unroll
  for (int m = 0; m < 2; ++m)
#pragma unroll
    for (int n = 0; n < 4; ++n) {
      const int col = colbase + n * 16 + lr;
#pragma unroll
      for (int i = 0; i < 4; ++i) {
        const int row = rowbase + w * 32 + m * 16 + lk * 4 + i;
        if (col < QL)       q_out[(size_t)row * QL + col] = acc[m][n][i];
        else if (col < N)   ckv_out[(size_t)row * CKV_N + (col - QL)] = acc[m][n][i];
      }
    }
}

// qb GEMM with fused RoPE + scale, writing qfull [NH][S][96] directly.
__global__ __launch_bounds__(256) void gemm_qb_rope(const bf16* __restrict__ A,
                                                    const bf16* __restrict__ B,
                                                    const float* __restrict__ ropc,
                                                    const float* __restrict__ rops,
                                                    bf16* __restrict__ qfull) {
  constexpr int BM = 128, BN = 128, BK = 64, K = QL, N = QB_N;
  __shared__ __bf16 ldsA[BM * BK];
  __shared__ __bf16 ldsB[BN * BK];
  const int t = threadIdx.x;
  const int l = t & 63, w = t >> 6;
  const int lr = l & 15, lk = l >> 4;
  const int wr = w >> 1, wc = w & 1;
  const int rowbase = blockIdx.y * BM;
  const int colbase = blockIdx.x * BN;
  const float scale = 0.14724444f; // 96^-0.5 * log2(e)

  f32x4 acc[4][4];
#pragma unroll
  for (int m = 0; m < 4; ++m)
#pragma unroll
    for (int n = 0; n < 4; ++n) acc[m][n] = f32x4{0.f, 0.f, 0.f, 0.f};

  for (int kt = 0; kt < K / BK; ++kt) {
    const int kb = kt * BK;
#pragma unroll
    for (int it = 0; it < 4; ++it) {
      const int r  = it * 32 + w * 8 + (l >> 3);
      const int c8 = ((l & 7) * 8) ^ ((r & 7) << 3);
      const bf16* ga = A + (size_t)(rowbase + r) * K + kb + c8;
      __builtin_amdgcn_global_load_lds((const __attribute__((address_space(1))) void*)ga,
          (__attribute__((address_space(3))) void*)(ldsA + it * 2048 + w * 512), 16, 0, 0);
      const bf16* gb = B + (size_t)(colbase + r) * K + kb + c8;
      __builtin_amdgcn_global_load_lds((const __attribute__((address_space(1))) void*)gb,
          (__attribute__((address_space(3))) void*)(ldsB + it * 2048 + w * 512), 16, 0, 0);
    }
    __syncthreads();
#pragma unroll
    for (int kk = 0; kk < 2; ++kk) {
      bf16x8 af[4], bfr[4];
#pragma unroll
      for (int m = 0; m < 4; ++m) {
        const int row = wr * 64 + m * 16 + lr;
        const int ce  = (kk * 32 + lk * 8) ^ ((row & 7) << 3);
        af[m] = *(const bf16x8*)(ldsA + row * BK + ce);
      }
#pragma unroll
      for (int n = 0; n < 4; ++n) {
        const int row = wc * 64 + n * 16 + lr;
        const int ce  = (kk * 32 + lk * 8) ^ ((row & 7) << 3);
        bfr[n] = *(const bf16x8*)(ldsB + row * BK + ce);
      }
#pragma unroll
      for (int m = 0; m < 4; ++m)
#pragma unroll
        for (int n = 0; n < 4; ++n)
          acc[m][n] = MFMA16(af[m], bfr[n], acc[m][n]);
    }
    __syncthreads();
  }

#pragma unroll
  for (int m = 0; m < 4; ++m) {
    const int rowtop = rowbase + wr * 64 + m * 16 + lk * 4;
#pragma unroll
    for (int n = 0; n < 4; ++n) {
      const int c0 = colbase + wc * 64 + n * 16; // frag base col
      const int h  = c0 / 96;
      const int d0 = c0 - h * 96;
      const size_t qb_ = ((size_t)h * S_LEN + rowtop) * QHD + d0 + lr;
      if (d0 < ND) {
#pragma unroll
        for (int i = 0; i < 4; ++i)
          qfull[qb_ + (size_t)i * QHD] = __float2bfloat16(acc[m][n][i] * scale);
      } else if (d0 == ND) { // rope-lo: out = x0*c - x1*s, x1 = acc[m][n+1]
#pragma unroll
        for (int i = 0; i < 4; ++i) {
          const float c = ropc[(rowtop + i) * 16 + lr];
          const float s = rops[(rowtop + i) * 16 + lr];
          const float x0 = acc[m][n][i], x1 = acc[m][n + 1][i];
          qfull[qb_ + (size_t)i * QHD] = __float2bfloat16((x0 * c - x1 * s) * scale);
        }
      } else { // d0 == 80, rope-hi: out = x1*c + x0*s, x0 = acc[m][n-1]
#pragma unroll
        for (int i = 0; i < 4; ++i) {
          const float c = ropc[(rowtop + i) * 16 + lr];
          const float s = rops[(rowtop + i) * 16 + lr];
          const float x1 = acc[m][n][i], x0 = acc[m][n - 1][i];
          qfull[qb_ + (size_t)i * QHD] = __float2bfloat16((x1 * c + x0 * s) * scale);
        }
      }
    }
  }
}

// kvb GEMM writing knope [NH][S][64] and vt [NH][64][S] directly.
__global__ __launch_bounds__(256) void gemm_kvb_split(const bf16* __restrict__ A,
                                                      const bf16* __restrict__ B,
                                                      bf16* __restrict__ knope,
                                                      bf16* __restrict__ vt) {
  constexpr int BM = 128, BN = 128, BK = 64, K = KVL;
  __shared__ __bf16 ldsA[BM * BK];
  __shared__ __bf16 ldsB[BN * BK];
  const int t = threadIdx.x;
  const int l = t & 63, w = t >> 6;
  const int lr = l & 15, lk = l >> 4;
  const int wr = w >> 1, wc = w & 1;
  const int rowbase = blockIdx.y * BM;
  const int h = blockIdx.x; // head == col tile
  const int colbase = h * BN;

  f32x4 acc[4][4];
#pragma unroll
  for (int m = 0; m < 4; ++m)
#pragma unroll
    for (int n = 0; n < 4; ++n) acc[m][n] = f32x4{0.f, 0.f, 0.f, 0.f};

  for (int kt = 0; kt < K / BK; ++kt) {
    const int kb = kt * BK;
#pragma unroll
    for (int it = 0; it < 4; ++it) {
      const int r  = it * 32 + w * 8 + (l >> 3);
      const int c8 = ((l & 7) * 8) ^ ((r & 7) << 3);
      const bf16* ga = A + (size_t)(rowbase + r) * K + kb + c8;
      __builtin_amdgcn_global_load_lds((const __attribute__((address_space(1))) void*)ga,
          (__attribute__((address_space(3))) void*)(ldsA + it * 2048 + w * 512), 16, 0, 0);
      const bf16* gb = B + (size_t)(colbase + r) * K + kb + c8;
      __builtin_amdgcn_global_load_lds((const __attribute__((address_space(1))) void*)gb,
          (__attribute__((address_space(3))) void*)(ldsB + it * 2048 + w * 512), 16, 0, 0);
    }
    __syncthreads();
#pragma unroll
    for (int kk = 0; kk < 2; ++kk) {
      bf16x8 af[4], bfr[4];
#pragma unroll
      for (int m = 0; m < 4; ++m) {
        const int row = wr * 64 + m * 16 + lr;
        const int ce  = (kk * 32 + lk * 8) ^ ((row & 7) << 3);
        af[m] = *(const bf16x8*)(ldsA + row * BK + ce);
      }
#pragma unroll
      for (int n = 0; n < 4; ++n) {
        const int row = wc * 64 + n * 16 + lr;
        const int ce  = (kk * 32 + lk * 8) ^ ((row & 7) << 3);
        bfr[n] = *(const bf16x8*)(ldsB + row * BK + ce);
      }
#pragma unroll
      for (int m = 0; m < 4; ++m)
#pragma unroll
        for (int n = 0; n < 4; ++n)
          acc[m][n] = MFMA16(af[m], bfr[n], acc[m][n]);
    }
    __syncthreads();
  }

#pragma unroll
  for (int m = 0; m < 4; ++m) {
    const int rowtop = rowbase + wr * 64 + m * 16 + lk * 4;
    if (wc == 0) { // k_nope -> knope[h][s][64]
#pragma unroll
      for (int n = 0; n < 4; ++n) {
        const int d = n * 16 + lr;
#pragma unroll
        for (int i = 0; i < 4; ++i)
          knope[((size_t)h * S_LEN + rowtop + i) * ND + d] = __float2bfloat16(acc[m][n][i]);
      }
    } else {        // V -> vt[h][64][S] (8B transposed stores, L2 merges)
#pragma unroll
      for (int n = 0; n < 4; ++n) {
        const int d = n * 16 + lr;
        bf16x4 pk;
#pragma unroll
        for (int i = 0; i < 4; ++i) pk[i] = (__bf16)acc[m][n][i];
        *(bf16x4*)(vt + ((size_t)h * VD + d) * S_LEN + rowtop) = pk;
      }
    }
  }
}

// ---------------- norms / prep ----------------

__global__ void rmsnorm_rows(const float* __restrict__ in, const float* __restrict__ w,
                             bf16* __restrict__ out, int C) {
  const int r = blockIdx.x;
  const float* row = in + (size_t)r * C;
  float ss = 0.f;
  for (int c = threadIdx.x; c < C; c += 256) { float v = row[c]; ss += v * v; }
#pragma unroll
  for (int d = 32; d > 0; d >>= 1) ss += __shfl_xor(ss, d);
  __shared__ float red[4];
  if ((threadIdx.x & 63) == 0) red[threadIdx.x >> 6] = ss;
  __syncthreads();
  const float tot = red[0] + red[1] + red[2] + red[3];
  const float rs = rsqrtf(tot / (float)C + 1e-6f);
  for (int c = threadIdx.x; c < C; c += 256)
    out[(size_t)r * C + c] = __float2bfloat16(row[c] * rs * w[c]);
}

// per row: rmsnorm(ckv[0:256]) -> bf16 ; rope(k_pe) -> bf16 ; rope tables
__global__ void kv_prep(const float* __restrict__ ckv, const float* __restrict__ w,
                        const int* __restrict__ pos, bf16* __restrict__ ckv_bf,
                        bf16* __restrict__ kpe, float* __restrict__ ropc,
                        float* __restrict__ rops) {
  const int s = blockIdx.x, t = threadIdx.x; // 64 threads
  const float* row = ckv + (size_t)s * CKV_N;
  float v[4]; float ss = 0.f;
#pragma unroll
  for (int j = 0; j < 4; ++j) { v[j] = row[t + 64 * j]; ss += v[j] * v[j]; }
#pragma unroll
  for (int d = 32; d > 0; d >>= 1) ss += __shfl_xor(ss, d);
  const float rs = rsqrtf(ss / (float)KVL + 1e-6f);
#pragma unroll
  for (int j = 0; j < 4; ++j)
    ckv_bf[(size_t)s * KVL + t + 64 * j] = __float2bfloat16(v[j] * rs * w[t + 64 * j]);
  if (t < 16) {
    const float x0 = row[KVL + t], x1 = row[KVL + 16 + t];
    const float p = (float)get_pos(pos, s);
    const float invf = exp2f(-(float)t * (13.2877124f / 16.f)); // 10000^(-t/16)
    const float ang = p * invf, c = cosf(ang), sn = sinf(ang);
    ropc[s * 16 + t] = c;
    rops[s * 16 + t] = sn;
    kpe[(size_t)s * RD + t]      = __float2bfloat16(x0 * c - x1 * sn);
    kpe[(size_t)s * RD + 16 + t] = __float2bfloat16(x1 * c + x0 * sn);
  }
}

// ---------------- causal flash attention ----------------
// UNIFORM-WORK waves: each wave handles the 16-row q-tile PAIR {127-p, p}
// sequentially -> every wave does ~33 k-tiles (makespan has no tail).
// Swapped QK^T (st = mfma(K,Q) -> S^T: q = lane&15 is lane-local; row
// reduce = 15 fmax + 2 shfl), log2-domain softmax, defer-rescale,
// XOR-swizzled per-wave P tile. K split: knope[h][s][64] + shared kpe[s][32].
// Block = 4 waves (256 thr), grid (NH, 16) = 640 blocks / 2560 uniform waves.
__global__ __launch_bounds__(256) void attn_kernel(const bf16* __restrict__ qfull,
                                                   const bf16* __restrict__ knope,
                                                   const bf16* __restrict__ kpe,
                                                   const bf16* __restrict__ vt,
                                                   bf16* __restrict__ ctx) {
  const int h = blockIdx.x;
  const int w = threadIdx.x >> 6, l = threadIdx.x & 63;
  const int p = blockIdx.y * 4 + w; // pair index 0..63
  const int lr = l & 15, lk = l >> 4;
  const bf16* Q  = qfull + (size_t)h * S_LEN * QHD;
  const bf16* Kn = knope + (size_t)h * S_LEN * ND;
  const bf16* V  = vt + (size_t)h * VD * S_LEN;
  __shared__ __bf16 plds[4][16][64]; // per-wave P tile, XOR-swizzled

#pragma unroll
  for (int half = 0; half < 2; ++half) {
    const int j  = half ? p : (127 - p); // heavy tile first
    const int qw = j * 16;
    const int lastkb = (qw / 64) * 64;

    bf16x8 qf[3];
#pragma unroll
    for (int ks = 0; ks < 3; ++ks)
      qf[ks] = *(const bf16x8*)(Q + (size_t)(qw + lr) * QHD + ks * 32 + lk * 8);

    f32x4 o[4];
#pragma unroll
    for (int dt = 0; dt < 4; ++dt) o[dt] = f32x4{0.f, 0.f, 0.f, 0.f};
    float mrow = -1e30f, lrow = 0.f;

    // preload K tile 0
    bf16x8 kf[4][3];
#pragma unroll
    for (int sub = 0; sub < 4; ++sub) {
#pragma unroll
      for (int ks = 0; ks < 2; ++ks)
        kf[sub][ks] = *(const bf16x8*)(Kn + (size_t)(sub * 16 + lr) * ND + ks * 32 + lk * 8);
      kf[sub][2] = *(const bf16x8*)(kpe + (size_t)(sub * 16 + lr) * RD + lk * 8);
    }

    for (int kb = 0;; kb += 64) {
      // st[sub][i] = S[q = qw+lr][k = kb+sub*16+lk*4+i] (log2 domain)
      f32x4 st[4];
#pragma unroll
      for (int sub = 0; sub < 4; ++sub) st[sub] = f32x4{0.f, 0.f, 0.f, 0.f};
#pragma unroll
      for (int sub = 0; sub < 4; ++sub)
#pragma unroll
        for (int ks = 0; ks < 3; ++ks)
          st[sub] = MFMA16(kf[sub][ks], qf[ks], st[sub]);

      // prefetch next K tile (hidden under softmax+PV)
      const int nkb = kb + 64;
      if (nkb <= lastkb) {
#pragma unroll
        for (int sub = 0; sub < 4; ++sub) {
#pragma unroll
          for (int ks = 0; ks < 2; ++ks)
            kf[sub][ks] = *(const bf16x8*)(Kn + (size_t)(nkb + sub * 16 + lr) * ND + ks * 32 + lk * 8);
          kf[sub][2] = *(const bf16x8*)(kpe + (size_t)(nkb + sub * 16 + lr) * RD + lk * 8);
        }
      }

      if (kb == lastkb) { // causal mask, only possible on the last tile
        const int q = qw + lr;
#pragma unroll
        for (int sub = 0; sub < 4; ++sub)
#pragma unroll
          for (int i = 0; i < 4; ++i)
            if (kb + sub * 16 + lk * 4 + i > q) st[sub][i] = -1e30f;
      }

      float m0 = -1e30f;
#pragma unroll
      for (int sub = 0; sub < 4; ++sub)
#pragma unroll
        for (int i = 0; i < 4; ++i) m0 = fmaxf(m0, st[sub][i]);
      m0 = fmaxf(m0, __shfl_xor(m0, 16));
      m0 = fmaxf(m0, __shfl_xor(m0, 32));

      const bool noresc = __all(m0 <= mrow + 8.f);
      const float mnew = noresc ? mrow : fmaxf(mrow, m0);
      float ts = 0.f;
#pragma unroll
      for (int sub = 0; sub < 4; ++sub) {
        bf16x4 pk;
#pragma unroll
        for (int i = 0; i < 4; ++i) {
          const float pv = exp2f(st[sub][i] - mnew);
          ts += pv;
          pk[i] = (__bf16)pv;
        }
        const int swc = (sub * 16 + lk * 4) ^ ((lr & 7) << 3);
        *(bf16x4*)(&plds[w][lr][swc]) = pk;
      }
      ts += __shfl_xor(ts, 16);
      ts += __shfl_xor(ts, 32);
      if (noresc) {
        lrow += ts;
      } else {
        const float fac = exp2f(mrow - mnew);
        lrow = lrow * fac + ts;
        mrow = mnew;
#pragma unroll
        for (int i = 0; i < 4; ++i) {
          const float fr = __shfl(fac, lk * 4 + i);
#pragma unroll
          for (int dt = 0; dt < 4; ++dt) o[dt][i] *= fr;
        }
      }

      // PV: A = P from LDS (swizzled read), B = V^T rows (contiguous in s)
#pragma unroll
      for (int h2 = 0; h2 < 2; ++h2) {
        const int swc = (h2 * 32 + lk * 8) ^ ((lr & 7) << 3);
        bf16x8 pa = *(const bf16x8*)(&plds[w][lr][swc]);
#pragma unroll
        for (int dt = 0; dt < 4; ++dt) {
          bf16x8 vf = *(const bf16x8*)(V + (size_t)(dt * 16 + lr) * S_LEN + kb + h2 * 32 + lk * 8);
          o[dt] = MFMA16(pa, vf, o[dt]);
        }
      }
      if (kb == lastkb) break;
    }

    const float linv = 1.0f / lrow;
#pragma unroll
    for (int i = 0; i < 4; ++i) {
      const float inv = __shfl(linv, lk * 4 + i);
#pragma unroll
      for (int dt = 0; dt < 4; ++dt) {
        const int row = qw + lk * 4 + i;
        const int col = h * VD + dt * 16 + lr;
        ctx[(size_t)row * HID + col] = __float2bfloat16(o[dt][i] * inv);
      }
    }
  }
}

// ---------------- launch ----------------

extern "C" void kernel_launch(void* const* d_in, const int* in_sizes, int n_in,
                              void* d_out, int out_size, void* d_ws, size_t ws_size,
                              hipStream_t stream) {
  const float* hidden = (const float*)d_in[0];
  const int*   pos    = (const int*)d_in[1];
  const float* w_qa   = (const float*)d_in[2];
  const float* q_ln   = (const float*)d_in[3];
  const float* w_qb   = (const float*)d_in[4];
  const float* w_kva  = (const float*)d_in[5];
  const float* kv_ln  = (const float*)d_in[6];
  const float* w_kvb  = (const float*)d_in[7];
  const float* w_o    = (const float*)d_in[8];
  float* out = (float*)d_out;
  char* ws = (char*)d_ws;
  (void)in_sizes; (void)n_in; (void)out_size; (void)ws_size;

  size_t off = 0;
  auto take = [&](size_t bytes) -> char* {
    char* p = ws + off;
    off = (off + bytes + 255) & ~(size_t)255;
    return p;
  };
  bf16*  hid_bf = (bf16*)take((size_t)S_LEN * HID * 2);
  bf16*  wabT   = (bf16*)take((size_t)AB_N * HID * 2);   // wqaT | wkvaT
  bf16*  wqbT   = (bf16*)take((size_t)QB_N * QL * 2);
  bf16*  wkvbT  = (bf16*)take((size_t)KVB_N * KVL * 2);
  bf16*  woT    = (bf16*)take((size_t)HID * HID * 2);
  float* qlora  = (float*)take((size_t)S_LEN * QL * 4);
  bf16*  qa_bf  = (bf16*)take((size_t)S_LEN * QL * 2);
  bf16*  qfull  = (bf16*)take((size_t)NH * S_LEN * QHD * 2);
  float* ckv    = (float*)take((size_t)S_LEN * CKV_N * 4);
  bf16*  ckv_bf = (bf16*)take((size_t)S_LEN * KVL * 2);
  bf16*  kpe    = (bf16*)take((size_t)S_LEN * RD * 2);
  float* ropc   = (float*)take((size_t)S_LEN * 16 * 4);
  float* rops   = (float*)take((size_t)S_LEN * 16 * 4);
  bf16*  knope  = (bf16*)take((size_t)NH * S_LEN * ND * 2);
  bf16*  vt     = (bf16*)take((size_t)NH * VD * S_LEN * 2);
  bf16*  ctx    = (bf16*)take((size_t)S_LEN * HID * 2);

  const dim3 tb(32, 8);
  cast_f32_bf16<<<(S_LEN * HID / 4 + 255) / 256, 256, 0, stream>>>(hidden, hid_bf, S_LEN * HID / 4);
  transpose_cast<<<dim3((QL + 31) / 32, (HID + 31) / 32), tb, 0, stream>>>(w_qa, wabT, HID, QL);
  transpose_cast<<<dim3((CKV_N + 31) / 32, (HID + 31) / 32), tb, 0, stream>>>(w_kva, wabT + (size_t)QL * HID, HID, CKV_N);
  transpose_cast<<<dim3((QB_N + 31) / 32, (QL + 31) / 32), tb, 0, stream>>>(w_qb, wqbT, QL, QB_N);
  transpose_cast<<<dim3((KVB_N + 31) / 32, (KVL + 31) / 32), tb, 0, stream>>>(w_kvb, wkvbT, KVL, KVB_N);
  transpose_cast<<<dim3((HID + 31) / 32, (HID + 31) / 32), tb, 0, stream>>>(w_o, woT, HID, HID);

  // fused qa|kva GEMM
  gemm_qakva<<<dim3((AB_N + 63) / 64, S_LEN / 128), 256, 0, stream>>>(hid_bf, wabT, qlora, ckv);

  // kv prep (also builds rope tables for q path)
  kv_prep<<<S_LEN, 64, 0, stream>>>(ckv, kv_ln, pos, ckv_bf, kpe, ropc, rops);

  // q path: rmsnorm -> qb GEMM with fused rope -> qfull
  rmsnorm_rows<<<S_LEN, 256, 0, stream>>>(qlora, q_ln, qa_bf, QL);
  gemm_qb_rope<<<dim3(QB_N / 128, S_LEN / 128), 256, 0, stream>>>(qa_bf, wqbT, ropc, rops, qfull);

  // kv path: kvb GEMM with fused split/transpose -> knope, vt
  gemm_kvb_split<<<dim3(KVB_N / 128, S_LEN / 128), 256, 0, stream>>>(ckv_bf, wkvbT, knope, vt);

  // attention (uniform-work paired waves) + output proj
  attn_kernel<<<dim3(NH, 16), 256, 0, stream>>>(qfull, knope, kpe, vt, ctx);
  gemm_bt<false, false><<<dim3(HID / 128, S_LEN / 128), 256, 0, stream>>>(ctx, woT, out, S_LEN, HID, HID);
}

// Round 8
// 268.037 us; speedup vs baseline: 1.3615x; 1.3615x over previous
//
#include <hip/hip_runtime.h>
#include <hip/hip_bf16.h>

typedef __hip_bfloat16 bf16;
typedef __attribute__((ext_vector_type(8))) __bf16 bf16x8;
typedef __attribute__((ext_vector_type(4))) __bf16 bf16x4;
typedef __attribute__((ext_vector_type(4))) float f32x4;

constexpr int S_LEN = 2048;
constexpr int HID   = 2560;
constexpr int NH    = 40;
constexpr int QL    = 768;
constexpr int KVL   = 256;
constexpr int RD    = 32;
constexpr int ND    = 64;
constexpr int VD    = 64;
constexpr int QHD   = 96;                 // NOPE_D + ROPE_D
constexpr int QB_N  = NH * QHD;           // 3840
constexpr int KVB_N = NH * (ND + VD);     // 5120
constexpr int CKV_N = KVL + RD;           // 288
constexpr int AB_N  = QL + CKV_N;         // 1056 (fused qa|kva output cols)

#define MFMA16(a, b, c) __builtin_amdgcn_mfma_f32_16x16x32_bf16((a), (b), (c), 0, 0, 0)

// position_ids may arrive as int32 or int64; values are 0..2047 so sniff layout.
__device__ __forceinline__ int get_pos(const int* pos, int s) {
  bool is64 = (pos[1] == 0 && pos[2] == 1);
  return is64 ? pos[2 * s] : pos[s];
}

// ---------------- prep ----------------

__global__ void cast_f32_bf16(const float* __restrict__ src, bf16* __restrict__ dst, int n4) {
  int i = blockIdx.x * blockDim.x + threadIdx.x;
  if (i >= n4) return;
  float4 v = reinterpret_cast<const float4*>(src)[i];
  struct { bf16 a, b, c, d; } pk;
  pk.a = __float2bfloat16(v.x); pk.b = __float2bfloat16(v.y);
  pk.c = __float2bfloat16(v.z); pk.d = __float2bfloat16(v.w);
  reinterpret_cast<uint2*>(dst)[i] = *reinterpret_cast<uint2*>(&pk);
}

// src [K][N] f32 -> dst [N][K] bf16  (B^T layout for the GEMMs)
__global__ void transpose_cast(const float* __restrict__ src, bf16* __restrict__ dst, int K, int N) {
  __shared__ float tile[32][33];
  int nb = blockIdx.x * 32, kb = blockIdx.y * 32;
  int x = threadIdx.x, y = threadIdx.y; // (32,8)
#pragma unroll
  for (int j = 0; j < 4; ++j) {
    int k = kb + y + j * 8, n = nb + x;
    tile[y + j * 8][x] = (k < K && n < N) ? src[(size_t)k * N + n] : 0.f;
  }
  __syncthreads();
#pragma unroll
  for (int j = 0; j < 4; ++j) {
    int n = nb + y + j * 8, k = kb + x;
    if (n < N && k < K) dst[(size_t)n * K + k] = __float2bfloat16(tile[x][y + j * 8]);
  }
}

// ---------------- GEMMs ----------------

// Generic GEMM: C[M][N] = A[M][K] * B^T[N][K], f32 or bf16 out
template<bool OBF16, bool NEDGE>
__global__ __launch_bounds__(256) void gemm_bt(const bf16* __restrict__ A,
                                               const bf16* __restrict__ B,
                                               void* __restrict__ Cv,
                                               int M, int N, int K) {
  constexpr int BM = 128, BN = 128, BK = 64;
  __shared__ __bf16 ldsA[BM * BK];
  __shared__ __bf16 ldsB[BN * BK];
  const int t = threadIdx.x;
  const int l = t & 63, w = t >> 6;
  const int lr = l & 15, lk = l >> 4;
  const int wr = w >> 1, wc = w & 1;
  const int rowbase = blockIdx.y * BM;
  const int colbase = blockIdx.x * BN;

  f32x4 acc[4][4];
#pragma unroll
  for (int m = 0; m < 4; ++m)
#pragma unroll
    for (int n = 0; n < 4; ++n) acc[m][n] = f32x4{0.f, 0.f, 0.f, 0.f};

  const int kiters = K / BK;
  for (int kt = 0; kt < kiters; ++kt) {
    const int kb = kt * BK;
#pragma unroll
    for (int it = 0; it < 4; ++it) {
      const int r  = it * 32 + w * 8 + (l >> 3);
      const int c8 = ((l & 7) * 8) ^ ((r & 7) << 3);
      const bf16* ga = A + (size_t)(rowbase + r) * K + kb + c8;
      __builtin_amdgcn_global_load_lds((const __attribute__((address_space(1))) void*)ga,
          (__attribute__((address_space(3))) void*)(ldsA + it * 2048 + w * 512), 16, 0, 0);
      int nrow = colbase + r;
      if (NEDGE) nrow = (nrow < N) ? nrow : (N - 1);
      const bf16* gb = B + (size_t)nrow * K + kb + c8;
      __builtin_amdgcn_global_load_lds((const __attribute__((address_space(1))) void*)gb,
          (__attribute__((address_space(3))) void*)(ldsB + it * 2048 + w * 512), 16, 0, 0);
    }
    __syncthreads();
#pragma unroll
    for (int kk = 0; kk < 2; ++kk) {
      bf16x8 af[4], bfr[4];
#pragma unroll
      for (int m = 0; m < 4; ++m) {
        const int row = wr * 64 + m * 16 + lr;
        const int ce  = (kk * 32 + lk * 8) ^ ((row & 7) << 3);
        af[m] = *(const bf16x8*)(ldsA + row * BK + ce);
      }
#pragma unroll
      for (int n = 0; n < 4; ++n) {
        const int row = wc * 64 + n * 16 + lr;
        const int ce  = (kk * 32 + lk * 8) ^ ((row & 7) << 3);
        bfr[n] = *(const bf16x8*)(ldsB + row * BK + ce);
      }
#pragma unroll
      for (int m = 0; m < 4; ++m)
#pragma unroll
        for (int n = 0; n < 4; ++n)
          acc[m][n] = MFMA16(af[m], bfr[n], acc[m][n]);
    }
    __syncthreads();
  }

#pragma unroll
  for (int m = 0; m < 4; ++m)
#pragma unroll
    for (int n = 0; n < 4; ++n) {
      const int col = colbase + wc * 64 + n * 16 + lr;
      if (NEDGE && col >= N) continue;
#pragma unroll
      for (int i = 0; i < 4; ++i) {
        const int row = rowbase + wr * 64 + m * 16 + lk * 4 + i;
        if (OBF16) ((bf16*)Cv)[(size_t)row * N + col] = __float2bfloat16(acc[m][n][i]);
        else       ((float*)Cv)[(size_t)row * N + col] = acc[m][n][i];
      }
    }
}

// Fused qa|kva GEMM: C[2048][1056] = hid_bf * wabT^T, BN=64 tiles.
__global__ __launch_bounds__(256) void gemm_qakva(const bf16* __restrict__ A,
                                                  const bf16* __restrict__ B,
                                                  float* __restrict__ q_out,
                                                  float* __restrict__ ckv_out) {
  constexpr int BM = 128, BK = 64, K = HID, N = AB_N;
  __shared__ __bf16 ldsA[BM * BK];
  __shared__ __bf16 ldsB[64 * BK];
  const int t = threadIdx.x;
  const int l = t & 63, w = t >> 6;
  const int lr = l & 15, lk = l >> 4;
  const int rowbase = blockIdx.y * BM;
  const int colbase = blockIdx.x * 64;

  f32x4 acc[2][4];
#pragma unroll
  for (int m = 0; m < 2; ++m)
#pragma unroll
    for (int n = 0; n < 4; ++n) acc[m][n] = f32x4{0.f, 0.f, 0.f, 0.f};

  for (int kt = 0; kt < K / BK; ++kt) {
    const int kb = kt * BK;
#pragma unroll
    for (int it = 0; it < 4; ++it) {
      const int r  = it * 32 + w * 8 + (l >> 3);
      const int c8 = ((l & 7) * 8) ^ ((r & 7) << 3);
      const bf16* ga = A + (size_t)(rowbase + r) * K + kb + c8;
      __builtin_amdgcn_global_load_lds((const __attribute__((address_space(1))) void*)ga,
          (__attribute__((address_space(3))) void*)(ldsA + it * 2048 + w * 512), 16, 0, 0);
      if (it < 2) {
        int nrow = colbase + r;
        nrow = (nrow < N) ? nrow : (N - 1);
        const bf16* gb = B + (size_t)nrow * K + kb + c8;
        __builtin_amdgcn_global_load_lds((const __attribute__((address_space(1))) void*)gb,
            (__attribute__((address_space(3))) void*)(ldsB + it * 2048 + w * 512), 16, 0, 0);
      }
    }
    __syncthreads();
#pragma unroll
    for (int kk = 0; kk < 2; ++kk) {
      bf16x8 af[2], bfr[4];
#pragma unroll
      for (int m = 0; m < 2; ++m) {
        const int row = w * 32 + m * 16 + lr;
        const int ce  = (kk * 32 + lk * 8) ^ ((row & 7) << 3);
        af[m] = *(const bf16x8*)(ldsA + row * BK + ce);
      }
#pragma unroll
      for (int n = 0; n < 4; ++n) {
        const int row = n * 16 + lr;
        const int ce  = (kk * 32 + lk * 8) ^ ((row & 7) << 3);
        bfr[n] = *(const bf16x8*)(ldsB + row * BK + ce);
      }
#pragma unroll
      for (int m = 0; m < 2; ++m)
#pragma unroll
        for (int n = 0; n < 4; ++n)
          acc[m][n] = MFMA16(af[m], bfr[n], acc[m][n]);
    }
    __syncthreads();
  }

#pragma unroll
  for (int m = 0; m < 2; ++m)
#pragma unroll
    for (int n = 0; n < 4; ++n) {
      const int col = colbase + n * 16 + lr;
#pragma unroll
      for (int i = 0; i < 4; ++i) {
        const int row = rowbase + w * 32 + m * 16 + lk * 4 + i;
        if (col < QL)       q_out[(size_t)row * QL + col] = acc[m][n][i];
        else if (col < N)   ckv_out[(size_t)row * CKV_N + (col - QL)] = acc[m][n][i];
      }
    }
}

// qb GEMM with fused RoPE + scale, writing qfull [NH][S][96] directly.
__global__ __launch_bounds__(256) void gemm_qb_rope(const bf16* __restrict__ A,
                                                    const bf16* __restrict__ B,
                                                    const float* __restrict__ ropc,
                                                    const float* __restrict__ rops,
                                                    bf16* __restrict__ qfull) {
  constexpr int BM = 128, BN = 128, BK = 64, K = QL, N = QB_N;
  __shared__ __bf16 ldsA[BM * BK];
  __shared__ __bf16 ldsB[BN * BK];
  const int t = threadIdx.x;
  const int l = t & 63, w = t >> 6;
  const int lr = l & 15, lk = l >> 4;
  const int wr = w >> 1, wc = w & 1;
  const int rowbase = blockIdx.y * BM;
  const int colbase = blockIdx.x * BN;
  const float scale = 0.14724444f; // 96^-0.5 * log2(e)

  f32x4 acc[4][4];
#pragma unroll
  for (int m = 0; m < 4; ++m)
#pragma unroll
    for (int n = 0; n < 4; ++n) acc[m][n] = f32x4{0.f, 0.f, 0.f, 0.f};

  for (int kt = 0; kt < K / BK; ++kt) {
    const int kb = kt * BK;
#pragma unroll
    for (int it = 0; it < 4; ++it) {
      const int r  = it * 32 + w * 8 + (l >> 3);
      const int c8 = ((l & 7) * 8) ^ ((r & 7) << 3);
      const bf16* ga = A + (size_t)(rowbase + r) * K + kb + c8;
      __builtin_amdgcn_global_load_lds((const __attribute__((address_space(1))) void*)ga,
          (__attribute__((address_space(3))) void*)(ldsA + it * 2048 + w * 512), 16, 0, 0);
      const bf16* gb = B + (size_t)(colbase + r) * K + kb + c8;
      __builtin_amdgcn_global_load_lds((const __attribute__((address_space(1))) void*)gb,
          (__attribute__((address_space(3))) void*)(ldsB + it * 2048 + w * 512), 16, 0, 0);
    }
    __syncthreads();
#pragma unroll
    for (int kk = 0; kk < 2; ++kk) {
      bf16x8 af[4], bfr[4];
#pragma unroll
      for (int m = 0; m < 4; ++m) {
        const int row = wr * 64 + m * 16 + lr;
        const int ce  = (kk * 32 + lk * 8) ^ ((row & 7) << 3);
        af[m] = *(const bf16x8*)(ldsA + row * BK + ce);
      }
#pragma unroll
      for (int n = 0; n < 4; ++n) {
        const int row = wc * 64 + n * 16 + lr;
        const int ce  = (kk * 32 + lk * 8) ^ ((row & 7) << 3);
        bfr[n] = *(const bf16x8*)(ldsB + row * BK + ce);
      }
#pragma unroll
      for (int m = 0; m < 4; ++m)
#pragma unroll
        for (int n = 0; n < 4; ++n)
          acc[m][n] = MFMA16(af[m], bfr[n], acc[m][n]);
    }
    __syncthreads();
  }

#pragma unroll
  for (int m = 0; m < 4; ++m) {
    const int rowtop = rowbase + wr * 64 + m * 16 + lk * 4;
#pragma unroll
    for (int n = 0; n < 4; ++n) {
      const int c0 = colbase + wc * 64 + n * 16; // frag base col
      const int h  = c0 / 96;
      const int d0 = c0 - h * 96;
      const size_t qb_ = ((size_t)h * S_LEN + rowtop) * QHD + d0 + lr;
      if (d0 < ND) {
#pragma unroll
        for (int i = 0; i < 4; ++i)
          qfull[qb_ + (size_t)i * QHD] = __float2bfloat16(acc[m][n][i] * scale);
      } else if (d0 == ND) { // rope-lo: out = x0*c - x1*s, x1 = acc[m][n+1]
#pragma unroll
        for (int i = 0; i < 4; ++i) {
          const float c = ropc[(rowtop + i) * 16 + lr];
          const float s = rops[(rowtop + i) * 16 + lr];
          const float x0 = acc[m][n][i], x1 = acc[m][n + 1][i];
          qfull[qb_ + (size_t)i * QHD] = __float2bfloat16((x0 * c - x1 * s) * scale);
        }
      } else { // d0 == 80, rope-hi: out = x1*c + x0*s, x0 = acc[m][n-1]
#pragma unroll
        for (int i = 0; i < 4; ++i) {
          const float c = ropc[(rowtop + i) * 16 + lr];
          const float s = rops[(rowtop + i) * 16 + lr];
          const float x1 = acc[m][n][i], x0 = acc[m][n - 1][i];
          qfull[qb_ + (size_t)i * QHD] = __float2bfloat16((x1 * c + x0 * s) * scale);
        }
      }
    }
  }
}

// kvb GEMM writing knope (PRE-SWIZZLED, 16B chunk c ^= s&7) and vt directly.
__global__ __launch_bounds__(256) void gemm_kvb_split(const bf16* __restrict__ A,
                                                      const bf16* __restrict__ B,
                                                      bf16* __restrict__ knope,
                                                      bf16* __restrict__ vt) {
  constexpr int BM = 128, BN = 128, BK = 64, K = KVL;
  __shared__ __bf16 ldsA[BM * BK];
  __shared__ __bf16 ldsB[BN * BK];
  const int t = threadIdx.x;
  const int l = t & 63, w = t >> 6;
  const int lr = l & 15, lk = l >> 4;
  const int wr = w >> 1, wc = w & 1;
  const int rowbase = blockIdx.y * BM;
  const int h = blockIdx.x; // head == col tile
  const int colbase = h * BN;

  f32x4 acc[4][4];
#pragma unroll
  for (int m = 0; m < 4; ++m)
#pragma unroll
    for (int n = 0; n < 4; ++n) acc[m][n] = f32x4{0.f, 0.f, 0.f, 0.f};

  for (int kt = 0; kt < K / BK; ++kt) {
    const int kb = kt * BK;
#pragma unroll
    for (int it = 0; it < 4; ++it) {
      const int r  = it * 32 + w * 8 + (l >> 3);
      const int c8 = ((l & 7) * 8) ^ ((r & 7) << 3);
      const bf16* ga = A + (size_t)(rowbase + r) * K + kb + c8;
      __builtin_amdgcn_global_load_lds((const __attribute__((address_space(1))) void*)ga,
          (__attribute__((address_space(3))) void*)(ldsA + it * 2048 + w * 512), 16, 0, 0);
      const bf16* gb = B + (size_t)(colbase + r) * K + kb + c8;
      __builtin_amdgcn_global_load_lds((const __attribute__((address_space(1))) void*)gb,
          (__attribute__((address_space(3))) void*)(ldsB + it * 2048 + w * 512), 16, 0, 0);
    }
    __syncthreads();
#pragma unroll
    for (int kk = 0; kk < 2; ++kk) {
      bf16x8 af[4], bfr[4];
#pragma unroll
      for (int m = 0; m < 4; ++m) {
        const int row = wr * 64 + m * 16 + lr;
        const int ce  = (kk * 32 + lk * 8) ^ ((row & 7) << 3);
        af[m] = *(const bf16x8*)(ldsA + row * BK + ce);
      }
#pragma unroll
      for (int n = 0; n < 4; ++n) {
        const int row = wc * 64 + n * 16 + lr;
        const int ce  = (kk * 32 + lk * 8) ^ ((row & 7) << 3);
        bfr[n] = *(const bf16x8*)(ldsB + row * BK + ce);
      }
#pragma unroll
      for (int m = 0; m < 4; ++m)
#pragma unroll
        for (int n = 0; n < 4; ++n)
          acc[m][n] = MFMA16(af[m], bfr[n], acc[m][n]);
    }
    __syncthreads();
  }

#pragma unroll
  for (int m = 0; m < 4; ++m) {
    const int rowtop = rowbase + wr * 64 + m * 16 + lk * 4;
    if (wc == 0) { // k_nope -> knope[h][s][ swizzled d ]
#pragma unroll
      for (int n = 0; n < 4; ++n) {
        const int d = n * 16 + lr;
        const int chunk = d >> 3, dlo = d & 7;
#pragma unroll
        for (int i = 0; i < 4; ++i) {
          const int s = rowtop + i;
          const int dsw = ((chunk ^ (s & 7)) << 3) + dlo;
          knope[((size_t)h * S_LEN + s) * ND + dsw] = __float2bfloat16(acc[m][n][i]);
        }
      }
    } else {        // V -> vt[h][64][S] (8B transposed stores, L2 merges)
#pragma unroll
      for (int n = 0; n < 4; ++n) {
        const int d = n * 16 + lr;
        bf16x4 pk;
#pragma unroll
        for (int i = 0; i < 4; ++i) pk[i] = (__bf16)acc[m][n][i];
        *(bf16x4*)(vt + ((size_t)h * VD + d) * S_LEN + rowtop) = pk;
      }
    }
  }
}

// ---------------- norms / prep ----------------

__global__ void rmsnorm_rows(const float* __restrict__ in, const float* __restrict__ w,
                             bf16* __restrict__ out, int C) {
  const int r = blockIdx.x;
  const float* row = in + (size_t)r * C;
  float ss = 0.f;
  for (int c = threadIdx.x; c < C; c += 256) { float v = row[c]; ss += v * v; }
#pragma unroll
  for (int d = 32; d > 0; d >>= 1) ss += __shfl_xor(ss, d);
  __shared__ float red[4];
  if ((threadIdx.x & 63) == 0) red[threadIdx.x >> 6] = ss;
  __syncthreads();
  const float tot = red[0] + red[1] + red[2] + red[3];
  const float rs = rsqrtf(tot / (float)C + 1e-6f);
  for (int c = threadIdx.x; c < C; c += 256)
    out[(size_t)r * C + c] = __float2bfloat16(row[c] * rs * w[c]);
}

// per row: rmsnorm(ckv[0:256]) -> bf16 ; rope(k_pe) -> bf16 ; rope tables
__global__ void kv_prep(const float* __restrict__ ckv, const float* __restrict__ w,
                        const int* __restrict__ pos, bf16* __restrict__ ckv_bf,
                        bf16* __restrict__ kpe, float* __restrict__ ropc,
                        float* __restrict__ rops) {
  const int s = blockIdx.x, t = threadIdx.x; // 64 threads
  const float* row = ckv + (size_t)s * CKV_N;
  float v[4]; float ss = 0.f;
#pragma unroll
  for (int j = 0; j < 4; ++j) { v[j] = row[t + 64 * j]; ss += v[j] * v[j]; }
#pragma unroll
  for (int d = 32; d > 0; d >>= 1) ss += __shfl_xor(ss, d);
  const float rs = rsqrtf(ss / (float)KVL + 1e-6f);
#pragma unroll
  for (int j = 0; j < 4; ++j)
    ckv_bf[(size_t)s * KVL + t + 64 * j] = __float2bfloat16(v[j] * rs * w[t + 64 * j]);
  if (t < 16) {
    const float x0 = row[KVL + t], x1 = row[KVL + 16 + t];
    const float p = (float)get_pos(pos, s);
    const float invf = exp2f(-(float)t * (13.2877124f / 16.f)); // 10000^(-t/16)
    const float ang = p * invf, c = cosf(ang), sn = sinf(ang);
    ropc[s * 16 + t] = c;
    rops[s * 16 + t] = sn;
    kpe[(size_t)s * RD + t]      = __float2bfloat16(x0 * c - x1 * sn);
    kpe[(size_t)s * RD + 16 + t] = __float2bfloat16(x1 * c + x0 * sn);
  }
}

// ---------------- causal flash attention ----------------
// Block = 128 q rows of one head, 4 waves x 32 rows, ALL waves share the
// k-loop; K_nope staged once per block into LDS double-buffer via
// global_load_lds (source pre-swizzled by gemm_kvb_split, linear LDS dest,
// XOR-swizzled read -> conflict-free). k_pe stays in regs (L1-hot, 1-tile
// prefetch). Per-wave: swapped QK^T (S^T: lane-local row reduce + 2 shfl),
// log2-domain softmax, defer-rescale, XOR-swizzled per-wave P tile, V direct
// from L2. Grid (NH, 16), q-blocks REVERSED (heavy first -> LPT).
__global__ __launch_bounds__(256) void attn_kernel(const bf16* __restrict__ qfull,
                                                   const bf16* __restrict__ knope,
                                                   const bf16* __restrict__ kpe,
                                                   const bf16* __restrict__ vt,
                                                   bf16* __restrict__ ctx) {
  const int h = blockIdx.x;
  const int qb = ((int)gridDim.y - 1 - (int)blockIdx.y) * 128;
  const int t = threadIdx.x, w = t >> 6, l = t & 63;
  const int lr = l & 15, lk = l >> 4;
  const int qw = qb + w * 32;
  const int lastw = (qw >> 6) << 6;          // this wave's final k-tile base
  const int last3 = ((qb + 96) >> 6) << 6;   // block's final k-tile base
  const bf16* Q  = qfull + (size_t)h * S_LEN * QHD;
  const bf16* Kn = knope + (size_t)h * S_LEN * ND;
  const bf16* V  = vt + (size_t)h * VD * S_LEN;
  __shared__ __bf16 kbuf[2][64 * ND];  // 16KB double-buffered K tile
  __shared__ __bf16 plds[4][32][64];   // 16KB per-wave P tiles, XOR-swizzled

  bf16x8 qf[2][3];
#pragma unroll
  for (int qg = 0; qg < 2; ++qg)
#pragma unroll
    for (int ks = 0; ks < 3; ++ks)
      qf[qg][ks] = *(const bf16x8*)(Q + (size_t)(qw + qg * 16 + lr) * QHD + ks * 32 + lk * 8);

  f32x4 o[2][4];
  float mrow[2], lrow[2];
#pragma unroll
  for (int qg = 0; qg < 2; ++qg) {
#pragma unroll
    for (int dt = 0; dt < 4; ++dt) o[qg][dt] = f32x4{0.f, 0.f, 0.f, 0.f};
    mrow[qg] = -1e30f; lrow[qg] = 0.f;
  }

  // stage: linear both sides (tile is contiguous 8KB in global; src pre-swizzled)
  auto stage = [&](int buf, int kb) {
    const bf16* src = Kn + (size_t)kb * ND + w * 512 + l * 8;
    __bf16* dst = &kbuf[buf][w * 512];
#pragma unroll
    for (int i = 0; i < 2; ++i)
      __builtin_amdgcn_global_load_lds((const __attribute__((address_space(1))) void*)(src + i * 2048),
          (__attribute__((address_space(3))) void*)(dst + i * 2048), 16, 0, 0);
  };

  stage(0, 0);
  bf16x8 pe[4];
#pragma unroll
  for (int sub = 0; sub < 4; ++sub)
    pe[sub] = *(const bf16x8*)(kpe + (size_t)(sub * 16 + lr) * RD + lk * 8);
  __syncthreads();

  for (int kb = 0;; kb += 64) {
    const int cur = (kb >> 6) & 1;
    if (kb + 64 <= last3) stage(cur ^ 1, kb + 64);

    if (kb <= lastw) {
      // K frags from LDS (swizzled read: chunk = (ks*4+lk) ^ (row&7))
      bf16x8 kfn[4][2];
#pragma unroll
      for (int sub = 0; sub < 4; ++sub) {
        const int row = sub * 16 + lr;
#pragma unroll
        for (int ks = 0; ks < 2; ++ks) {
          const int ch = ((ks * 4 + lk) ^ (lr & 7)) << 3;
          kfn[sub][ks] = *(const bf16x8*)(&kbuf[cur][row * ND + ch]);
        }
      }

      f32x4 st[2][4];
#pragma unroll
      for (int qg = 0; qg < 2; ++qg)
#pragma unroll
        for (int sub = 0; sub < 4; ++sub) st[qg][sub] = f32x4{0.f, 0.f, 0.f, 0.f};
#pragma unroll
      for (int qg = 0; qg < 2; ++qg)
#pragma unroll
        for (int sub = 0; sub < 4; ++sub) {
          st[qg][sub] = MFMA16(kfn[sub][0], qf[qg][0], st[qg][sub]);
          st[qg][sub] = MFMA16(kfn[sub][1], qf[qg][1], st[qg][sub]);
          st[qg][sub] = MFMA16(pe[sub],     qf[qg][2], st[qg][sub]);
        }

      // prefetch next tile's k_pe regs (hidden under softmax+PV)
      const int nkb = kb + 64;
      bf16x8 pen[4];
      if (nkb <= lastw) {
#pragma unroll
        for (int sub = 0; sub < 4; ++sub)
          pen[sub] = *(const bf16x8*)(kpe + (size_t)(nkb + sub * 16 + lr) * RD + lk * 8);
      }

      const bool diag = (kb == lastw);
      float tm[2];
#pragma unroll
      for (int qg = 0; qg < 2; ++qg) {
        const int q = qw + qg * 16 + lr;
        if (diag) {
#pragma unroll
          for (int sub = 0; sub < 4; ++sub)
#pragma unroll
            for (int i = 0; i < 4; ++i)
              if (kb + sub * 16 + lk * 4 + i > q) st[qg][sub][i] = -1e30f;
        }
        float m0 = -1e30f;
#pragma unroll
        for (int sub = 0; sub < 4; ++sub)
#pragma unroll
          for (int i = 0; i < 4; ++i) m0 = fmaxf(m0, st[qg][sub][i]);
        m0 = fmaxf(m0, __shfl_xor(m0, 16));
        m0 = fmaxf(m0, __shfl_xor(m0, 32));
        tm[qg] = m0;
      }

      const bool noresc = __all((tm[0] <= mrow[0] + 8.f) && (tm[1] <= mrow[1] + 8.f));
      float fac[2];
#pragma unroll
      for (int qg = 0; qg < 2; ++qg) {
        const float mnew = noresc ? mrow[qg] : fmaxf(mrow[qg], tm[qg]);
        float ts = 0.f;
#pragma unroll
        for (int sub = 0; sub < 4; ++sub) {
          bf16x4 pk;
#pragma unroll
          for (int i = 0; i < 4; ++i) {
            const float pv = exp2f(st[qg][sub][i] - mnew);
            ts += pv;
            pk[i] = (__bf16)pv;
          }
          const int swc = (sub * 16 + lk * 4) ^ ((lr & 7) << 3);
          *(bf16x4*)(&plds[w][qg * 16 + lr][swc]) = pk;
        }
        ts += __shfl_xor(ts, 16);
        ts += __shfl_xor(ts, 32);
        if (noresc) {
          lrow[qg] += ts;
        } else {
          fac[qg] = exp2f(mrow[qg] - mnew);
          lrow[qg] = lrow[qg] * fac[qg] + ts;
          mrow[qg] = mnew;
        }
      }
      if (!noresc) {
#pragma unroll
        for (int qg = 0; qg < 2; ++qg)
#pragma unroll
          for (int i = 0; i < 4; ++i) {
            const float fr = __shfl(fac[qg], lk * 4 + i);
#pragma unroll
            for (int dt = 0; dt < 4; ++dt) o[qg][dt][i] *= fr;
          }
      }

      // PV: A = P from LDS (swizzled read), B = V^T rows (contiguous in s)
#pragma unroll
      for (int h2 = 0; h2 < 2; ++h2) {
        const int swc = (h2 * 32 + lk * 8) ^ ((lr & 7) << 3);
        bf16x8 pa0 = *(const bf16x8*)(&plds[w][lr][swc]);
        bf16x8 pa1 = *(const bf16x8*)(&plds[w][16 + lr][swc]);
#pragma unroll
        for (int dt = 0; dt < 4; ++dt) {
          bf16x8 vf = *(const bf16x8*)(V + (size_t)(dt * 16 + lr) * S_LEN + kb + h2 * 32 + lk * 8);
          o[0][dt] = MFMA16(pa0, vf, o[0][dt]);
          o[1][dt] = MFMA16(pa1, vf, o[1][dt]);
        }
      }

      if (nkb <= lastw) {
#pragma unroll
        for (int sub = 0; sub < 4; ++sub) pe[sub] = pen[sub];
      }
    }

    __syncthreads();
    if (kb == last3) break;
  }

#pragma unroll
  for (int qg = 0; qg < 2; ++qg) {
    const float linv = 1.0f / lrow[qg];
#pragma unroll
    for (int i = 0; i < 4; ++i) {
      const float inv = __shfl(linv, lk * 4 + i);
#pragma unroll
      for (int dt = 0; dt < 4; ++dt) {
        const int row = qw + qg * 16 + lk * 4 + i;
        const int col = h * VD + dt * 16 + lr;
        ctx[(size_t)row * HID + col] = __float2bfloat16(o[qg][dt][i] * inv);
      }
    }
  }
}

// ---------------- launch ----------------

extern "C" void kernel_launch(void* const* d_in, const int* in_sizes, int n_in,
                              void* d_out, int out_size, void* d_ws, size_t ws_size,
                              hipStream_t stream) {
  const float* hidden = (const float*)d_in[0];
  const int*   pos    = (const int*)d_in[1];
  const float* w_qa   = (const float*)d_in[2];
  const float* q_ln   = (const float*)d_in[3];
  const float* w_qb   = (const float*)d_in[4];
  const float* w_kva  = (const float*)d_in[5];
  const float* kv_ln  = (const float*)d_in[6];
  const float* w_kvb  = (const float*)d_in[7];
  const float* w_o    = (const float*)d_in[8];
  float* out = (float*)d_out;
  char* ws = (char*)d_ws;
  (void)in_sizes; (void)n_in; (void)out_size; (void)ws_size;

  size_t off = 0;
  auto take = [&](size_t bytes) -> char* {
    char* p = ws + off;
    off = (off + bytes + 255) & ~(size_t)255;
    return p;
  };
  bf16*  hid_bf = (bf16*)take((size_t)S_LEN * HID * 2);
  bf16*  wabT   = (bf16*)take((size_t)AB_N * HID * 2);   // wqaT | wkvaT
  bf16*  wqbT   = (bf16*)take((size_t)QB_N * QL * 2);
  bf16*  wkvbT  = (bf16*)take((size_t)KVB_N * KVL * 2);
  bf16*  woT    = (bf16*)take((size_t)HID * HID * 2);
  float* qlora  = (float*)take((size_t)S_LEN * QL * 4);
  bf16*  qa_bf  = (bf16*)take((size_t)S_LEN * QL * 2);
  bf16*  qfull  = (bf16*)take((size_t)NH * S_LEN * QHD * 2);
  float* ckv    = (float*)take((size_t)S_LEN * CKV_N * 4);
  bf16*  ckv_bf = (bf16*)take((size_t)S_LEN * KVL * 2);
  bf16*  kpe    = (bf16*)take((size_t)S_LEN * RD * 2);
  float* ropc   = (float*)take((size_t)S_LEN * 16 * 4);
  float* rops   = (float*)take((size_t)S_LEN * 16 * 4);
  bf16*  knope  = (bf16*)take((size_t)NH * S_LEN * ND * 2);
  bf16*  vt     = (bf16*)take((size_t)NH * VD * S_LEN * 2);
  bf16*  ctx    = (bf16*)take((size_t)S_LEN * HID * 2);

  const dim3 tb(32, 8);
  cast_f32_bf16<<<(S_LEN * HID / 4 + 255) / 256, 256, 0, stream>>>(hidden, hid_bf, S_LEN * HID / 4);
  transpose_cast<<<dim3((QL + 31) / 32, (HID + 31) / 32), tb, 0, stream>>>(w_qa, wabT, HID, QL);
  transpose_cast<<<dim3((CKV_N + 31) / 32, (HID + 31) / 32), tb, 0, stream>>>(w_kva, wabT + (size_t)QL * HID, HID, CKV_N);
  transpose_cast<<<dim3((QB_N + 31) / 32, (QL + 31) / 32), tb, 0, stream>>>(w_qb, wqbT, QL, QB_N);
  transpose_cast<<<dim3((KVB_N + 31) / 32, (KVL + 31) / 32), tb, 0, stream>>>(w_kvb, wkvbT, KVL, KVB_N);
  transpose_cast<<<dim3((HID + 31) / 32, (HID + 31) / 32), tb, 0, stream>>>(w_o, woT, HID, HID);

  // fused qa|kva GEMM
  gemm_qakva<<<dim3((AB_N + 63) / 64, S_LEN / 128), 256, 0, stream>>>(hid_bf, wabT, qlora, ckv);

  // kv prep (also builds rope tables for q path)
  kv_prep<<<S_LEN, 64, 0, stream>>>(ckv, kv_ln, pos, ckv_bf, kpe, ropc, rops);

  // q path: rmsnorm -> qb GEMM with fused rope -> qfull
  rmsnorm_rows<<<S_LEN, 256, 0, stream>>>(qlora, q_ln, qa_bf, QL);
  gemm_qb_rope<<<dim3(QB_N / 128, S_LEN / 128), 256, 0, stream>>>(qa_bf, wqbT, ropc, rops, qfull);

  // kv path: kvb GEMM with fused split/transpose -> knope(swizzled), vt
  gemm_kvb_split<<<dim3(KVB_N / 128, S_LEN / 128), 256, 0, stream>>>(ckv_bf, wkvbT, knope, vt);

  // attention (4-wave shared-K blocks) + output proj
  attn_kernel<<<dim3(NH, 16), 256, 0, stream>>>(qfull, knope, kpe, vt, ctx);
  gemm_bt<false, false><<<dim3(HID / 128, S_LEN / 128), 256, 0, stream>>>(ctx, woT, out, S_LEN, HID, HID);
}

// Round 9
// 264.865 us; speedup vs baseline: 1.3778x; 1.0120x over previous
//
#include <hip/hip_runtime.h>
#include <hip/hip_bf16.h>

typedef __hip_bfloat16 bf16;
typedef __attribute__((ext_vector_type(8))) __bf16 bf16x8;
typedef __attribute__((ext_vector_type(4))) __bf16 bf16x4;
typedef __attribute__((ext_vector_type(4))) float f32x4;

constexpr int S_LEN = 2048;
constexpr int HID   = 2560;
constexpr int NH    = 40;
constexpr int QL    = 768;
constexpr int KVL   = 256;
constexpr int RD    = 32;
constexpr int ND    = 64;
constexpr int VD    = 64;
constexpr int QHD   = 96;                 // NOPE_D + ROPE_D
constexpr int QB_N  = NH * QHD;           // 3840
constexpr int KVB_N = NH * (ND + VD);     // 5120
constexpr int CKV_N = KVL + RD;           // 288
constexpr int AB_N  = QL + CKV_N;         // 1056 (fused qa|kva output cols)

#define MFMA16(a, b, c) __builtin_amdgcn_mfma_f32_16x16x32_bf16((a), (b), (c), 0, 0, 0)

// position_ids may arrive as int32 or int64; values are 0..2047 so sniff layout.
__device__ __forceinline__ int get_pos(const int* pos, int s) {
  bool is64 = (pos[1] == 0 && pos[2] == 1);
  return is64 ? pos[2 * s] : pos[s];
}

// ---------------- prep ----------------

__global__ void cast_f32_bf16(const float* __restrict__ src, bf16* __restrict__ dst, int n4) {
  int i = blockIdx.x * blockDim.x + threadIdx.x;
  if (i >= n4) return;
  float4 v = reinterpret_cast<const float4*>(src)[i];
  struct { bf16 a, b, c, d; } pk;
  pk.a = __float2bfloat16(v.x); pk.b = __float2bfloat16(v.y);
  pk.c = __float2bfloat16(v.z); pk.d = __float2bfloat16(v.w);
  reinterpret_cast<uint2*>(dst)[i] = *reinterpret_cast<uint2*>(&pk);
}

// src [K][N] f32 -> dst [N][K] bf16  (B^T layout for the GEMMs)
__global__ void transpose_cast(const float* __restrict__ src, bf16* __restrict__ dst, int K, int N) {
  __shared__ float tile[32][33];
  int nb = blockIdx.x * 32, kb = blockIdx.y * 32;
  int x = threadIdx.x, y = threadIdx.y; // (32,8)
#pragma unroll
  for (int j = 0; j < 4; ++j) {
    int k = kb + y + j * 8, n = nb + x;
    tile[y + j * 8][x] = (k < K && n < N) ? src[(size_t)k * N + n] : 0.f;
  }
  __syncthreads();
#pragma unroll
  for (int j = 0; j < 4; ++j) {
    int n = nb + y + j * 8, k = kb + x;
    if (n < N && k < K) dst[(size_t)n * K + k] = __float2bfloat16(tile[x][y + j * 8]);
  }
}

// ---------------- GEMMs ----------------

// Generic GEMM: C[M][N] = A[M][K] * B^T[N][K], f32 or bf16 out
template<bool OBF16, bool NEDGE>
__global__ __launch_bounds__(256) void gemm_bt(const bf16* __restrict__ A,
                                               const bf16* __restrict__ B,
                                               void* __restrict__ Cv,
                                               int M, int N, int K) {
  constexpr int BM = 128, BN = 128, BK = 64;
  __shared__ __bf16 ldsA[BM * BK];
  __shared__ __bf16 ldsB[BN * BK];
  const int t = threadIdx.x;
  const int l = t & 63, w = t >> 6;
  const int lr = l & 15, lk = l >> 4;
  const int wr = w >> 1, wc = w & 1;
  const int rowbase = blockIdx.y * BM;
  const int colbase = blockIdx.x * BN;

  f32x4 acc[4][4];
#pragma unroll
  for (int m = 0; m < 4; ++m)
#pragma unroll
    for (int n = 0; n < 4; ++n) acc[m][n] = f32x4{0.f, 0.f, 0.f, 0.f};

  const int kiters = K / BK;
  for (int kt = 0; kt < kiters; ++kt) {
    const int kb = kt * BK;
#pragma unroll
    for (int it = 0; it < 4; ++it) {
      const int r  = it * 32 + w * 8 + (l >> 3);
      const int c8 = ((l & 7) * 8) ^ ((r & 7) << 3);
      const bf16* ga = A + (size_t)(rowbase + r) * K + kb + c8;
      __builtin_amdgcn_global_load_lds((const __attribute__((address_space(1))) void*)ga,
          (__attribute__((address_space(3))) void*)(ldsA + it * 2048 + w * 512), 16, 0, 0);
      int nrow = colbase + r;
      if (NEDGE) nrow = (nrow < N) ? nrow : (N - 1);
      const bf16* gb = B + (size_t)nrow * K + kb + c8;
      __builtin_amdgcn_global_load_lds((const __attribute__((address_space(1))) void*)gb,
          (__attribute__((address_space(3))) void*)(ldsB + it * 2048 + w * 512), 16, 0, 0);
    }
    __syncthreads();
#pragma unroll
    for (int kk = 0; kk < 2; ++kk) {
      bf16x8 af[4], bfr[4];
#pragma unroll
      for (int m = 0; m < 4; ++m) {
        const int row = wr * 64 + m * 16 + lr;
        const int ce  = (kk * 32 + lk * 8) ^ ((row & 7) << 3);
        af[m] = *(const bf16x8*)(ldsA + row * BK + ce);
      }
#pragma unroll
      for (int n = 0; n < 4; ++n) {
        const int row = wc * 64 + n * 16 + lr;
        const int ce  = (kk * 32 + lk * 8) ^ ((row & 7) << 3);
        bfr[n] = *(const bf16x8*)(ldsB + row * BK + ce);
      }
#pragma unroll
      for (int m = 0; m < 4; ++m)
#pragma unroll
        for (int n = 0; n < 4; ++n)
          acc[m][n] = MFMA16(af[m], bfr[n], acc[m][n]);
    }
    __syncthreads();
  }

#pragma unroll
  for (int m = 0; m < 4; ++m)
#pragma unroll
    for (int n = 0; n < 4; ++n) {
      const int col = colbase + wc * 64 + n * 16 + lr;
      if (NEDGE && col >= N) continue;
#pragma unroll
      for (int i = 0; i < 4; ++i) {
        const int row = rowbase + wr * 64 + m * 16 + lk * 4 + i;
        if (OBF16) ((bf16*)Cv)[(size_t)row * N + col] = __float2bfloat16(acc[m][n][i]);
        else       ((float*)Cv)[(size_t)row * N + col] = acc[m][n][i];
      }
    }
}

// Fused qa|kva GEMM: C[2048][1056] = hid_bf * wabT^T, BN=64 tiles.
__global__ __launch_bounds__(256) void gemm_qakva(const bf16* __restrict__ A,
                                                  const bf16* __restrict__ B,
                                                  float* __restrict__ q_out,
                                                  float* __restrict__ ckv_out) {
  constexpr int BM = 128, BK = 64, K = HID, N = AB_N;
  __shared__ __bf16 ldsA[BM * BK];
  __shared__ __bf16 ldsB[64 * BK];
  const int t = threadIdx.x;
  const int l = t & 63, w = t >> 6;
  const int lr = l & 15, lk = l >> 4;
  const int rowbase = blockIdx.y * BM;
  const int colbase = blockIdx.x * 64;

  f32x4 acc[2][4];
#pragma unroll
  for (int m = 0; m < 2; ++m)
#pragma unroll
    for (int n = 0; n < 4; ++n) acc[m][n] = f32x4{0.f, 0.f, 0.f, 0.f};

  for (int kt = 0; kt < K / BK; ++kt) {
    const int kb = kt * BK;
#pragma unroll
    for (int it = 0; it < 4; ++it) {
      const int r  = it * 32 + w * 8 + (l >> 3);
      const int c8 = ((l & 7) * 8) ^ ((r & 7) << 3);
      const bf16* ga = A + (size_t)(rowbase + r) * K + kb + c8;
      __builtin_amdgcn_global_load_lds((const __attribute__((address_space(1))) void*)ga,
          (__attribute__((address_space(3))) void*)(ldsA + it * 2048 + w * 512), 16, 0, 0);
      if (it < 2) {
        int nrow = colbase + r;
        nrow = (nrow < N) ? nrow : (N - 1);
        const bf16* gb = B + (size_t)nrow * K + kb + c8;
        __builtin_amdgcn_global_load_lds((const __attribute__((address_space(1))) void*)gb,
            (__attribute__((address_space(3))) void*)(ldsB + it * 2048 + w * 512), 16, 0, 0);
      }
    }
    __syncthreads();
#pragma unroll
    for (int kk = 0; kk < 2; ++kk) {
      bf16x8 af[2], bfr[4];
#pragma unroll
      for (int m = 0; m < 2; ++m) {
        const int row = w * 32 + m * 16 + lr;
        const int ce  = (kk * 32 + lk * 8) ^ ((row & 7) << 3);
        af[m] = *(const bf16x8*)(ldsA + row * BK + ce);
      }
#pragma unroll
      for (int n = 0; n < 4; ++n) {
        const int row = n * 16 + lr;
        const int ce  = (kk * 32 + lk * 8) ^ ((row & 7) << 3);
        bfr[n] = *(const bf16x8*)(ldsB + row * BK + ce);
      }
#pragma unroll
      for (int m = 0; m < 2; ++m)
#pragma unroll
        for (int n = 0; n < 4; ++n)
          acc[m][n] = MFMA16(af[m], bfr[n], acc[m][n]);
    }
    __syncthreads();
  }

#pragma unroll
  for (int m = 0; m < 2; ++m)
#pragma unroll
    for (int n = 0; n < 4; ++n) {
      const int col = colbase + n * 16 + lr;
#pragma unroll
      for (int i = 0; i < 4; ++i) {
        const int row = rowbase + w * 32 + m * 16 + lk * 4 + i;
        if (col < QL)       q_out[(size_t)row * QL + col] = acc[m][n][i];
        else if (col < N)   ckv_out[(size_t)row * CKV_N + (col - QL)] = acc[m][n][i];
      }
    }
}

// qb GEMM with fused RoPE + scale, writing qfull [NH][S][96] directly.
__global__ __launch_bounds__(256) void gemm_qb_rope(const bf16* __restrict__ A,
                                                    const bf16* __restrict__ B,
                                                    const float* __restrict__ ropc,
                                                    const float* __restrict__ rops,
                                                    bf16* __restrict__ qfull) {
  constexpr int BM = 128, BN = 128, BK = 64, K = QL, N = QB_N;
  __shared__ __bf16 ldsA[BM * BK];
  __shared__ __bf16 ldsB[BN * BK];
  const int t = threadIdx.x;
  const int l = t & 63, w = t >> 6;
  const int lr = l & 15, lk = l >> 4;
  const int wr = w >> 1, wc = w & 1;
  const int rowbase = blockIdx.y * BM;
  const int colbase = blockIdx.x * BN;
  const float scale = 0.14724444f; // 96^-0.5 * log2(e)

  f32x4 acc[4][4];
#pragma unroll
  for (int m = 0; m < 4; ++m)
#pragma unroll
    for (int n = 0; n < 4; ++n) acc[m][n] = f32x4{0.f, 0.f, 0.f, 0.f};

  for (int kt = 0; kt < K / BK; ++kt) {
    const int kb = kt * BK;
#pragma unroll
    for (int it = 0; it < 4; ++it) {
      const int r  = it * 32 + w * 8 + (l >> 3);
      const int c8 = ((l & 7) * 8) ^ ((r & 7) << 3);
      const bf16* ga = A + (size_t)(rowbase + r) * K + kb + c8;
      __builtin_amdgcn_global_load_lds((const __attribute__((address_space(1))) void*)ga,
          (__attribute__((address_space(3))) void*)(ldsA + it * 2048 + w * 512), 16, 0, 0);
      const bf16* gb = B + (size_t)(colbase + r) * K + kb + c8;
      __builtin_amdgcn_global_load_lds((const __attribute__((address_space(1))) void*)gb,
          (__attribute__((address_space(3))) void*)(ldsB + it * 2048 + w * 512), 16, 0, 0);
    }
    __syncthreads();
#pragma unroll
    for (int kk = 0; kk < 2; ++kk) {
      bf16x8 af[4], bfr[4];
#pragma unroll
      for (int m = 0; m < 4; ++m) {
        const int row = wr * 64 + m * 16 + lr;
        const int ce  = (kk * 32 + lk * 8) ^ ((row & 7) << 3);
        af[m] = *(const bf16x8*)(ldsA + row * BK + ce);
      }
#pragma unroll
      for (int n = 0; n < 4; ++n) {
        const int row = wc * 64 + n * 16 + lr;
        const int ce  = (kk * 32 + lk * 8) ^ ((row & 7) << 3);
        bfr[n] = *(const bf16x8*)(ldsB + row * BK + ce);
      }
#pragma unroll
      for (int m = 0; m < 4; ++m)
#pragma unroll
        for (int n = 0; n < 4; ++n)
          acc[m][n] = MFMA16(af[m], bfr[n], acc[m][n]);
    }
    __syncthreads();
  }

#pragma unroll
  for (int m = 0; m < 4; ++m) {
    const int rowtop = rowbase + wr * 64 + m * 16 + lk * 4;
#pragma unroll
    for (int n = 0; n < 4; ++n) {
      const int c0 = colbase + wc * 64 + n * 16; // frag base col
      const int h  = c0 / 96;
      const int d0 = c0 - h * 96;
      const size_t qb_ = ((size_t)h * S_LEN + rowtop) * QHD + d0 + lr;
      if (d0 < ND) {
#pragma unroll
        for (int i = 0; i < 4; ++i)
          qfull[qb_ + (size_t)i * QHD] = __float2bfloat16(acc[m][n][i] * scale);
      } else if (d0 == ND) { // rope-lo: out = x0*c - x1*s, x1 = acc[m][n+1]
#pragma unroll
        for (int i = 0; i < 4; ++i) {
          const float c = ropc[(rowtop + i) * 16 + lr];
          const float s = rops[(rowtop + i) * 16 + lr];
          const float x0 = acc[m][n][i], x1 = acc[m][n + 1][i];
          qfull[qb_ + (size_t)i * QHD] = __float2bfloat16((x0 * c - x1 * s) * scale);
        }
      } else { // d0 == 80, rope-hi: out = x1*c + x0*s, x0 = acc[m][n-1]
#pragma unroll
        for (int i = 0; i < 4; ++i) {
          const float c = ropc[(rowtop + i) * 16 + lr];
          const float s = rops[(rowtop + i) * 16 + lr];
          const float x1 = acc[m][n][i], x0 = acc[m][n - 1][i];
          qfull[qb_ + (size_t)i * QHD] = __float2bfloat16((x1 * c + x0 * s) * scale);
        }
      }
    }
  }
}

// kvb GEMM writing knope [NH][S][64] and vt [NH][64][S] directly.
__global__ __launch_bounds__(256) void gemm_kvb_split(const bf16* __restrict__ A,
                                                      const bf16* __restrict__ B,
                                                      bf16* __restrict__ knope,
                                                      bf16* __restrict__ vt) {
  constexpr int BM = 128, BN = 128, BK = 64, K = KVL;
  __shared__ __bf16 ldsA[BM * BK];
  __shared__ __bf16 ldsB[BN * BK];
  const int t = threadIdx.x;
  const int l = t & 63, w = t >> 6;
  const int lr = l & 15, lk = l >> 4;
  const int wr = w >> 1, wc = w & 1;
  const int rowbase = blockIdx.y * BM;
  const int h = blockIdx.x; // head == col tile
  const int colbase = h * BN;

  f32x4 acc[4][4];
#pragma unroll
  for (int m = 0; m < 4; ++m)
#pragma unroll
    for (int n = 0; n < 4; ++n) acc[m][n] = f32x4{0.f, 0.f, 0.f, 0.f};

  for (int kt = 0; kt < K / BK; ++kt) {
    const int kb = kt * BK;
#pragma unroll
    for (int it = 0; it < 4; ++it) {
      const int r  = it * 32 + w * 8 + (l >> 3);
      const int c8 = ((l & 7) * 8) ^ ((r & 7) << 3);
      const bf16* ga = A + (size_t)(rowbase + r) * K + kb + c8;
      __builtin_amdgcn_global_load_lds((const __attribute__((address_space(1))) void*)ga,
          (__attribute__((address_space(3))) void*)(ldsA + it * 2048 + w * 512), 16, 0, 0);
      const bf16* gb = B + (size_t)(colbase + r) * K + kb + c8;
      __builtin_amdgcn_global_load_lds((const __attribute__((address_space(1))) void*)gb,
          (__attribute__((address_space(3))) void*)(ldsB + it * 2048 + w * 512), 16, 0, 0);
    }
    __syncthreads();
#pragma unroll
    for (int kk = 0; kk < 2; ++kk) {
      bf16x8 af[4], bfr[4];
#pragma unroll
      for (int m = 0; m < 4; ++m) {
        const int row = wr * 64 + m * 16 + lr;
        const int ce  = (kk * 32 + lk * 8) ^ ((row & 7) << 3);
        af[m] = *(const bf16x8*)(ldsA + row * BK + ce);
      }
#pragma unroll
      for (int n = 0; n < 4; ++n) {
        const int row = wc * 64 + n * 16 + lr;
        const int ce  = (kk * 32 + lk * 8) ^ ((row & 7) << 3);
        bfr[n] = *(const bf16x8*)(ldsB + row * BK + ce);
      }
#pragma unroll
      for (int m = 0; m < 4; ++m)
#pragma unroll
        for (int n = 0; n < 4; ++n)
          acc[m][n] = MFMA16(af[m], bfr[n], acc[m][n]);
    }
    __syncthreads();
  }

#pragma unroll
  for (int m = 0; m < 4; ++m) {
    const int rowtop = rowbase + wr * 64 + m * 16 + lk * 4;
    if (wc == 0) { // k_nope -> knope[h][s][64]
#pragma unroll
      for (int n = 0; n < 4; ++n) {
        const int d = n * 16 + lr;
#pragma unroll
        for (int i = 0; i < 4; ++i)
          knope[((size_t)h * S_LEN + rowtop + i) * ND + d] = __float2bfloat16(acc[m][n][i]);
      }
    } else {        // V -> vt[h][64][S] (8B transposed stores, L2 merges)
#pragma unroll
      for (int n = 0; n < 4; ++n) {
        const int d = n * 16 + lr;
        bf16x4 pk;
#pragma unroll
        for (int i = 0; i < 4; ++i) pk[i] = (__bf16)acc[m][n][i];
        *(bf16x4*)(vt + ((size_t)h * VD + d) * S_LEN + rowtop) = pk;
      }
    }
  }
}

// ---------------- norms / prep ----------------

__global__ void rmsnorm_rows(const float* __restrict__ in, const float* __restrict__ w,
                             bf16* __restrict__ out, int C) {
  const int r = blockIdx.x;
  const float* row = in + (size_t)r * C;
  float ss = 0.f;
  for (int c = threadIdx.x; c < C; c += 256) { float v = row[c]; ss += v * v; }
#pragma unroll
  for (int d = 32; d > 0; d >>= 1) ss += __shfl_xor(ss, d);
  __shared__ float red[4];
  if ((threadIdx.x & 63) == 0) red[threadIdx.x >> 6] = ss;
  __syncthreads();
  const float tot = red[0] + red[1] + red[2] + red[3];
  const float rs = rsqrtf(tot / (float)C + 1e-6f);
  for (int c = threadIdx.x; c < C; c += 256)
    out[(size_t)r * C + c] = __float2bfloat16(row[c] * rs * w[c]);
}

// per row: rmsnorm(ckv[0:256]) -> bf16 ; rope(k_pe) -> bf16 ; rope tables
__global__ void kv_prep(const float* __restrict__ ckv, const float* __restrict__ w,
                        const int* __restrict__ pos, bf16* __restrict__ ckv_bf,
                        bf16* __restrict__ kpe, float* __restrict__ ropc,
                        float* __restrict__ rops) {
  const int s = blockIdx.x, t = threadIdx.x; // 64 threads
  const float* row = ckv + (size_t)s * CKV_N;
  float v[4]; float ss = 0.f;
#pragma unroll
  for (int j = 0; j < 4; ++j) { v[j] = row[t + 64 * j]; ss += v[j] * v[j]; }
#pragma unroll
  for (int d = 32; d > 0; d >>= 1) ss += __shfl_xor(ss, d);
  const float rs = rsqrtf(ss / (float)KVL + 1e-6f);
#pragma unroll
  for (int j = 0; j < 4; ++j)
    ckv_bf[(size_t)s * KVL + t + 64 * j] = __float2bfloat16(v[j] * rs * w[t + 64 * j]);
  if (t < 16) {
    const float x0 = row[KVL + t], x1 = row[KVL + 16 + t];
    const float p = (float)get_pos(pos, s);
    const float invf = exp2f(-(float)t * (13.2877124f / 16.f)); // 10000^(-t/16)
    const float ang = p * invf, c = cosf(ang), sn = sinf(ang);
    ropc[s * 16 + t] = c;
    rops[s * 16 + t] = sn;
    kpe[(size_t)s * RD + t]      = __float2bfloat16(x0 * c - x1 * sn);
    kpe[(size_t)s * RD + 16 + t] = __float2bfloat16(x1 * c + x0 * sn);
  }
}

// ---------------- causal flash attention ----------------
// One wave per block, 32 q rows, KVBLK=64, K prefetch, swapped QK^T
// (st = mfma(K,Q) -> S^T: lane-local row reduce + 2 shfl), log2-domain
// softmax, defer-rescale, XOR-swizzled P tile, row-sum l via MFMA with a
// ones B-frag (l lands in the SAME C-layout as O -> no shfl broadcasts).
// 2-WAY SPLIT-K for heavy q-tiles (j>=32): two independent waves cover
// [0,nA) and [nA,ktiles) k-tiles; partials (unnorm O, m, l) -> scratch,
// merged by attn_combine. Every wave does <= 17 k-tiles (flat makespan).
// Grid: flat 3840 blocks; B-halves dispatched first; h = i%40 keeps
// head->XCD affinity (40 % 8 == 0).
__global__ __launch_bounds__(64) void attn_kernel(const bf16* __restrict__ qfull,
                                                  const bf16* __restrict__ knope,
                                                  const bf16* __restrict__ kpe,
                                                  const bf16* __restrict__ vt,
                                                  bf16* __restrict__ ctx,
                                                  float* __restrict__ osc,
                                                  float* __restrict__ msc,
                                                  float* __restrict__ lsc) {
  const int i = blockIdx.x;
  int h, j; bool isB;
  if (i < 1280) { h = i % 40; j = 63 - i / 40; isB = true; }          // B-halves (j>=32)
  else { const int i2 = i - 1280; h = i2 % 40; j = 63 - i2 / 40; isB = false; }
  const int ktiles = j / 2 + 1;
  const bool split = (j >= 32);
  const int nA = (ktiles + 1) >> 1;
  const int kt0 = (split && isB) ? nA : 0;
  const int kt1 = (split && !isB) ? nA : ktiles;
  const int kb0 = kt0 * 64;
  const int kbLast = (kt1 - 1) * 64;
  const int lastkb = (ktiles - 1) * 64; // causal-diag tile base
  const int qw = j * 32;
  const int l = threadIdx.x, lr = l & 15, lk = l >> 4;
  const bf16* Q  = qfull + (size_t)h * S_LEN * QHD;
  const bf16* Kn = knope + (size_t)h * S_LEN * ND;
  const bf16* V  = vt + (size_t)h * VD * S_LEN;
  __shared__ __bf16 plds[32][64]; // XOR-swizzled: col ^= (lr&7)<<3

  bf16x8 qf[2][3];
#pragma unroll
  for (int qg = 0; qg < 2; ++qg)
#pragma unroll
    for (int ks = 0; ks < 3; ++ks)
      qf[qg][ks] = *(const bf16x8*)(Q + (size_t)(qw + qg * 16 + lr) * QHD + ks * 32 + lk * 8);

  bf16x8 ones;
#pragma unroll
  for (int c = 0; c < 8; ++c) ones[c] = (__bf16)1.0f;

  f32x4 o[2][4], lac[2];
  float mrow[2];
#pragma unroll
  for (int qg = 0; qg < 2; ++qg) {
#pragma unroll
    for (int dt = 0; dt < 4; ++dt) o[qg][dt] = f32x4{0.f, 0.f, 0.f, 0.f};
    lac[qg] = f32x4{0.f, 0.f, 0.f, 0.f};
    mrow[qg] = -1e30f;
  }

  // preload first K tile
  bf16x8 kf[4][3];
#pragma unroll
  for (int sub = 0; sub < 4; ++sub) {
#pragma unroll
    for (int ks = 0; ks < 2; ++ks)
      kf[sub][ks] = *(const bf16x8*)(Kn + (size_t)(kb0 + sub * 16 + lr) * ND + ks * 32 + lk * 8);
    kf[sub][2] = *(const bf16x8*)(kpe + (size_t)(kb0 + sub * 16 + lr) * RD + lk * 8);
  }

  for (int kb = kb0;; kb += 64) {
    // st[qg][sub][i] = S[q=qw+qg*16+lr][k=kb+sub*16+lk*4+i] (log2 domain)
    f32x4 st[2][4];
#pragma unroll
    for (int qg = 0; qg < 2; ++qg)
#pragma unroll
      for (int sub = 0; sub < 4; ++sub) st[qg][sub] = f32x4{0.f, 0.f, 0.f, 0.f};
#pragma unroll
    for (int qg = 0; qg < 2; ++qg)
#pragma unroll
      for (int sub = 0; sub < 4; ++sub)
#pragma unroll
        for (int ks = 0; ks < 3; ++ks)
          st[qg][sub] = MFMA16(kf[sub][ks], qf[qg][ks], st[qg][sub]);

    // prefetch next K tile (hidden under softmax+PV)
    const int nkb = kb + 64;
    if (nkb <= kbLast) {
#pragma unroll
      for (int sub = 0; sub < 4; ++sub) {
#pragma unroll
        for (int ks = 0; ks < 2; ++ks)
          kf[sub][ks] = *(const bf16x8*)(Kn + (size_t)(nkb + sub * 16 + lr) * ND + ks * 32 + lk * 8);
        kf[sub][2] = *(const bf16x8*)(kpe + (size_t)(nkb + sub * 16 + lr) * RD + lk * 8);
      }
    }

    if (kb == lastkb) { // causal mask, only on the diag tile
#pragma unroll
      for (int qg = 0; qg < 2; ++qg) {
        const int q = qw + qg * 16 + lr;
#pragma unroll
        for (int sub = 0; sub < 4; ++sub)
#pragma unroll
          for (int ii = 0; ii < 4; ++ii)
            if (kb + sub * 16 + lk * 4 + ii > q) st[qg][sub][ii] = -1e30f;
      }
    }

    float tm[2];
#pragma unroll
    for (int qg = 0; qg < 2; ++qg) {
      float m0 = -1e30f;
#pragma unroll
      for (int sub = 0; sub < 4; ++sub)
#pragma unroll
        for (int ii = 0; ii < 4; ++ii) m0 = fmaxf(m0, st[qg][sub][ii]);
      m0 = fmaxf(m0, __shfl_xor(m0, 16));
      m0 = fmaxf(m0, __shfl_xor(m0, 32));
      tm[qg] = m0;
    }

    const bool noresc = __all((tm[0] <= mrow[0] + 8.f) && (tm[1] <= mrow[1] + 8.f));
    float mnew[2];
#pragma unroll
    for (int qg = 0; qg < 2; ++qg) {
      mnew[qg] = noresc ? mrow[qg] : fmaxf(mrow[qg], tm[qg]);
#pragma unroll
      for (int sub = 0; sub < 4; ++sub) {
        bf16x4 pk;
#pragma unroll
        for (int ii = 0; ii < 4; ++ii)
          pk[ii] = (__bf16)exp2f(st[qg][sub][ii] - mnew[qg]);
        const int swc = (sub * 16 + lk * 4) ^ ((lr & 7) << 3);
        *(bf16x4*)(&plds[qg * 16 + lr][swc]) = pk;
      }
    }
    if (!noresc) {
#pragma unroll
      for (int qg = 0; qg < 2; ++qg) {
        const float fac = exp2f(mrow[qg] - mnew[qg]);
        mrow[qg] = mnew[qg];
#pragma unroll
        for (int ii = 0; ii < 4; ++ii) {
          const float fr = __shfl(fac, lk * 4 + ii);
#pragma unroll
          for (int dt = 0; dt < 4; ++dt) o[qg][dt][ii] *= fr;
          lac[qg][ii] *= fr;
        }
      }
    }

    // PV + row-sum l via ones-MFMA (A = P from LDS, B = V^T rows / ones)
#pragma unroll
    for (int h2 = 0; h2 < 2; ++h2) {
      const int swc = (h2 * 32 + lk * 8) ^ ((lr & 7) << 3);
      bf16x8 pa0 = *(const bf16x8*)(&plds[lr][swc]);
      bf16x8 pa1 = *(const bf16x8*)(&plds[16 + lr][swc]);
#pragma unroll
      for (int dt = 0; dt < 4; ++dt) {
        bf16x8 vf = *(const bf16x8*)(V + (size_t)(dt * 16 + lr) * S_LEN + kb + h2 * 32 + lk * 8);
        o[0][dt] = MFMA16(pa0, vf, o[0][dt]);
        o[1][dt] = MFMA16(pa1, vf, o[1][dt]);
      }
      lac[0] = MFMA16(pa0, ones, lac[0]);
      lac[1] = MFMA16(pa1, ones, lac[1]);
    }
    if (kb == kbLast) break;
  }

  if (!split) { // normalize and write ctx directly (l in C-layout: no shfl)
#pragma unroll
    for (int qg = 0; qg < 2; ++qg)
#pragma unroll
      for (int ii = 0; ii < 4; ++ii) {
        const float inv = 1.0f / lac[qg][ii];
        const int row = qw + qg * 16 + lk * 4 + ii;
#pragma unroll
        for (int dt = 0; dt < 4; ++dt)
          ctx[(size_t)row * HID + h * VD + dt * 16 + lr] =
              __float2bfloat16(o[qg][dt][ii] * inv);
      }
  } else {      // write unnormalized partials to scratch
    const int sidx = h * 32 + (j - 32);
    const int part = isB ? 1 : 0;
    const int rbase = (sidx * 2 + part) * 32;
    float* ob = osc + (size_t)rbase * 64;
#pragma unroll
    for (int qg = 0; qg < 2; ++qg)
#pragma unroll
      for (int ii = 0; ii < 4; ++ii) {
        const int row = qg * 16 + lk * 4 + ii;
#pragma unroll
        for (int dt = 0; dt < 4; ++dt)
          ob[(size_t)row * 64 + dt * 16 + lr] = o[qg][dt][ii];
        if (lr == 0) lsc[rbase + row] = lac[qg][ii];
      }
    if (lk == 0) {
      msc[rbase + lr]      = mrow[0];
      msc[rbase + 16 + lr] = mrow[1];
    }
  }
}

// merge the two split-K halves for heavy q-tiles (j>=32)
__global__ __launch_bounds__(256) void attn_combine(const float* __restrict__ osc,
                                                    const float* __restrict__ msc,
                                                    const float* __restrict__ lsc,
                                                    bf16* __restrict__ ctx) {
  const int sidx = blockIdx.x;            // 0..1279 = h*32 + (j-32)
  const int h = sidx / 32, j = (sidx & 31) + 32;
  const int t = threadIdx.x;
  const int row = t >> 3, g = t & 7;
  const int ra = sidx * 64 + row, rb = ra + 32;
  const float mA = msc[ra], mB = msc[rb];
  const float lA = lsc[ra], lB = lsc[rb];
  const float M = fmaxf(mA, mB);
  const float wA = exp2f(mA - M), wB = exp2f(mB - M);
  const float inv = 1.0f / (wA * lA + wB * lB);
  const float* oA = osc + (size_t)ra * 64 + g * 8;
  const float* oB = osc + (size_t)rb * 64 + g * 8;
  bf16* dst = ctx + (size_t)(j * 32 + row) * HID + h * VD + g * 8;
#pragma unroll
  for (int c = 0; c < 8; ++c)
    dst[c] = __float2bfloat16((wA * oA[c] + wB * oB[c]) * inv);
}

// ---------------- launch ----------------

extern "C" void kernel_launch(void* const* d_in, const int* in_sizes, int n_in,
                              void* d_out, int out_size, void* d_ws, size_t ws_size,
                              hipStream_t stream) {
  const float* hidden = (const float*)d_in[0];
  const int*   pos    = (const int*)d_in[1];
  const float* w_qa   = (const float*)d_in[2];
  const float* q_ln   = (const float*)d_in[3];
  const float* w_qb   = (const float*)d_in[4];
  const float* w_kva  = (const float*)d_in[5];
  const float* kv_ln  = (const float*)d_in[6];
  const float* w_kvb  = (const float*)d_in[7];
  const float* w_o    = (const float*)d_in[8];
  float* out = (float*)d_out;
  char* ws = (char*)d_ws;
  (void)in_sizes; (void)n_in; (void)out_size; (void)ws_size;

  size_t off = 0;
  auto take = [&](size_t bytes) -> char* {
    char* p = ws + off;
    off = (off + bytes + 255) & ~(size_t)255;
    return p;
  };
  bf16*  hid_bf = (bf16*)take((size_t)S_LEN * HID * 2);
  bf16*  wabT   = (bf16*)take((size_t)AB_N * HID * 2);   // wqaT | wkvaT
  bf16*  wqbT   = (bf16*)take((size_t)QB_N * QL * 2);
  bf16*  wkvbT  = (bf16*)take((size_t)KVB_N * KVL * 2);
  bf16*  woT    = (bf16*)take((size_t)HID * HID * 2);
  float* qlora  = (float*)take((size_t)S_LEN * QL * 4);
  bf16*  qa_bf  = (bf16*)take((size_t)S_LEN * QL * 2);
  bf16*  qfull  = (bf16*)take((size_t)NH * S_LEN * QHD * 2);
  float* ckv    = (float*)take((size_t)S_LEN * CKV_N * 4);
  bf16*  ckv_bf = (bf16*)take((size_t)S_LEN * KVL * 2);
  bf16*  kpe    = (bf16*)take((size_t)S_LEN * RD * 2);
  float* ropc   = (float*)take((size_t)S_LEN * 16 * 4);
  float* rops   = (float*)take((size_t)S_LEN * 16 * 4);
  bf16*  knope  = (bf16*)take((size_t)NH * S_LEN * ND * 2);
  bf16*  vt     = (bf16*)take((size_t)NH * VD * S_LEN * 2);
  bf16*  ctx    = (bf16*)take((size_t)S_LEN * HID * 2);
  float* osc    = (float*)take((size_t)1280 * 2 * 32 * 64 * 4);  // 21 MB
  float* msc    = (float*)take((size_t)1280 * 2 * 32 * 4);
  float* lsc    = (float*)take((size_t)1280 * 2 * 32 * 4);

  const dim3 tb(32, 8);
  cast_f32_bf16<<<(S_LEN * HID / 4 + 255) / 256, 256, 0, stream>>>(hidden, hid_bf, S_LEN * HID / 4);
  transpose_cast<<<dim3((QL + 31) / 32, (HID + 31) / 32), tb, 0, stream>>>(w_qa, wabT, HID, QL);
  transpose_cast<<<dim3((CKV_N + 31) / 32, (HID + 31) / 32), tb, 0, stream>>>(w_kva, wabT + (size_t)QL * HID, HID, CKV_N);
  transpose_cast<<<dim3((QB_N + 31) / 32, (QL + 31) / 32), tb, 0, stream>>>(w_qb, wqbT, QL, QB_N);
  transpose_cast<<<dim3((KVB_N + 31) / 32, (KVL + 31) / 32), tb, 0, stream>>>(w_kvb, wkvbT, KVL, KVB_N);
  transpose_cast<<<dim3((HID + 31) / 32, (HID + 31) / 32), tb, 0, stream>>>(w_o, woT, HID, HID);

  // fused qa|kva GEMM
  gemm_qakva<<<dim3((AB_N + 63) / 64, S_LEN / 128), 256, 0, stream>>>(hid_bf, wabT, qlora, ckv);

  // kv prep (also builds rope tables for q path)
  kv_prep<<<S_LEN, 64, 0, stream>>>(ckv, kv_ln, pos, ckv_bf, kpe, ropc, rops);

  // q path: rmsnorm -> qb GEMM with fused rope -> qfull
  rmsnorm_rows<<<S_LEN, 256, 0, stream>>>(qlora, q_ln, qa_bf, QL);
  gemm_qb_rope<<<dim3(QB_N / 128, S_LEN / 128), 256, 0, stream>>>(qa_bf, wqbT, ropc, rops, qfull);

  // kv path: kvb GEMM with fused split/transpose -> knope, vt
  gemm_kvb_split<<<dim3(KVB_N / 128, S_LEN / 128), 256, 0, stream>>>(ckv_bf, wkvbT, knope, vt);

  // attention: flat grid, uniform <=17-tile waves (split-K on heavy tiles)
  attn_kernel<<<3840, 64, 0, stream>>>(qfull, knope, kpe, vt, ctx, osc, msc, lsc);
  attn_combine<<<1280, 256, 0, stream>>>(osc, msc, lsc, ctx);

  // output proj
  gemm_bt<false, false><<<dim3(HID / 128, S_LEN / 128), 256, 0, stream>>>(ctx, woT, out, S_LEN, HID, HID);
}

// Round 10
// 250.980 us; speedup vs baseline: 1.4540x; 1.0553x over previous
//
#include <hip/hip_runtime.h>
#include <hip/hip_bf16.h>

typedef __hip_bfloat16 bf16;
typedef __attribute__((ext_vector_type(8))) __bf16 bf16x8;
typedef __attribute__((ext_vector_type(4))) __bf16 bf16x4;
typedef __attribute__((ext_vector_type(4))) float f32x4;

constexpr int S_LEN = 2048;
constexpr int HID   = 2560;
constexpr int NH    = 40;
constexpr int QL    = 768;
constexpr int KVL   = 256;
constexpr int RD    = 32;
constexpr int ND    = 64;
constexpr int VD    = 64;
constexpr int QHD   = 96;                 // NOPE_D + ROPE_D
constexpr int QB_N  = NH * QHD;           // 3840
constexpr int KVB_N = NH * (ND + VD);     // 5120
constexpr int CKV_N = KVL + RD;           // 288
constexpr int AB_N  = QL + CKV_N;         // 1056 (fused qa|kva output cols)

#define MFMA16(a, b, c) __builtin_amdgcn_mfma_f32_16x16x32_bf16((a), (b), (c), 0, 0, 0)

// position_ids may arrive as int32 or int64; values are 0..2047 so sniff layout.
__device__ __forceinline__ int get_pos(const int* pos, int s) {
  bool is64 = (pos[1] == 0 && pos[2] == 1);
  return is64 ? pos[2 * s] : pos[s];
}

// ---------------- prep ----------------

__global__ void cast_f32_bf16(const float* __restrict__ src, bf16* __restrict__ dst, int n4) {
  int i = blockIdx.x * blockDim.x + threadIdx.x;
  if (i >= n4) return;
  float4 v = reinterpret_cast<const float4*>(src)[i];
  struct { bf16 a, b, c, d; } pk;
  pk.a = __float2bfloat16(v.x); pk.b = __float2bfloat16(v.y);
  pk.c = __float2bfloat16(v.z); pk.d = __float2bfloat16(v.w);
  reinterpret_cast<uint2*>(dst)[i] = *reinterpret_cast<uint2*>(&pk);
}

// src [K][N] f32 -> dst [N][K] bf16  (B^T layout for the GEMMs)
__global__ void transpose_cast(const float* __restrict__ src, bf16* __restrict__ dst, int K, int N) {
  __shared__ float tile[32][33];
  int nb = blockIdx.x * 32, kb = blockIdx.y * 32;
  int x = threadIdx.x, y = threadIdx.y; // (32,8)
#pragma unroll
  for (int j = 0; j < 4; ++j) {
    int k = kb + y + j * 8, n = nb + x;
    tile[y + j * 8][x] = (k < K && n < N) ? src[(size_t)k * N + n] : 0.f;
  }
  __syncthreads();
#pragma unroll
  for (int j = 0; j < 4; ++j) {
    int n = nb + y + j * 8, k = kb + x;
    if (n < N && k < K) dst[(size_t)n * K + k] = __float2bfloat16(tile[x][y + j * 8]);
  }
}

// ---------------- GEMMs ----------------

// Fused qa|kva GEMM: C[2048][1056] = hid_bf * wabT^T, BN=64 tiles.
__global__ __launch_bounds__(256) void gemm_qakva(const bf16* __restrict__ A,
                                                  const bf16* __restrict__ B,
                                                  float* __restrict__ q_out,
                                                  float* __restrict__ ckv_out) {
  constexpr int BM = 128, BK = 64, K = HID, N = AB_N;
  __shared__ __bf16 ldsA[BM * BK];
  __shared__ __bf16 ldsB[64 * BK];
  const int t = threadIdx.x;
  const int l = t & 63, w = t >> 6;
  const int lr = l & 15, lk = l >> 4;
  const int rowbase = blockIdx.y * BM;
  const int colbase = blockIdx.x * 64;

  f32x4 acc[2][4];
#pragma unroll
  for (int m = 0; m < 2; ++m)
#pragma unroll
    for (int n = 0; n < 4; ++n) acc[m][n] = f32x4{0.f, 0.f, 0.f, 0.f};

  for (int kt = 0; kt < K / BK; ++kt) {
    const int kb = kt * BK;
#pragma unroll
    for (int it = 0; it < 4; ++it) {
      const int r  = it * 32 + w * 8 + (l >> 3);
      const int c8 = ((l & 7) * 8) ^ ((r & 7) << 3);
      const bf16* ga = A + (size_t)(rowbase + r) * K + kb + c8;
      __builtin_amdgcn_global_load_lds((const __attribute__((address_space(1))) void*)ga,
          (__attribute__((address_space(3))) void*)(ldsA + it * 2048 + w * 512), 16, 0, 0);
      if (it < 2) {
        int nrow = colbase + r;
        nrow = (nrow < N) ? nrow : (N - 1);
        const bf16* gb = B + (size_t)nrow * K + kb + c8;
        __builtin_amdgcn_global_load_lds((const __attribute__((address_space(1))) void*)gb,
            (__attribute__((address_space(3))) void*)(ldsB + it * 2048 + w * 512), 16, 0, 0);
      }
    }
    __syncthreads();
#pragma unroll
    for (int kk = 0; kk < 2; ++kk) {
      bf16x8 af[2], bfr[4];
#pragma unroll
      for (int m = 0; m < 2; ++m) {
        const int row = w * 32 + m * 16 + lr;
        const int ce  = (kk * 32 + lk * 8) ^ ((row & 7) << 3);
        af[m] = *(const bf16x8*)(ldsA + row * BK + ce);
      }
#pragma unroll
      for (int n = 0; n < 4; ++n) {
        const int row = n * 16 + lr;
        const int ce  = (kk * 32 + lk * 8) ^ ((row & 7) << 3);
        bfr[n] = *(const bf16x8*)(ldsB + row * BK + ce);
      }
#pragma unroll
      for (int m = 0; m < 2; ++m)
#pragma unroll
        for (int n = 0; n < 4; ++n)
          acc[m][n] = MFMA16(af[m], bfr[n], acc[m][n]);
    }
    __syncthreads();
  }

#pragma unroll
  for (int m = 0; m < 2; ++m)
#pragma unroll
    for (int n = 0; n < 4; ++n) {
      const int col = colbase + n * 16 + lr;
#pragma unroll
      for (int i = 0; i < 4; ++i) {
        const int row = rowbase + w * 32 + m * 16 + lk * 4 + i;
        if (col < QL)       q_out[(size_t)row * QL + col] = acc[m][n][i];
        else if (col < N)   ckv_out[(size_t)row * CKV_N + (col - QL)] = acc[m][n][i];
      }
    }
}

// Output projection: out[2048][2560] = ctx * woT^T, BM=128 x BN=64 tiles
// (640 blocks -> ~2.5 blocks/CU; the 128x128 version had only 320 = 1.25/CU
// and was occupancy-starved). Same skeleton as gemm_qakva, f32 out.
__global__ __launch_bounds__(256) void gemm_out64(const bf16* __restrict__ A,
                                                  const bf16* __restrict__ B,
                                                  float* __restrict__ C) {
  constexpr int BM = 128, BK = 64, K = HID, N = HID;
  __shared__ __bf16 ldsA[BM * BK];
  __shared__ __bf16 ldsB[64 * BK];
  const int t = threadIdx.x;
  const int l = t & 63, w = t >> 6;
  const int lr = l & 15, lk = l >> 4;
  const int rowbase = blockIdx.y * BM;
  const int colbase = blockIdx.x * 64;

  f32x4 acc[2][4];
#pragma unroll
  for (int m = 0; m < 2; ++m)
#pragma unroll
    for (int n = 0; n < 4; ++n) acc[m][n] = f32x4{0.f, 0.f, 0.f, 0.f};

  for (int kt = 0; kt < K / BK; ++kt) {
    const int kb = kt * BK;
#pragma unroll
    for (int it = 0; it < 4; ++it) {
      const int r  = it * 32 + w * 8 + (l >> 3);
      const int c8 = ((l & 7) * 8) ^ ((r & 7) << 3);
      const bf16* ga = A + (size_t)(rowbase + r) * K + kb + c8;
      __builtin_amdgcn_global_load_lds((const __attribute__((address_space(1))) void*)ga,
          (__attribute__((address_space(3))) void*)(ldsA + it * 2048 + w * 512), 16, 0, 0);
      if (it < 2) {
        const bf16* gb = B + (size_t)(colbase + r) * K + kb + c8;
        __builtin_amdgcn_global_load_lds((const __attribute__((address_space(1))) void*)gb,
            (__attribute__((address_space(3))) void*)(ldsB + it * 2048 + w * 512), 16, 0, 0);
      }
    }
    __syncthreads();
#pragma unroll
    for (int kk = 0; kk < 2; ++kk) {
      bf16x8 af[2], bfr[4];
#pragma unroll
      for (int m = 0; m < 2; ++m) {
        const int row = w * 32 + m * 16 + lr;
        const int ce  = (kk * 32 + lk * 8) ^ ((row & 7) << 3);
        af[m] = *(const bf16x8*)(ldsA + row * BK + ce);
      }
#pragma unroll
      for (int n = 0; n < 4; ++n) {
        const int row = n * 16 + lr;
        const int ce  = (kk * 32 + lk * 8) ^ ((row & 7) << 3);
        bfr[n] = *(const bf16x8*)(ldsB + row * BK + ce);
      }
#pragma unroll
      for (int m = 0; m < 2; ++m)
#pragma unroll
        for (int n = 0; n < 4; ++n)
          acc[m][n] = MFMA16(af[m], bfr[n], acc[m][n]);
    }
    __syncthreads();
  }

#pragma unroll
  for (int m = 0; m < 2; ++m)
#pragma unroll
    for (int n = 0; n < 4; ++n) {
      const int col = colbase + n * 16 + lr;
#pragma unroll
      for (int i = 0; i < 4; ++i) {
        const int row = rowbase + w * 32 + m * 16 + lk * 4 + i;
        C[(size_t)row * N + col] = acc[m][n][i];
      }
    }
}

// qb GEMM with fused RoPE + scale, writing qfull [NH][S][96] directly.
__global__ __launch_bounds__(256) void gemm_qb_rope(const bf16* __restrict__ A,
                                                    const bf16* __restrict__ B,
                                                    const float* __restrict__ ropc,
                                                    const float* __restrict__ rops,
                                                    bf16* __restrict__ qfull) {
  constexpr int BM = 128, BN = 128, BK = 64, K = QL, N = QB_N;
  __shared__ __bf16 ldsA[BM * BK];
  __shared__ __bf16 ldsB[BN * BK];
  const int t = threadIdx.x;
  const int l = t & 63, w = t >> 6;
  const int lr = l & 15, lk = l >> 4;
  const int wr = w >> 1, wc = w & 1;
  const int rowbase = blockIdx.y * BM;
  const int colbase = blockIdx.x * BN;
  const float scale = 0.14724444f; // 96^-0.5 * log2(e)

  f32x4 acc[4][4];
#pragma unroll
  for (int m = 0; m < 4; ++m)
#pragma unroll
    for (int n = 0; n < 4; ++n) acc[m][n] = f32x4{0.f, 0.f, 0.f, 0.f};

  for (int kt = 0; kt < K / BK; ++kt) {
    const int kb = kt * BK;
#pragma unroll
    for (int it = 0; it < 4; ++it) {
      const int r  = it * 32 + w * 8 + (l >> 3);
      const int c8 = ((l & 7) * 8) ^ ((r & 7) << 3);
      const bf16* ga = A + (size_t)(rowbase + r) * K + kb + c8;
      __builtin_amdgcn_global_load_lds((const __attribute__((address_space(1))) void*)ga,
          (__attribute__((address_space(3))) void*)(ldsA + it * 2048 + w * 512), 16, 0, 0);
      const bf16* gb = B + (size_t)(colbase + r) * K + kb + c8;
      __builtin_amdgcn_global_load_lds((const __attribute__((address_space(1))) void*)gb,
          (__attribute__((address_space(3))) void*)(ldsB + it * 2048 + w * 512), 16, 0, 0);
    }
    __syncthreads();
#pragma unroll
    for (int kk = 0; kk < 2; ++kk) {
      bf16x8 af[4], bfr[4];
#pragma unroll
      for (int m = 0; m < 4; ++m) {
        const int row = wr * 64 + m * 16 + lr;
        const int ce  = (kk * 32 + lk * 8) ^ ((row & 7) << 3);
        af[m] = *(const bf16x8*)(ldsA + row * BK + ce);
      }
#pragma unroll
      for (int n = 0; n < 4; ++n) {
        const int row = wc * 64 + n * 16 + lr;
        const int ce  = (kk * 32 + lk * 8) ^ ((row & 7) << 3);
        bfr[n] = *(const bf16x8*)(ldsB + row * BK + ce);
      }
#pragma unroll
      for (int m = 0; m < 4; ++m)
#pragma unroll
        for (int n = 0; n < 4; ++n)
          acc[m][n] = MFMA16(af[m], bfr[n], acc[m][n]);
    }
    __syncthreads();
  }

#pragma unroll
  for (int m = 0; m < 4; ++m) {
    const int rowtop = rowbase + wr * 64 + m * 16 + lk * 4;
#pragma unroll
    for (int n = 0; n < 4; ++n) {
      const int c0 = colbase + wc * 64 + n * 16; // frag base col
      const int h  = c0 / 96;
      const int d0 = c0 - h * 96;
      const size_t qb_ = ((size_t)h * S_LEN + rowtop) * QHD + d0 + lr;
      if (d0 < ND) {
#pragma unroll
        for (int i = 0; i < 4; ++i)
          qfull[qb_ + (size_t)i * QHD] = __float2bfloat16(acc[m][n][i] * scale);
      } else if (d0 == ND) { // rope-lo: out = x0*c - x1*s, x1 = acc[m][n+1]
#pragma unroll
        for (int i = 0; i < 4; ++i) {
          const float c = ropc[(rowtop + i) * 16 + lr];
          const float s = rops[(rowtop + i) * 16 + lr];
          const float x0 = acc[m][n][i], x1 = acc[m][n + 1][i];
          qfull[qb_ + (size_t)i * QHD] = __float2bfloat16((x0 * c - x1 * s) * scale);
        }
      } else { // d0 == 80, rope-hi: out = x1*c + x0*s, x0 = acc[m][n-1]
#pragma unroll
        for (int i = 0; i < 4; ++i) {
          const float c = ropc[(rowtop + i) * 16 + lr];
          const float s = rops[(rowtop + i) * 16 + lr];
          const float x1 = acc[m][n][i], x0 = acc[m][n - 1][i];
          qfull[qb_ + (size_t)i * QHD] = __float2bfloat16((x1 * c + x0 * s) * scale);
        }
      }
    }
  }
}

// kvb GEMM writing knope [NH][S][64] and vt [NH][64][S] directly.
__global__ __launch_bounds__(256) void gemm_kvb_split(const bf16* __restrict__ A,
                                                      const bf16* __restrict__ B,
                                                      bf16* __restrict__ knope,
                                                      bf16* __restrict__ vt) {
  constexpr int BM = 128, BN = 128, BK = 64, K = KVL;
  __shared__ __bf16 ldsA[BM * BK];
  __shared__ __bf16 ldsB[BN * BK];
  const int t = threadIdx.x;
  const int l = t & 63, w = t >> 6;
  const int lr = l & 15, lk = l >> 4;
  const int wr = w >> 1, wc = w & 1;
  const int rowbase = blockIdx.y * BM;
  const int h = blockIdx.x; // head == col tile
  const int colbase = h * BN;

  f32x4 acc[4][4];
#pragma unroll
  for (int m = 0; m < 4; ++m)
#pragma unroll
    for (int n = 0; n < 4; ++n) acc[m][n] = f32x4{0.f, 0.f, 0.f, 0.f};

  for (int kt = 0; kt < K / BK; ++kt) {
    const int kb = kt * BK;
#pragma unroll
    for (int it = 0; it < 4; ++it) {
      const int r  = it * 32 + w * 8 + (l >> 3);
      const int c8 = ((l & 7) * 8) ^ ((r & 7) << 3);
      const bf16* ga = A + (size_t)(rowbase + r) * K + kb + c8;
      __builtin_amdgcn_global_load_lds((const __attribute__((address_space(1))) void*)ga,
          (__attribute__((address_space(3))) void*)(ldsA + it * 2048 + w * 512), 16, 0, 0);
      const bf16* gb = B + (size_t)(colbase + r) * K + kb + c8;
      __builtin_amdgcn_global_load_lds((const __attribute__((address_space(1))) void*)gb,
          (__attribute__((address_space(3))) void*)(ldsB + it * 2048 + w * 512), 16, 0, 0);
    }
    __syncthreads();
#pragma unroll
    for (int kk = 0; kk < 2; ++kk) {
      bf16x8 af[4], bfr[4];
#pragma unroll
      for (int m = 0; m < 4; ++m) {
        const int row = wr * 64 + m * 16 + lr;
        const int ce  = (kk * 32 + lk * 8) ^ ((row & 7) << 3);
        af[m] = *(const bf16x8*)(ldsA + row * BK + ce);
      }
#pragma unroll
      for (int n = 0; n < 4; ++n) {
        const int row = wc * 64 + n * 16 + lr;
        const int ce  = (kk * 32 + lk * 8) ^ ((row & 7) << 3);
        bfr[n] = *(const bf16x8*)(ldsB + row * BK + ce);
      }
#pragma unroll
      for (int m = 0; m < 4; ++m)
#pragma unroll
        for (int n = 0; n < 4; ++n)
          acc[m][n] = MFMA16(af[m], bfr[n], acc[m][n]);
    }
    __syncthreads();
  }

#pragma unroll
  for (int m = 0; m < 4; ++m) {
    const int rowtop = rowbase + wr * 64 + m * 16 + lk * 4;
    if (wc == 0) { // k_nope -> knope[h][s][64]
#pragma unroll
      for (int n = 0; n < 4; ++n) {
        const int d = n * 16 + lr;
#pragma unroll
        for (int i = 0; i < 4; ++i)
          knope[((size_t)h * S_LEN + rowtop + i) * ND + d] = __float2bfloat16(acc[m][n][i]);
      }
    } else {        // V -> vt[h][64][S] (8B transposed stores, L2 merges)
#pragma unroll
      for (int n = 0; n < 4; ++n) {
        const int d = n * 16 + lr;
        bf16x4 pk;
#pragma unroll
        for (int i = 0; i < 4; ++i) pk[i] = (__bf16)acc[m][n][i];
        *(bf16x4*)(vt + ((size_t)h * VD + d) * S_LEN + rowtop) = pk;
      }
    }
  }
}

// ---------------- norms / prep ----------------

__global__ void rmsnorm_rows(const float* __restrict__ in, const float* __restrict__ w,
                             bf16* __restrict__ out, int C) {
  const int r = blockIdx.x;
  const float* row = in + (size_t)r * C;
  float ss = 0.f;
  for (int c = threadIdx.x; c < C; c += 256) { float v = row[c]; ss += v * v; }
#pragma unroll
  for (int d = 32; d > 0; d >>= 1) ss += __shfl_xor(ss, d);
  __shared__ float red[4];
  if ((threadIdx.x & 63) == 0) red[threadIdx.x >> 6] = ss;
  __syncthreads();
  const float tot = red[0] + red[1] + red[2] + red[3];
  const float rs = rsqrtf(tot / (float)C + 1e-6f);
  for (int c = threadIdx.x; c < C; c += 256)
    out[(size_t)r * C + c] = __float2bfloat16(row[c] * rs * w[c]);
}

// per row: rmsnorm(ckv[0:256]) -> bf16 ; rope(k_pe) -> bf16 ; rope tables
__global__ void kv_prep(const float* __restrict__ ckv, const float* __restrict__ w,
                        const int* __restrict__ pos, bf16* __restrict__ ckv_bf,
                        bf16* __restrict__ kpe, float* __restrict__ ropc,
                        float* __restrict__ rops) {
  const int s = blockIdx.x, t = threadIdx.x; // 64 threads
  const float* row = ckv + (size_t)s * CKV_N;
  float v[4]; float ss = 0.f;
#pragma unroll
  for (int j = 0; j < 4; ++j) { v[j] = row[t + 64 * j]; ss += v[j] * v[j]; }
#pragma unroll
  for (int d = 32; d > 0; d >>= 1) ss += __shfl_xor(ss, d);
  const float rs = rsqrtf(ss / (float)KVL + 1e-6f);
#pragma unroll
  for (int j = 0; j < 4; ++j)
    ckv_bf[(size_t)s * KVL + t + 64 * j] = __float2bfloat16(v[j] * rs * w[t + 64 * j]);
  if (t < 16) {
    const float x0 = row[KVL + t], x1 = row[KVL + 16 + t];
    const float p = (float)get_pos(pos, s);
    const float invf = exp2f(-(float)t * (13.2877124f / 16.f)); // 10000^(-t/16)
    const float ang = p * invf, c = cosf(ang), sn = sinf(ang);
    ropc[s * 16 + t] = c;
    rops[s * 16 + t] = sn;
    kpe[(size_t)s * RD + t]      = __float2bfloat16(x0 * c - x1 * sn);
    kpe[(size_t)s * RD + 16 + t] = __float2bfloat16(x1 * c + x0 * sn);
  }
}

// ---------------- causal flash attention ----------------
// One wave per block, 32 q rows, KVBLK=64, K prefetch, swapped QK^T
// (st = mfma(K,Q) -> S^T: lane-local row reduce + 2 shfl), log2-domain
// softmax, defer-rescale, XOR-swizzled P tile, row-sum l via ones-MFMA
// (l lands in the same C-layout as O -> no shfl broadcasts in epilogue).
// K split: knope[h][s][64] + head-shared kpe[s][32] (L1-hot).
// Grid (NH, 64), q-tiles REVERSED (heavy first -> LPT); h = blockIdx.x
// keeps per-head XCD affinity (flat%8 == h%8 since NH%8 == 0).
__global__ __launch_bounds__(64) void attn_kernel(const bf16* __restrict__ qfull,
                                                  const bf16* __restrict__ knope,
                                                  const bf16* __restrict__ kpe,
                                                  const bf16* __restrict__ vt,
                                                  bf16* __restrict__ ctx) {
  const int h = blockIdx.x;
  const int qw = ((int)gridDim.y - 1 - (int)blockIdx.y) * 32;
  const int l = threadIdx.x;
  const int lr = l & 15, lk = l >> 4;
  const int lastkb = (qw >> 6) << 6;
  const bf16* Q  = qfull + (size_t)h * S_LEN * QHD;
  const bf16* Kn = knope + (size_t)h * S_LEN * ND;
  const bf16* V  = vt + (size_t)h * VD * S_LEN;
  __shared__ __bf16 plds[32][64]; // XOR-swizzled: col ^= (lr&7)<<3

  bf16x8 qf[2][3];
#pragma unroll
  for (int qg = 0; qg < 2; ++qg)
#pragma unroll
    for (int ks = 0; ks < 3; ++ks)
      qf[qg][ks] = *(const bf16x8*)(Q + (size_t)(qw + qg * 16 + lr) * QHD + ks * 32 + lk * 8);

  bf16x8 ones;
#pragma unroll
  for (int c = 0; c < 8; ++c) ones[c] = (__bf16)1.0f;

  f32x4 o[2][4], lac[2];
  float mrow[2];
#pragma unroll
  for (int qg = 0; qg < 2; ++qg) {
#pragma unroll
    for (int dt = 0; dt < 4; ++dt) o[qg][dt] = f32x4{0.f, 0.f, 0.f, 0.f};
    lac[qg] = f32x4{0.f, 0.f, 0.f, 0.f};
    mrow[qg] = -1e30f;
  }

  // preload K tile 0
  bf16x8 kf[4][3];
#pragma unroll
  for (int sub = 0; sub < 4; ++sub) {
#pragma unroll
    for (int ks = 0; ks < 2; ++ks)
      kf[sub][ks] = *(const bf16x8*)(Kn + (size_t)(sub * 16 + lr) * ND + ks * 32 + lk * 8);
    kf[sub][2] = *(const bf16x8*)(kpe + (size_t)(sub * 16 + lr) * RD + lk * 8);
  }

  for (int kb = 0;; kb += 64) {
    // st[qg][sub][i] = S[q=qw+qg*16+lr][k=kb+sub*16+lk*4+i] (log2 domain)
    f32x4 st[2][4];
#pragma unroll
    for (int qg = 0; qg < 2; ++qg)
#pragma unroll
      for (int sub = 0; sub < 4; ++sub) st[qg][sub] = f32x4{0.f, 0.f, 0.f, 0.f};
#pragma unroll
    for (int qg = 0; qg < 2; ++qg)
#pragma unroll
      for (int sub = 0; sub < 4; ++sub)
#pragma unroll
        for (int ks = 0; ks < 3; ++ks)
          st[qg][sub] = MFMA16(kf[sub][ks], qf[qg][ks], st[qg][sub]);

    // prefetch next K tile (hidden under softmax+PV)
    const int nkb = kb + 64;
    if (nkb <= lastkb) {
#pragma unroll
      for (int sub = 0; sub < 4; ++sub) {
#pragma unroll
        for (int ks = 0; ks < 2; ++ks)
          kf[sub][ks] = *(const bf16x8*)(Kn + (size_t)(nkb + sub * 16 + lr) * ND + ks * 32 + lk * 8);
        kf[sub][2] = *(const bf16x8*)(kpe + (size_t)(nkb + sub * 16 + lr) * RD + lk * 8);
      }
    }

    if (kb == lastkb) { // causal mask, only on the diag tile
#pragma unroll
      for (int qg = 0; qg < 2; ++qg) {
        const int q = qw + qg * 16 + lr;
#pragma unroll
        for (int sub = 0; sub < 4; ++sub)
#pragma unroll
          for (int ii = 0; ii < 4; ++ii)
            if (kb + sub * 16 + lk * 4 + ii > q) st[qg][sub][ii] = -1e30f;
      }
    }

    float tm[2];
#pragma unroll
    for (int qg = 0; qg < 2; ++qg) {
      float m0 = -1e30f;
#pragma unroll
      for (int sub = 0; sub < 4; ++sub)
#pragma unroll
        for (int ii = 0; ii < 4; ++ii) m0 = fmaxf(m0, st[qg][sub][ii]);
      m0 = fmaxf(m0, __shfl_xor(m0, 16));
      m0 = fmaxf(m0, __shfl_xor(m0, 32));
      tm[qg] = m0;
    }

    const bool noresc = __all((tm[0] <= mrow[0] + 8.f) && (tm[1] <= mrow[1] + 8.f));
#pragma unroll
    for (int qg = 0; qg < 2; ++qg) {
      const float mnew = noresc ? mrow[qg] : fmaxf(mrow[qg], tm[qg]);
#pragma unroll
      for (int sub = 0; sub < 4; ++sub) {
        bf16x4 pk;
#pragma unroll
        for (int ii = 0; ii < 4; ++ii)
          pk[ii] = (__bf16)exp2f(st[qg][sub][ii] - mnew);
        const int swc = (sub * 16 + lk * 4) ^ ((lr & 7) << 3);
        *(bf16x4*)(&plds[qg * 16 + lr][swc]) = pk;
      }
      if (!noresc) {
        const float fac = exp2f(mrow[qg] - mnew);
        mrow[qg] = mnew;
#pragma unroll
        for (int ii = 0; ii < 4; ++ii) {
          const float fr = __shfl(fac, lk * 4 + ii);
#pragma unroll
          for (int dt = 0; dt < 4; ++dt) o[qg][dt][ii] *= fr;
          lac[qg][ii] *= fr;
        }
      }
    }

    // PV + row-sum l via ones-MFMA (A = P from LDS, B = V^T rows / ones)
#pragma unroll
    for (int h2 = 0; h2 < 2; ++h2) {
      const int swc = (h2 * 32 + lk * 8) ^ ((lr & 7) << 3);
      bf16x8 pa0 = *(const bf16x8*)(&plds[lr][swc]);
      bf16x8 pa1 = *(const bf16x8*)(&plds[16 + lr][swc]);
#pragma unroll
      for (int dt = 0; dt < 4; ++dt) {
        bf16x8 vf = *(const bf16x8*)(V + (size_t)(dt * 16 + lr) * S_LEN + kb + h2 * 32 + lk * 8);
        o[0][dt] = MFMA16(pa0, vf, o[0][dt]);
        o[1][dt] = MFMA16(pa1, vf, o[1][dt]);
      }
      lac[0] = MFMA16(pa0, ones, lac[0]);
      lac[1] = MFMA16(pa1, ones, lac[1]);
    }
    if (kb == lastkb) break;
  }

  // epilogue: l is in C-layout (same rows as o) -> direct divide, no shfl
#pragma unroll
  for (int qg = 0; qg < 2; ++qg)
#pragma unroll
    for (int ii = 0; ii < 4; ++ii) {
      const float inv = 1.0f / lac[qg][ii];
      const int row = qw + qg * 16 + lk * 4 + ii;
#pragma unroll
      for (int dt = 0; dt < 4; ++dt)
        ctx[(size_t)row * HID + h * VD + dt * 16 + lr] =
            __float2bfloat16(o[qg][dt][ii] * inv);
    }
}

// ---------------- launch ----------------

extern "C" void kernel_launch(void* const* d_in, const int* in_sizes, int n_in,
                              void* d_out, int out_size, void* d_ws, size_t ws_size,
                              hipStream_t stream) {
  const float* hidden = (const float*)d_in[0];
  const int*   pos    = (const int*)d_in[1];
  const float* w_qa   = (const float*)d_in[2];
  const float* q_ln   = (const float*)d_in[3];
  const float* w_qb   = (const float*)d_in[4];
  const float* w_kva  = (const float*)d_in[5];
  const float* kv_ln  = (const float*)d_in[6];
  const float* w_kvb  = (const float*)d_in[7];
  const float* w_o    = (const float*)d_in[8];
  float* out = (float*)d_out;
  char* ws = (char*)d_ws;
  (void)in_sizes; (void)n_in; (void)out_size; (void)ws_size;

  size_t off = 0;
  auto take = [&](size_t bytes) -> char* {
    char* p = ws + off;
    off = (off + bytes + 255) & ~(size_t)255;
    return p;
  };
  bf16*  hid_bf = (bf16*)take((size_t)S_LEN * HID * 2);
  bf16*  wabT   = (bf16*)take((size_t)AB_N * HID * 2);   // wqaT | wkvaT
  bf16*  wqbT   = (bf16*)take((size_t)QB_N * QL * 2);
  bf16*  wkvbT  = (bf16*)take((size_t)KVB_N * KVL * 2);
  bf16*  woT    = (bf16*)take((size_t)HID * HID * 2);
  float* qlora  = (float*)take((size_t)S_LEN * QL * 4);
  bf16*  qa_bf  = (bf16*)take((size_t)S_LEN * QL * 2);
  bf16*  qfull  = (bf16*)take((size_t)NH * S_LEN * QHD * 2);
  float* ckv    = (float*)take((size_t)S_LEN * CKV_N * 4);
  bf16*  ckv_bf = (bf16*)take((size_t)S_LEN * KVL * 2);
  bf16*  kpe    = (bf16*)take((size_t)S_LEN * RD * 2);
  float* ropc   = (float*)take((size_t)S_LEN * 16 * 4);
  float* rops   = (float*)take((size_t)S_LEN * 16 * 4);
  bf16*  knope  = (bf16*)take((size_t)NH * S_LEN * ND * 2);
  bf16*  vt     = (bf16*)take((size_t)NH * VD * S_LEN * 2);
  bf16*  ctx    = (bf16*)take((size_t)S_LEN * HID * 2);

  const dim3 tb(32, 8);
  cast_f32_bf16<<<(S_LEN * HID / 4 + 255) / 256, 256, 0, stream>>>(hidden, hid_bf, S_LEN * HID / 4);
  transpose_cast<<<dim3((QL + 31) / 32, (HID + 31) / 32), tb, 0, stream>>>(w_qa, wabT, HID, QL);
  transpose_cast<<<dim3((CKV_N + 31) / 32, (HID + 31) / 32), tb, 0, stream>>>(w_kva, wabT + (size_t)QL * HID, HID, CKV_N);
  transpose_cast<<<dim3((QB_N + 31) / 32, (QL + 31) / 32), tb, 0, stream>>>(w_qb, wqbT, QL, QB_N);
  transpose_cast<<<dim3((KVB_N + 31) / 32, (KVL + 31) / 32), tb, 0, stream>>>(w_kvb, wkvbT, KVL, KVB_N);
  transpose_cast<<<dim3((HID + 31) / 32, (HID + 31) / 32), tb, 0, stream>>>(w_o, woT, HID, HID);

  // fused qa|kva GEMM
  gemm_qakva<<<dim3((AB_N + 63) / 64, S_LEN / 128), 256, 0, stream>>>(hid_bf, wabT, qlora, ckv);

  // kv prep (also builds rope tables for q path)
  kv_prep<<<S_LEN, 64, 0, stream>>>(ckv, kv_ln, pos, ckv_bf, kpe, ropc, rops);

  // q path: rmsnorm -> qb GEMM with fused rope -> qfull
  rmsnorm_rows<<<S_LEN, 256, 0, stream>>>(qlora, q_ln, qa_bf, QL);
  gemm_qb_rope<<<dim3(QB_N / 128, S_LEN / 128), 256, 0, stream>>>(qa_bf, wqbT, ropc, rops, qfull);

  // kv path: kvb GEMM with fused split/transpose -> knope, vt
  gemm_kvb_split<<<dim3(KVB_N / 128, S_LEN / 128), 256, 0, stream>>>(ckv_bf, wkvbT, knope, vt);

  // attention + output proj (BN=64 tiling: 640 blocks for occupancy)
  attn_kernel<<<dim3(NH, S_LEN / 32), 64, 0, stream>>>(qfull, knope, kpe, vt, ctx);
  gemm_out64<<<dim3(HID / 64, S_LEN / 128), 256, 0, stream>>>(ctx, woT, out);
}

// Round 11
// 241.940 us; speedup vs baseline: 1.5084x; 1.0374x over previous
//
#include <hip/hip_runtime.h>
#include <hip/hip_bf16.h>

typedef __hip_bfloat16 bf16;
typedef __attribute__((ext_vector_type(8))) __bf16 bf16x8;
typedef __attribute__((ext_vector_type(4))) __bf16 bf16x4;
typedef __attribute__((ext_vector_type(4))) float f32x4;

constexpr int S_LEN = 2048;
constexpr int HID   = 2560;
constexpr int NH    = 40;
constexpr int QL    = 768;
constexpr int KVL   = 256;
constexpr int RD    = 32;
constexpr int ND    = 64;
constexpr int VD    = 64;
constexpr int QHD   = 96;                 // NOPE_D + ROPE_D
constexpr int QB_N  = NH * QHD;           // 3840
constexpr int KVB_N = NH * (ND + VD);     // 5120
constexpr int CKV_N = KVL + RD;           // 288
constexpr int AB_N  = QL + CKV_N;         // 1056 (fused qa|kva output cols)

#define MFMA16(a, b, c) __builtin_amdgcn_mfma_f32_16x16x32_bf16((a), (b), (c), 0, 0, 0)

// position_ids may arrive as int32 or int64; values are 0..2047 so sniff layout.
__device__ __forceinline__ int get_pos(const int* pos, int s) {
  bool is64 = (pos[1] == 0 && pos[2] == 1);
  return is64 ? pos[2 * s] : pos[s];
}

// ---------------- prep ----------------

__global__ void cast_f32_bf16(const float* __restrict__ src, bf16* __restrict__ dst, int n4) {
  int i = blockIdx.x * blockDim.x + threadIdx.x;
  if (i >= n4) return;
  float4 v = reinterpret_cast<const float4*>(src)[i];
  struct { bf16 a, b, c, d; } pk;
  pk.a = __float2bfloat16(v.x); pk.b = __float2bfloat16(v.y);
  pk.c = __float2bfloat16(v.z); pk.d = __float2bfloat16(v.w);
  reinterpret_cast<uint2*>(dst)[i] = *reinterpret_cast<uint2*>(&pk);
}

// src [K][N] f32 -> dst [N][K] bf16  (B^T layout for the GEMMs)
__global__ void transpose_cast(const float* __restrict__ src, bf16* __restrict__ dst, int K, int N) {
  __shared__ float tile[32][33];
  int nb = blockIdx.x * 32, kb = blockIdx.y * 32;
  int x = threadIdx.x, y = threadIdx.y; // (32,8)
#pragma unroll
  for (int j = 0; j < 4; ++j) {
    int k = kb + y + j * 8, n = nb + x;
    tile[y + j * 8][x] = (k < K && n < N) ? src[(size_t)k * N + n] : 0.f;
  }
  __syncthreads();
#pragma unroll
  for (int j = 0; j < 4; ++j) {
    int n = nb + y + j * 8, k = kb + x;
    if (n < N && k < K) dst[(size_t)n * K + k] = __float2bfloat16(tile[x][y + j * 8]);
  }
}

// ---------------- GEMMs ----------------

// Fused qa|kva GEMM: C[2048][1056] = hid_bf * wabT^T, BN=64 tiles.
__global__ __launch_bounds__(256) void gemm_qakva(const bf16* __restrict__ A,
                                                  const bf16* __restrict__ B,
                                                  float* __restrict__ q_out,
                                                  float* __restrict__ ckv_out) {
  constexpr int BM = 128, BK = 64, K = HID, N = AB_N;
  __shared__ __bf16 ldsA[BM * BK];
  __shared__ __bf16 ldsB[64 * BK];
  const int t = threadIdx.x;
  const int l = t & 63, w = t >> 6;
  const int lr = l & 15, lk = l >> 4;
  const int rowbase = blockIdx.y * BM;
  const int colbase = blockIdx.x * 64;

  f32x4 acc[2][4];
#pragma unroll
  for (int m = 0; m < 2; ++m)
#pragma unroll
    for (int n = 0; n < 4; ++n) acc[m][n] = f32x4{0.f, 0.f, 0.f, 0.f};

  for (int kt = 0; kt < K / BK; ++kt) {
    const int kb = kt * BK;
#pragma unroll
    for (int it = 0; it < 4; ++it) {
      const int r  = it * 32 + w * 8 + (l >> 3);
      const int c8 = ((l & 7) * 8) ^ ((r & 7) << 3);
      const bf16* ga = A + (size_t)(rowbase + r) * K + kb + c8;
      __builtin_amdgcn_global_load_lds((const __attribute__((address_space(1))) void*)ga,
          (__attribute__((address_space(3))) void*)(ldsA + it * 2048 + w * 512), 16, 0, 0);
      if (it < 2) {
        int nrow = colbase + r;
        nrow = (nrow < N) ? nrow : (N - 1);
        const bf16* gb = B + (size_t)nrow * K + kb + c8;
        __builtin_amdgcn_global_load_lds((const __attribute__((address_space(1))) void*)gb,
            (__attribute__((address_space(3))) void*)(ldsB + it * 2048 + w * 512), 16, 0, 0);
      }
    }
    __syncthreads();
#pragma unroll
    for (int kk = 0; kk < 2; ++kk) {
      bf16x8 af[2], bfr[4];
#pragma unroll
      for (int m = 0; m < 2; ++m) {
        const int row = w * 32 + m * 16 + lr;
        const int ce  = (kk * 32 + lk * 8) ^ ((row & 7) << 3);
        af[m] = *(const bf16x8*)(ldsA + row * BK + ce);
      }
#pragma unroll
      for (int n = 0; n < 4; ++n) {
        const int row = n * 16 + lr;
        const int ce  = (kk * 32 + lk * 8) ^ ((row & 7) << 3);
        bfr[n] = *(const bf16x8*)(ldsB + row * BK + ce);
      }
#pragma unroll
      for (int m = 0; m < 2; ++m)
#pragma unroll
        for (int n = 0; n < 4; ++n)
          acc[m][n] = MFMA16(af[m], bfr[n], acc[m][n]);
    }
    __syncthreads();
  }

#pragma unroll
  for (int m = 0; m < 2; ++m)
#pragma unroll
    for (int n = 0; n < 4; ++n) {
      const int col = colbase + n * 16 + lr;
#pragma unroll
      for (int i = 0; i < 4; ++i) {
        const int row = rowbase + w * 32 + m * 16 + lk * 4 + i;
        if (col < QL)       q_out[(size_t)row * QL + col] = acc[m][n][i];
        else if (col < N)   ckv_out[(size_t)row * CKV_N + (col - QL)] = acc[m][n][i];
      }
    }
}

// Output projection: out[2048][2560] = ctx * woT^T, BM=128 x BN=64 tiles.
__global__ __launch_bounds__(256) void gemm_out64(const bf16* __restrict__ A,
                                                  const bf16* __restrict__ B,
                                                  float* __restrict__ C) {
  constexpr int BM = 128, BK = 64, K = HID, N = HID;
  __shared__ __bf16 ldsA[BM * BK];
  __shared__ __bf16 ldsB[64 * BK];
  const int t = threadIdx.x;
  const int l = t & 63, w = t >> 6;
  const int lr = l & 15, lk = l >> 4;
  const int rowbase = blockIdx.y * BM;
  const int colbase = blockIdx.x * 64;

  f32x4 acc[2][4];
#pragma unroll
  for (int m = 0; m < 2; ++m)
#pragma unroll
    for (int n = 0; n < 4; ++n) acc[m][n] = f32x4{0.f, 0.f, 0.f, 0.f};

  for (int kt = 0; kt < K / BK; ++kt) {
    const int kb = kt * BK;
#pragma unroll
    for (int it = 0; it < 4; ++it) {
      const int r  = it * 32 + w * 8 + (l >> 3);
      const int c8 = ((l & 7) * 8) ^ ((r & 7) << 3);
      const bf16* ga = A + (size_t)(rowbase + r) * K + kb + c8;
      __builtin_amdgcn_global_load_lds((const __attribute__((address_space(1))) void*)ga,
          (__attribute__((address_space(3))) void*)(ldsA + it * 2048 + w * 512), 16, 0, 0);
      if (it < 2) {
        const bf16* gb = B + (size_t)(colbase + r) * K + kb + c8;
        __builtin_amdgcn_global_load_lds((const __attribute__((address_space(1))) void*)gb,
            (__attribute__((address_space(3))) void*)(ldsB + it * 2048 + w * 512), 16, 0, 0);
      }
    }
    __syncthreads();
#pragma unroll
    for (int kk = 0; kk < 2; ++kk) {
      bf16x8 af[2], bfr[4];
#pragma unroll
      for (int m = 0; m < 2; ++m) {
        const int row = w * 32 + m * 16 + lr;
        const int ce  = (kk * 32 + lk * 8) ^ ((row & 7) << 3);
        af[m] = *(const bf16x8*)(ldsA + row * BK + ce);
      }
#pragma unroll
      for (int n = 0; n < 4; ++n) {
        const int row = n * 16 + lr;
        const int ce  = (kk * 32 + lk * 8) ^ ((row & 7) << 3);
        bfr[n] = *(const bf16x8*)(ldsB + row * BK + ce);
      }
#pragma unroll
      for (int m = 0; m < 2; ++m)
#pragma unroll
        for (int n = 0; n < 4; ++n)
          acc[m][n] = MFMA16(af[m], bfr[n], acc[m][n]);
    }
    __syncthreads();
  }

#pragma unroll
  for (int m = 0; m < 2; ++m)
#pragma unroll
    for (int n = 0; n < 4; ++n) {
      const int col = colbase + n * 16 + lr;
#pragma unroll
      for (int i = 0; i < 4; ++i) {
        const int row = rowbase + w * 32 + m * 16 + lk * 4 + i;
        C[(size_t)row * N + col] = acc[m][n][i];
      }
    }
}

// qb GEMM with fused RoPE + scale, writing qfull [NH][S][96] directly.
__global__ __launch_bounds__(256) void gemm_qb_rope(const bf16* __restrict__ A,
                                                    const bf16* __restrict__ B,
                                                    const float* __restrict__ ropc,
                                                    const float* __restrict__ rops,
                                                    bf16* __restrict__ qfull) {
  constexpr int BM = 128, BN = 128, BK = 64, K = QL, N = QB_N;
  __shared__ __bf16 ldsA[BM * BK];
  __shared__ __bf16 ldsB[BN * BK];
  const int t = threadIdx.x;
  const int l = t & 63, w = t >> 6;
  const int lr = l & 15, lk = l >> 4;
  const int wr = w >> 1, wc = w & 1;
  const int rowbase = blockIdx.y * BM;
  const int colbase = blockIdx.x * BN;
  const float scale = 0.14724444f; // 96^-0.5 * log2(e)

  f32x4 acc[4][4];
#pragma unroll
  for (int m = 0; m < 4; ++m)
#pragma unroll
    for (int n = 0; n < 4; ++n) acc[m][n] = f32x4{0.f, 0.f, 0.f, 0.f};

  for (int kt = 0; kt < K / BK; ++kt) {
    const int kb = kt * BK;
#pragma unroll
    for (int it = 0; it < 4; ++it) {
      const int r  = it * 32 + w * 8 + (l >> 3);
      const int c8 = ((l & 7) * 8) ^ ((r & 7) << 3);
      const bf16* ga = A + (size_t)(rowbase + r) * K + kb + c8;
      __builtin_amdgcn_global_load_lds((const __attribute__((address_space(1))) void*)ga,
          (__attribute__((address_space(3))) void*)(ldsA + it * 2048 + w * 512), 16, 0, 0);
      const bf16* gb = B + (size_t)(colbase + r) * K + kb + c8;
      __builtin_amdgcn_global_load_lds((const __attribute__((address_space(1))) void*)gb,
          (__attribute__((address_space(3))) void*)(ldsB + it * 2048 + w * 512), 16, 0, 0);
    }
    __syncthreads();
#pragma unroll
    for (int kk = 0; kk < 2; ++kk) {
      bf16x8 af[4], bfr[4];
#pragma unroll
      for (int m = 0; m < 4; ++m) {
        const int row = wr * 64 + m * 16 + lr;
        const int ce  = (kk * 32 + lk * 8) ^ ((row & 7) << 3);
        af[m] = *(const bf16x8*)(ldsA + row * BK + ce);
      }
#pragma unroll
      for (int n = 0; n < 4; ++n) {
        const int row = wc * 64 + n * 16 + lr;
        const int ce  = (kk * 32 + lk * 8) ^ ((row & 7) << 3);
        bfr[n] = *(const bf16x8*)(ldsB + row * BK + ce);
      }
#pragma unroll
      for (int m = 0; m < 4; ++m)
#pragma unroll
        for (int n = 0; n < 4; ++n)
          acc[m][n] = MFMA16(af[m], bfr[n], acc[m][n]);
    }
    __syncthreads();
  }

#pragma unroll
  for (int m = 0; m < 4; ++m) {
    const int rowtop = rowbase + wr * 64 + m * 16 + lk * 4;
#pragma unroll
    for (int n = 0; n < 4; ++n) {
      const int c0 = colbase + wc * 64 + n * 16; // frag base col
      const int h  = c0 / 96;
      const int d0 = c0 - h * 96;
      const size_t qb_ = ((size_t)h * S_LEN + rowtop) * QHD + d0 + lr;
      if (d0 < ND) {
#pragma unroll
        for (int i = 0; i < 4; ++i)
          qfull[qb_ + (size_t)i * QHD] = __float2bfloat16(acc[m][n][i] * scale);
      } else if (d0 == ND) { // rope-lo: out = x0*c - x1*s, x1 = acc[m][n+1]
#pragma unroll
        for (int i = 0; i < 4; ++i) {
          const float c = ropc[(rowtop + i) * 16 + lr];
          const float s = rops[(rowtop + i) * 16 + lr];
          const float x0 = acc[m][n][i], x1 = acc[m][n + 1][i];
          qfull[qb_ + (size_t)i * QHD] = __float2bfloat16((x0 * c - x1 * s) * scale);
        }
      } else { // d0 == 80, rope-hi: out = x1*c + x0*s, x0 = acc[m][n-1]
#pragma unroll
        for (int i = 0; i < 4; ++i) {
          const float c = ropc[(rowtop + i) * 16 + lr];
          const float s = rops[(rowtop + i) * 16 + lr];
          const float x1 = acc[m][n][i], x0 = acc[m][n - 1][i];
          qfull[qb_ + (size_t)i * QHD] = __float2bfloat16((x1 * c + x0 * s) * scale);
        }
      }
    }
  }
}

// kvb GEMM writing k_nope into kfull[h][s][0:64] (stride 96) and vt [NH][64][S].
__global__ __launch_bounds__(256) void gemm_kvb_split(const bf16* __restrict__ A,
                                                      const bf16* __restrict__ B,
                                                      bf16* __restrict__ kfull,
                                                      bf16* __restrict__ vt) {
  constexpr int BM = 128, BN = 128, BK = 64, K = KVL;
  __shared__ __bf16 ldsA[BM * BK];
  __shared__ __bf16 ldsB[BN * BK];
  const int t = threadIdx.x;
  const int l = t & 63, w = t >> 6;
  const int lr = l & 15, lk = l >> 4;
  const int wr = w >> 1, wc = w & 1;
  const int rowbase = blockIdx.y * BM;
  const int h = blockIdx.x; // head == col tile
  const int colbase = h * BN;

  f32x4 acc[4][4];
#pragma unroll
  for (int m = 0; m < 4; ++m)
#pragma unroll
    for (int n = 0; n < 4; ++n) acc[m][n] = f32x4{0.f, 0.f, 0.f, 0.f};

  for (int kt = 0; kt < K / BK; ++kt) {
    const int kb = kt * BK;
#pragma unroll
    for (int it = 0; it < 4; ++it) {
      const int r  = it * 32 + w * 8 + (l >> 3);
      const int c8 = ((l & 7) * 8) ^ ((r & 7) << 3);
      const bf16* ga = A + (size_t)(rowbase + r) * K + kb + c8;
      __builtin_amdgcn_global_load_lds((const __attribute__((address_space(1))) void*)ga,
          (__attribute__((address_space(3))) void*)(ldsA + it * 2048 + w * 512), 16, 0, 0);
      const bf16* gb = B + (size_t)(colbase + r) * K + kb + c8;
      __builtin_amdgcn_global_load_lds((const __attribute__((address_space(1))) void*)gb,
          (__attribute__((address_space(3))) void*)(ldsB + it * 2048 + w * 512), 16, 0, 0);
    }
    __syncthreads();
#pragma unroll
    for (int kk = 0; kk < 2; ++kk) {
      bf16x8 af[4], bfr[4];
#pragma unroll
      for (int m = 0; m < 4; ++m) {
        const int row = wr * 64 + m * 16 + lr;
        const int ce  = (kk * 32 + lk * 8) ^ ((row & 7) << 3);
        af[m] = *(const bf16x8*)(ldsA + row * BK + ce);
      }
#pragma unroll
      for (int n = 0; n < 4; ++n) {
        const int row = wc * 64 + n * 16 + lr;
        const int ce  = (kk * 32 + lk * 8) ^ ((row & 7) << 3);
        bfr[n] = *(const bf16x8*)(ldsB + row * BK + ce);
      }
#pragma unroll
      for (int m = 0; m < 4; ++m)
#pragma unroll
        for (int n = 0; n < 4; ++n)
          acc[m][n] = MFMA16(af[m], bfr[n], acc[m][n]);
    }
    __syncthreads();
  }

#pragma unroll
  for (int m = 0; m < 4; ++m) {
    const int rowtop = rowbase + wr * 64 + m * 16 + lk * 4;
    if (wc == 0) { // k_nope -> kfull[h][s][0:64] (stride QHD)
#pragma unroll
      for (int n = 0; n < 4; ++n) {
        const int d = n * 16 + lr;
#pragma unroll
        for (int i = 0; i < 4; ++i)
          kfull[((size_t)h * S_LEN + rowtop + i) * QHD + d] = __float2bfloat16(acc[m][n][i]);
      }
    } else {        // V -> vt[h][64][S] (8B transposed stores, L2 merges)
#pragma unroll
      for (int n = 0; n < 4; ++n) {
        const int d = n * 16 + lr;
        bf16x4 pk;
#pragma unroll
        for (int i = 0; i < 4; ++i) pk[i] = (__bf16)acc[m][n][i];
        *(bf16x4*)(vt + ((size_t)h * VD + d) * S_LEN + rowtop) = pk;
      }
    }
  }
}

// ---------------- norms / prep ----------------

__global__ void rmsnorm_rows(const float* __restrict__ in, const float* __restrict__ w,
                             bf16* __restrict__ out, int C) {
  const int r = blockIdx.x;
  const float* row = in + (size_t)r * C;
  float ss = 0.f;
  for (int c = threadIdx.x; c < C; c += 256) { float v = row[c]; ss += v * v; }
#pragma unroll
  for (int d = 32; d > 0; d >>= 1) ss += __shfl_xor(ss, d);
  __shared__ float red[4];
  if ((threadIdx.x & 63) == 0) red[threadIdx.x >> 6] = ss;
  __syncthreads();
  const float tot = red[0] + red[1] + red[2] + red[3];
  const float rs = rsqrtf(tot / (float)C + 1e-6f);
  for (int c = threadIdx.x; c < C; c += 256)
    out[(size_t)r * C + c] = __float2bfloat16(row[c] * rs * w[c]);
}

// per row: rmsnorm(ckv[0:256]) -> bf16 ; rope(k_pe) broadcast into
// kfull[h][s][64:96] for ALL heads (via LDS); rope tables for the q path.
__global__ void kv_prep(const float* __restrict__ ckv, const float* __restrict__ w,
                        const int* __restrict__ pos, bf16* __restrict__ ckv_bf,
                        bf16* __restrict__ kfull, float* __restrict__ ropc,
                        float* __restrict__ rops) {
  const int s = blockIdx.x, t = threadIdx.x; // 64 threads
  __shared__ bf16 pe_lds[32];
  const float* row = ckv + (size_t)s * CKV_N;
  float v[4]; float ss = 0.f;
#pragma unroll
  for (int j = 0; j < 4; ++j) { v[j] = row[t + 64 * j]; ss += v[j] * v[j]; }
#pragma unroll
  for (int d = 32; d > 0; d >>= 1) ss += __shfl_xor(ss, d);
  const float rs = rsqrtf(ss / (float)KVL + 1e-6f);
#pragma unroll
  for (int j = 0; j < 4; ++j)
    ckv_bf[(size_t)s * KVL + t + 64 * j] = __float2bfloat16(v[j] * rs * w[t + 64 * j]);
  if (t < 16) {
    const float x0 = row[KVL + t], x1 = row[KVL + 16 + t];
    const float p = (float)get_pos(pos, s);
    const float invf = exp2f(-(float)t * (13.2877124f / 16.f)); // 10000^(-t/16)
    const float ang = p * invf, c = cosf(ang), sn = sinf(ang);
    ropc[s * 16 + t] = c;
    rops[s * 16 + t] = sn;
    pe_lds[t]      = __float2bfloat16(x0 * c - x1 * sn);
    pe_lds[16 + t] = __float2bfloat16(x1 * c + x0 * sn);
  }
  __syncthreads();
  // broadcast pe into every head's kfull row (coalesced 64B per 32-lane group)
  for (int idx = t; idx < NH * 32; idx += 64) {
    const int h = idx >> 5, d = idx & 31;
    kfull[((size_t)h * S_LEN + s) * QHD + ND + d] = pe_lds[d];
  }
}

// ---------------- causal flash attention (R4 structure) ----------------
// One wave per block, 32 q rows, KVBLK=64, K prefetch, SWAPPED QK^T
// (st = mfma(K,Q) -> S^T: lane-local row reduce + 2 shfl), log2-domain
// softmax (log2e folded into Q), defer-rescale (skip O-rescale while tile
// max stays within 8 of running max), XOR-swizzled P tile. Single-pointer
// K walk over kfull[h][s][96]. Grid (NH, 64), q-tiles REVERSED (LPT).
__global__ __launch_bounds__(64) void attn_kernel(const bf16* __restrict__ qfull,
                                                  const bf16* __restrict__ kfull,
                                                  const bf16* __restrict__ vt,
                                                  bf16* __restrict__ ctx) {
  const int h = blockIdx.x;
  const int qw = ((int)gridDim.y - 1 - (int)blockIdx.y) * 32;
  const int l = threadIdx.x;
  const int lr = l & 15, lk = l >> 4;
  const bf16* Q  = qfull + (size_t)h * S_LEN * QHD;
  const bf16* Kf = kfull + (size_t)h * S_LEN * QHD;
  const bf16* V  = vt + (size_t)h * VD * S_LEN;
  __shared__ __bf16 plds[32][64]; // XOR-swizzled: col ^= (lr&7)<<3

  bf16x8 qf[2][3];
#pragma unroll
  for (int qg = 0; qg < 2; ++qg)
#pragma unroll
    for (int ks = 0; ks < 3; ++ks)
      qf[qg][ks] = *(const bf16x8*)(Q + (size_t)(qw + qg * 16 + lr) * QHD + ks * 32 + lk * 8);

  f32x4 o[2][4];
  float mrow[2], lrow[2];
#pragma unroll
  for (int qg = 0; qg < 2; ++qg) {
#pragma unroll
    for (int dt = 0; dt < 4; ++dt) o[qg][dt] = f32x4{0.f, 0.f, 0.f, 0.f};
    mrow[qg] = -1e30f; lrow[qg] = 0.f;
  }

  // preload K tile 0
  bf16x8 kf[4][3];
#pragma unroll
  for (int sub = 0; sub < 4; ++sub)
#pragma unroll
    for (int ks = 0; ks < 3; ++ks)
      kf[sub][ks] = *(const bf16x8*)(Kf + (size_t)(sub * 16 + lr) * QHD + ks * 32 + lk * 8);

  for (int kb = 0;; kb += 64) {
    // S^T tile: st[qg][sub][i] = S[q = qw+qg*16+lr][k = kb+sub*16+lk*4+i]
    f32x4 st[2][4];
#pragma unroll
    for (int qg = 0; qg < 2; ++qg)
#pragma unroll
      for (int sub = 0; sub < 4; ++sub) st[qg][sub] = f32x4{0.f, 0.f, 0.f, 0.f};
#pragma unroll
    for (int qg = 0; qg < 2; ++qg)
#pragma unroll
      for (int sub = 0; sub < 4; ++sub)
#pragma unroll
        for (int ks = 0; ks < 3; ++ks)
          st[qg][sub] = MFMA16(kf[sub][ks], qf[qg][ks], st[qg][sub]);

    // prefetch next K tile (hidden under softmax+PV)
    const int nkb = kb + 64;
    if (nkb <= qw) {
#pragma unroll
      for (int sub = 0; sub < 4; ++sub)
#pragma unroll
        for (int ks = 0; ks < 3; ++ks)
          kf[sub][ks] = *(const bf16x8*)(Kf + (size_t)(nkb + sub * 16 + lr) * QHD + ks * 32 + lk * 8);
    }

    const bool diag = (kb + 64 > qw);
    float tm[2];
#pragma unroll
    for (int qg = 0; qg < 2; ++qg) {
      const int q = qw + qg * 16 + lr;
      if (diag) {
#pragma unroll
        for (int sub = 0; sub < 4; ++sub)
#pragma unroll
          for (int i = 0; i < 4; ++i)
            if (kb + sub * 16 + lk * 4 + i > q) st[qg][sub][i] = -1e30f;
      }
      float m0 = -1e30f;
#pragma unroll
      for (int sub = 0; sub < 4; ++sub)
#pragma unroll
        for (int i = 0; i < 4; ++i) m0 = fmaxf(m0, st[qg][sub][i]);
      m0 = fmaxf(m0, __shfl_xor(m0, 16));
      m0 = fmaxf(m0, __shfl_xor(m0, 32));
      tm[qg] = m0;
    }

    // defer-rescale: if no row grew past m+8, keep old max (P <= 2^8).
    const bool noresc = __all((tm[0] <= mrow[0] + 8.f) && (tm[1] <= mrow[1] + 8.f));
    float fac[2];
#pragma unroll
    for (int qg = 0; qg < 2; ++qg) {
      const float mnew = noresc ? mrow[qg] : fmaxf(mrow[qg], tm[qg]);
      float ts = 0.f;
#pragma unroll
      for (int sub = 0; sub < 4; ++sub) {
        bf16x4 pk;
#pragma unroll
        for (int i = 0; i < 4; ++i) {
          const float p = exp2f(st[qg][sub][i] - mnew);
          ts += p;
          pk[i] = (__bf16)p;
        }
        const int swc = (sub * 16 + lk * 4) ^ ((lr & 7) << 3);
        *(bf16x4*)(&plds[qg * 16 + lr][swc]) = pk;
      }
      ts += __shfl_xor(ts, 16);
      ts += __shfl_xor(ts, 32);
      if (noresc) {
        lrow[qg] += ts;
      } else {
        fac[qg] = exp2f(mrow[qg] - mnew);
        lrow[qg] = lrow[qg] * fac[qg] + ts;
        mrow[qg] = mnew;
      }
    }
    if (!noresc) {
#pragma unroll
      for (int qg = 0; qg < 2; ++qg)
#pragma unroll
        for (int i = 0; i < 4; ++i) {
          const float fr = __shfl(fac[qg], lk * 4 + i);
#pragma unroll
          for (int dt = 0; dt < 4; ++dt) o[qg][dt][i] *= fr;
        }
    }

    // PV: A = P from LDS (swizzled read), B = V^T rows (contiguous in s)
#pragma unroll
    for (int h2 = 0; h2 < 2; ++h2) {
      const int swc = (h2 * 32 + lk * 8) ^ ((lr & 7) << 3);
      bf16x8 pa0 = *(const bf16x8*)(&plds[lr][swc]);
      bf16x8 pa1 = *(const bf16x8*)(&plds[16 + lr][swc]);
#pragma unroll
      for (int dt = 0; dt < 4; ++dt) {
        bf16x8 vf = *(const bf16x8*)(V + (size_t)(dt * 16 + lr) * S_LEN + kb + h2 * 32 + lk * 8);
        o[0][dt] = MFMA16(pa0, vf, o[0][dt]);
        o[1][dt] = MFMA16(pa1, vf, o[1][dt]);
      }
    }
    if (nkb > qw) break;
  }

#pragma unroll
  for (int qg = 0; qg < 2; ++qg) {
    const float linv = 1.0f / lrow[qg];
#pragma unroll
    for (int i = 0; i < 4; ++i) {
      const float inv = __shfl(linv, lk * 4 + i);
#pragma unroll
      for (int dt = 0; dt < 4; ++dt) {
        const int row = qw + qg * 16 + lk * 4 + i;
        const int col = h * VD + dt * 16 + lr;
        ctx[(size_t)row * HID + col] = __float2bfloat16(o[qg][dt][i] * inv);
      }
    }
  }
}

// ---------------- launch ----------------

extern "C" void kernel_launch(void* const* d_in, const int* in_sizes, int n_in,
                              void* d_out, int out_size, void* d_ws, size_t ws_size,
                              hipStream_t stream) {
  const float* hidden = (const float*)d_in[0];
  const int*   pos    = (const int*)d_in[1];
  const float* w_qa   = (const float*)d_in[2];
  const float* q_ln   = (const float*)d_in[3];
  const float* w_qb   = (const float*)d_in[4];
  const float* w_kva  = (const float*)d_in[5];
  const float* kv_ln  = (const float*)d_in[6];
  const float* w_kvb  = (const float*)d_in[7];
  const float* w_o    = (const float*)d_in[8];
  float* out = (float*)d_out;
  char* ws = (char*)d_ws;
  (void)in_sizes; (void)n_in; (void)out_size; (void)ws_size;

  size_t off = 0;
  auto take = [&](size_t bytes) -> char* {
    char* p = ws + off;
    off = (off + bytes + 255) & ~(size_t)255;
    return p;
  };
  bf16*  hid_bf = (bf16*)take((size_t)S_LEN * HID * 2);
  bf16*  wabT   = (bf16*)take((size_t)AB_N * HID * 2);   // wqaT | wkvaT
  bf16*  wqbT   = (bf16*)take((size_t)QB_N * QL * 2);
  bf16*  wkvbT  = (bf16*)take((size_t)KVB_N * KVL * 2);
  bf16*  woT    = (bf16*)take((size_t)HID * HID * 2);
  float* qlora  = (float*)take((size_t)S_LEN * QL * 4);
  bf16*  qa_bf  = (bf16*)take((size_t)S_LEN * QL * 2);
  bf16*  qfull  = (bf16*)take((size_t)NH * S_LEN * QHD * 2);
  float* ckv    = (float*)take((size_t)S_LEN * CKV_N * 4);
  bf16*  ckv_bf = (bf16*)take((size_t)S_LEN * KVL * 2);
  float* ropc   = (float*)take((size_t)S_LEN * 16 * 4);
  float* rops   = (float*)take((size_t)S_LEN * 16 * 4);
  bf16*  kfull  = (bf16*)take((size_t)NH * S_LEN * QHD * 2);
  bf16*  vt     = (bf16*)take((size_t)NH * VD * S_LEN * 2);
  bf16*  ctx    = (bf16*)take((size_t)S_LEN * HID * 2);

  const dim3 tb(32, 8);
  cast_f32_bf16<<<(S_LEN * HID / 4 + 255) / 256, 256, 0, stream>>>(hidden, hid_bf, S_LEN * HID / 4);
  transpose_cast<<<dim3((QL + 31) / 32, (HID + 31) / 32), tb, 0, stream>>>(w_qa, wabT, HID, QL);
  transpose_cast<<<dim3((CKV_N + 31) / 32, (HID + 31) / 32), tb, 0, stream>>>(w_kva, wabT + (size_t)QL * HID, HID, CKV_N);
  transpose_cast<<<dim3((QB_N + 31) / 32, (QL + 31) / 32), tb, 0, stream>>>(w_qb, wqbT, QL, QB_N);
  transpose_cast<<<dim3((KVB_N + 31) / 32, (KVL + 31) / 32), tb, 0, stream>>>(w_kvb, wkvbT, KVL, KVB_N);
  transpose_cast<<<dim3((HID + 31) / 32, (HID + 31) / 32), tb, 0, stream>>>(w_o, woT, HID, HID);

  // fused qa|kva GEMM
  gemm_qakva<<<dim3((AB_N + 63) / 64, S_LEN / 128), 256, 0, stream>>>(hid_bf, wabT, qlora, ckv);

  // kv prep (rmsnorm, rope tables, k_pe broadcast into kfull)
  kv_prep<<<S_LEN, 64, 0, stream>>>(ckv, kv_ln, pos, ckv_bf, kfull, ropc, rops);

  // q path: rmsnorm -> qb GEMM with fused rope -> qfull
  rmsnorm_rows<<<S_LEN, 256, 0, stream>>>(qlora, q_ln, qa_bf, QL);
  gemm_qb_rope<<<dim3(QB_N / 128, S_LEN / 128), 256, 0, stream>>>(qa_bf, wqbT, ropc, rops, qfull);

  // kv path: kvb GEMM writes k_nope into kfull + vt transposed
  gemm_kvb_split<<<dim3(KVB_N / 128, S_LEN / 128), 256, 0, stream>>>(ckv_bf, wkvbT, kfull, vt);

  // attention + output proj
  attn_kernel<<<dim3(NH, S_LEN / 32), 64, 0, stream>>>(qfull, kfull, vt, ctx);
  gemm_out64<<<dim3(HID / 64, S_LEN / 128), 256, 0, stream>>>(ctx, woT, out);
}

// Round 12
// 235.159 us; speedup vs baseline: 1.5519x; 1.0288x over previous
//
#include <hip/hip_runtime.h>
#include <hip/hip_bf16.h>

typedef __hip_bfloat16 bf16;
typedef __attribute__((ext_vector_type(8))) __bf16 bf16x8;
typedef __attribute__((ext_vector_type(4))) __bf16 bf16x4;
typedef __attribute__((ext_vector_type(4))) float f32x4;

constexpr int S_LEN = 2048;
constexpr int HID   = 2560;
constexpr int NH    = 40;
constexpr int QL    = 768;
constexpr int KVL   = 256;
constexpr int RD    = 32;
constexpr int ND    = 64;
constexpr int VD    = 64;
constexpr int QHD   = 96;                 // NOPE_D + ROPE_D
constexpr int QB_N  = NH * QHD;           // 3840
constexpr int KVB_N = NH * (ND + VD);     // 5120
constexpr int CKV_N = KVL + RD;           // 288
constexpr int AB_N  = QL + CKV_N;         // 1056 (fused qa|kva output cols)

#define MFMA16(a, b, c) __builtin_amdgcn_mfma_f32_16x16x32_bf16((a), (b), (c), 0, 0, 0)

// position_ids may arrive as int32 or int64; values are 0..2047 so sniff layout.
__device__ __forceinline__ int get_pos(const int* pos, int s) {
  bool is64 = (pos[1] == 0 && pos[2] == 1);
  return is64 ? pos[2 * s] : pos[s];
}

// ---------------- prep ----------------

__global__ void cast_f32_bf16(const float* __restrict__ src, bf16* __restrict__ dst, int n4) {
  int i = blockIdx.x * blockDim.x + threadIdx.x;
  if (i >= n4) return;
  float4 v = reinterpret_cast<const float4*>(src)[i];
  struct { bf16 a, b, c, d; } pk;
  pk.a = __float2bfloat16(v.x); pk.b = __float2bfloat16(v.y);
  pk.c = __float2bfloat16(v.z); pk.d = __float2bfloat16(v.w);
  reinterpret_cast<uint2*>(dst)[i] = *reinterpret_cast<uint2*>(&pk);
}

// src [K][N] f32 -> dst [N][K] bf16  (B^T layout for the GEMMs)
__global__ void transpose_cast(const float* __restrict__ src, bf16* __restrict__ dst, int K, int N) {
  __shared__ float tile[32][33];
  int nb = blockIdx.x * 32, kb = blockIdx.y * 32;
  int x = threadIdx.x, y = threadIdx.y; // (32,8)
#pragma unroll
  for (int j = 0; j < 4; ++j) {
    int k = kb + y + j * 8, n = nb + x;
    tile[y + j * 8][x] = (k < K && n < N) ? src[(size_t)k * N + n] : 0.f;
  }
  __syncthreads();
#pragma unroll
  for (int j = 0; j < 4; ++j) {
    int n = nb + y + j * 8, k = kb + x;
    if (n < N && k < K) dst[(size_t)n * K + k] = __float2bfloat16(tile[x][y + j * 8]);
  }
}

// ---------------- GEMMs ----------------

// Fused qa|kva GEMM: C[2048][1056] = hid_bf * wabT^T.
// BM=64 x BN=64 tiles -> grid 17x32 = 544 blocks (2.1/CU; BM=128 gave 272
// = 1.06/CU, occupancy-starved). 4 waves, each 16 rows x 64 cols.
__global__ __launch_bounds__(256) void gemm_qakva(const bf16* __restrict__ A,
                                                  const bf16* __restrict__ B,
                                                  float* __restrict__ q_out,
                                                  float* __restrict__ ckv_out) {
  constexpr int BM = 64, BK = 64, K = HID, N = AB_N;
  __shared__ __bf16 ldsA[BM * BK]; // 8KB
  __shared__ __bf16 ldsB[64 * BK]; // 8KB
  const int t = threadIdx.x;
  const int l = t & 63, w = t >> 6;
  const int lr = l & 15, lk = l >> 4;
  const int rowbase = blockIdx.y * BM;
  const int colbase = blockIdx.x * 64;

  f32x4 acc[4];
#pragma unroll
  for (int n = 0; n < 4; ++n) acc[n] = f32x4{0.f, 0.f, 0.f, 0.f};

  for (int kt = 0; kt < K / BK; ++kt) {
    const int kb = kt * BK;
#pragma unroll
    for (int it = 0; it < 2; ++it) {
      const int r  = it * 32 + w * 8 + (l >> 3);
      const int c8 = ((l & 7) * 8) ^ ((r & 7) << 3);
      const bf16* ga = A + (size_t)(rowbase + r) * K + kb + c8;
      __builtin_amdgcn_global_load_lds((const __attribute__((address_space(1))) void*)ga,
          (__attribute__((address_space(3))) void*)(ldsA + it * 2048 + w * 512), 16, 0, 0);
      int nrow = colbase + r;
      nrow = (nrow < N) ? nrow : (N - 1);
      const bf16* gb = B + (size_t)nrow * K + kb + c8;
      __builtin_amdgcn_global_load_lds((const __attribute__((address_space(1))) void*)gb,
          (__attribute__((address_space(3))) void*)(ldsB + it * 2048 + w * 512), 16, 0, 0);
    }
    __syncthreads();
#pragma unroll
    for (int kk = 0; kk < 2; ++kk) {
      const int arow = w * 16 + lr;
      const int ace  = (kk * 32 + lk * 8) ^ ((arow & 7) << 3);
      bf16x8 af = *(const bf16x8*)(ldsA + arow * BK + ace);
#pragma unroll
      for (int n = 0; n < 4; ++n) {
        const int row = n * 16 + lr;
        const int ce  = (kk * 32 + lk * 8) ^ ((row & 7) << 3);
        bf16x8 bfr = *(const bf16x8*)(ldsB + row * BK + ce);
        acc[n] = MFMA16(af, bfr, acc[n]);
      }
    }
    __syncthreads();
  }

#pragma unroll
  for (int n = 0; n < 4; ++n) {
    const int col = colbase + n * 16 + lr;
#pragma unroll
    for (int i = 0; i < 4; ++i) {
      const int row = rowbase + w * 16 + lk * 4 + i;
      if (col < QL)       q_out[(size_t)row * QL + col] = acc[n][i];
      else if (col < N)   ckv_out[(size_t)row * CKV_N + (col - QL)] = acc[n][i];
    }
  }
}

// Output projection: out[2048][2560] = ctx * woT^T, BM=128 x BN=64 tiles.
__global__ __launch_bounds__(256) void gemm_out64(const bf16* __restrict__ A,
                                                  const bf16* __restrict__ B,
                                                  float* __restrict__ C) {
  constexpr int BM = 128, BK = 64, K = HID, N = HID;
  __shared__ __bf16 ldsA[BM * BK];
  __shared__ __bf16 ldsB[64 * BK];
  const int t = threadIdx.x;
  const int l = t & 63, w = t >> 6;
  const int lr = l & 15, lk = l >> 4;
  const int rowbase = blockIdx.y * BM;
  const int colbase = blockIdx.x * 64;

  f32x4 acc[2][4];
#pragma unroll
  for (int m = 0; m < 2; ++m)
#pragma unroll
    for (int n = 0; n < 4; ++n) acc[m][n] = f32x4{0.f, 0.f, 0.f, 0.f};

  for (int kt = 0; kt < K / BK; ++kt) {
    const int kb = kt * BK;
#pragma unroll
    for (int it = 0; it < 4; ++it) {
      const int r  = it * 32 + w * 8 + (l >> 3);
      const int c8 = ((l & 7) * 8) ^ ((r & 7) << 3);
      const bf16* ga = A + (size_t)(rowbase + r) * K + kb + c8;
      __builtin_amdgcn_global_load_lds((const __attribute__((address_space(1))) void*)ga,
          (__attribute__((address_space(3))) void*)(ldsA + it * 2048 + w * 512), 16, 0, 0);
      if (it < 2) {
        const bf16* gb = B + (size_t)(colbase + r) * K + kb + c8;
        __builtin_amdgcn_global_load_lds((const __attribute__((address_space(1))) void*)gb,
            (__attribute__((address_space(3))) void*)(ldsB + it * 2048 + w * 512), 16, 0, 0);
      }
    }
    __syncthreads();
#pragma unroll
    for (int kk = 0; kk < 2; ++kk) {
      bf16x8 af[2], bfr[4];
#pragma unroll
      for (int m = 0; m < 2; ++m) {
        const int row = w * 32 + m * 16 + lr;
        const int ce  = (kk * 32 + lk * 8) ^ ((row & 7) << 3);
        af[m] = *(const bf16x8*)(ldsA + row * BK + ce);
      }
#pragma unroll
      for (int n = 0; n < 4; ++n) {
        const int row = n * 16 + lr;
        const int ce  = (kk * 32 + lk * 8) ^ ((row & 7) << 3);
        bfr[n] = *(const bf16x8*)(ldsB + row * BK + ce);
      }
#pragma unroll
      for (int m = 0; m < 2; ++m)
#pragma unroll
        for (int n = 0; n < 4; ++n)
          acc[m][n] = MFMA16(af[m], bfr[n], acc[m][n]);
    }
    __syncthreads();
  }

#pragma unroll
  for (int m = 0; m < 2; ++m)
#pragma unroll
    for (int n = 0; n < 4; ++n) {
      const int col = colbase + n * 16 + lr;
#pragma unroll
      for (int i = 0; i < 4; ++i) {
        const int row = rowbase + w * 32 + m * 16 + lk * 4 + i;
        C[(size_t)row * N + col] = acc[m][n][i];
      }
    }
}

// qb GEMM with fused RoPE + scale, writing qfull [NH][S][96] directly.
// BM=128 x BN=64 -> grid 60x16 = 960 blocks (3.75/CU; BN=128 gave 480).
// Rope pair (d, d+16) is always frags (n, n+1) of the SAME 64-col tile:
// head base 96h mod 64 in {0,32} -> rope-lo frag at n=0 (h even) or n=2 (h odd).
__global__ __launch_bounds__(256) void gemm_qb_rope(const bf16* __restrict__ A,
                                                    const bf16* __restrict__ B,
                                                    const float* __restrict__ ropc,
                                                    const float* __restrict__ rops,
                                                    bf16* __restrict__ qfull) {
  constexpr int BM = 128, BK = 64, K = QL;
  __shared__ __bf16 ldsA[BM * BK];
  __shared__ __bf16 ldsB[64 * BK];
  const int t = threadIdx.x;
  const int l = t & 63, w = t >> 6;
  const int lr = l & 15, lk = l >> 4;
  const int rowbase = blockIdx.y * BM;
  const int colbase = blockIdx.x * 64;
  const float scale = 0.14724444f; // 96^-0.5 * log2(e)

  f32x4 acc[2][4];
#pragma unroll
  for (int m = 0; m < 2; ++m)
#pragma unroll
    for (int n = 0; n < 4; ++n) acc[m][n] = f32x4{0.f, 0.f, 0.f, 0.f};

  for (int kt = 0; kt < K / BK; ++kt) {
    const int kb = kt * BK;
#pragma unroll
    for (int it = 0; it < 4; ++it) {
      const int r  = it * 32 + w * 8 + (l >> 3);
      const int c8 = ((l & 7) * 8) ^ ((r & 7) << 3);
      const bf16* ga = A + (size_t)(rowbase + r) * K + kb + c8;
      __builtin_amdgcn_global_load_lds((const __attribute__((address_space(1))) void*)ga,
          (__attribute__((address_space(3))) void*)(ldsA + it * 2048 + w * 512), 16, 0, 0);
      if (it < 2) {
        const bf16* gb = B + (size_t)(colbase + r) * K + kb + c8;
        __builtin_amdgcn_global_load_lds((const __attribute__((address_space(1))) void*)gb,
            (__attribute__((address_space(3))) void*)(ldsB + it * 2048 + w * 512), 16, 0, 0);
      }
    }
    __syncthreads();
#pragma unroll
    for (int kk = 0; kk < 2; ++kk) {
      bf16x8 af[2], bfr[4];
#pragma unroll
      for (int m = 0; m < 2; ++m) {
        const int row = w * 32 + m * 16 + lr;
        const int ce  = (kk * 32 + lk * 8) ^ ((row & 7) << 3);
        af[m] = *(const bf16x8*)(ldsA + row * BK + ce);
      }
#pragma unroll
      for (int n = 0; n < 4; ++n) {
        const int row = n * 16 + lr;
        const int ce  = (kk * 32 + lk * 8) ^ ((row & 7) << 3);
        bfr[n] = *(const bf16x8*)(ldsB + row * BK + ce);
      }
#pragma unroll
      for (int m = 0; m < 2; ++m)
#pragma unroll
        for (int n = 0; n < 4; ++n)
          acc[m][n] = MFMA16(af[m], bfr[n], acc[m][n]);
    }
    __syncthreads();
  }

#pragma unroll
  for (int m = 0; m < 2; ++m) {
    const int rowtop = rowbase + w * 32 + m * 16 + lk * 4;
#pragma unroll
    for (int n = 0; n < 4; ++n) {
      const int c0 = colbase + n * 16; // frag base col
      const int h  = c0 / 96;
      const int d0 = c0 - h * 96;
      const size_t qb_ = ((size_t)h * S_LEN + rowtop) * QHD + d0 + lr;
      if (d0 < ND) {
#pragma unroll
        for (int i = 0; i < 4; ++i)
          qfull[qb_ + (size_t)i * QHD] = __float2bfloat16(acc[m][n][i] * scale);
      } else if (d0 == ND) { // rope-lo: out = x0*c - x1*s, x1 = acc[m][n+1]
#pragma unroll
        for (int i = 0; i < 4; ++i) {
          const float c = ropc[(rowtop + i) * 16 + lr];
          const float s = rops[(rowtop + i) * 16 + lr];
          const float x0 = acc[m][n][i], x1 = acc[m][n + 1][i];
          qfull[qb_ + (size_t)i * QHD] = __float2bfloat16((x0 * c - x1 * s) * scale);
        }
      } else { // d0 == 80, rope-hi: out = x1*c + x0*s, x0 = acc[m][n-1]
#pragma unroll
        for (int i = 0; i < 4; ++i) {
          const float c = ropc[(rowtop + i) * 16 + lr];
          const float s = rops[(rowtop + i) * 16 + lr];
          const float x1 = acc[m][n][i], x0 = acc[m][n - 1][i];
          qfull[qb_ + (size_t)i * QHD] = __float2bfloat16((x1 * c + x0 * s) * scale);
        }
      }
    }
  }
}

// kvb GEMM writing k_nope into kfull[h][s][0:64] (stride 96) and vt [NH][64][S].
__global__ __launch_bounds__(256) void gemm_kvb_split(const bf16* __restrict__ A,
                                                      const bf16* __restrict__ B,
                                                      bf16* __restrict__ kfull,
                                                      bf16* __restrict__ vt) {
  constexpr int BM = 128, BN = 128, BK = 64, K = KVL;
  __shared__ __bf16 ldsA[BM * BK];
  __shared__ __bf16 ldsB[BN * BK];
  const int t = threadIdx.x;
  const int l = t & 63, w = t >> 6;
  const int lr = l & 15, lk = l >> 4;
  const int wr = w >> 1, wc = w & 1;
  const int rowbase = blockIdx.y * BM;
  const int h = blockIdx.x; // head == col tile
  const int colbase = h * BN;

  f32x4 acc[4][4];
#pragma unroll
  for (int m = 0; m < 4; ++m)
#pragma unroll
    for (int n = 0; n < 4; ++n) acc[m][n] = f32x4{0.f, 0.f, 0.f, 0.f};

  for (int kt = 0; kt < K / BK; ++kt) {
    const int kb = kt * BK;
#pragma unroll
    for (int it = 0; it < 4; ++it) {
      const int r  = it * 32 + w * 8 + (l >> 3);
      const int c8 = ((l & 7) * 8) ^ ((r & 7) << 3);
      const bf16* ga = A + (size_t)(rowbase + r) * K + kb + c8;
      __builtin_amdgcn_global_load_lds((const __attribute__((address_space(1))) void*)ga,
          (__attribute__((address_space(3))) void*)(ldsA + it * 2048 + w * 512), 16, 0, 0);
      const bf16* gb = B + (size_t)(colbase + r) * K + kb + c8;
      __builtin_amdgcn_global_load_lds((const __attribute__((address_space(1))) void*)gb,
          (__attribute__((address_space(3))) void*)(ldsB + it * 2048 + w * 512), 16, 0, 0);
    }
    __syncthreads();
#pragma unroll
    for (int kk = 0; kk < 2; ++kk) {
      bf16x8 af[4], bfr[4];
#pragma unroll
      for (int m = 0; m < 4; ++m) {
        const int row = wr * 64 + m * 16 + lr;
        const int ce  = (kk * 32 + lk * 8) ^ ((row & 7) << 3);
        af[m] = *(const bf16x8*)(ldsA + row * BK + ce);
      }
#pragma unroll
      for (int n = 0; n < 4; ++n) {
        const int row = wc * 64 + n * 16 + lr;
        const int ce  = (kk * 32 + lk * 8) ^ ((row & 7) << 3);
        bfr[n] = *(const bf16x8*)(ldsB + row * BK + ce);
      }
#pragma unroll
      for (int m = 0; m < 4; ++m)
#pragma unroll
        for (int n = 0; n < 4; ++n)
          acc[m][n] = MFMA16(af[m], bfr[n], acc[m][n]);
    }
    __syncthreads();
  }

#pragma unroll
  for (int m = 0; m < 4; ++m) {
    const int rowtop = rowbase + wr * 64 + m * 16 + lk * 4;
    if (wc == 0) { // k_nope -> kfull[h][s][0:64] (stride QHD)
#pragma unroll
      for (int n = 0; n < 4; ++n) {
        const int d = n * 16 + lr;
#pragma unroll
        for (int i = 0; i < 4; ++i)
          kfull[((size_t)h * S_LEN + rowtop + i) * QHD + d] = __float2bfloat16(acc[m][n][i]);
      }
    } else {        // V -> vt[h][64][S] (8B transposed stores, L2 merges)
#pragma unroll
      for (int n = 0; n < 4; ++n) {
        const int d = n * 16 + lr;
        bf16x4 pk;
#pragma unroll
        for (int i = 0; i < 4; ++i) pk[i] = (__bf16)acc[m][n][i];
        *(bf16x4*)(vt + ((size_t)h * VD + d) * S_LEN + rowtop) = pk;
      }
    }
  }
}

// ---------------- norms / prep ----------------

__global__ void rmsnorm_rows(const float* __restrict__ in, const float* __restrict__ w,
                             bf16* __restrict__ out, int C) {
  const int r = blockIdx.x;
  const float* row = in + (size_t)r * C;
  float ss = 0.f;
  for (int c = threadIdx.x; c < C; c += 256) { float v = row[c]; ss += v * v; }
#pragma unroll
  for (int d = 32; d > 0; d >>= 1) ss += __shfl_xor(ss, d);
  __shared__ float red[4];
  if ((threadIdx.x & 63) == 0) red[threadIdx.x >> 6] = ss;
  __syncthreads();
  const float tot = red[0] + red[1] + red[2] + red[3];
  const float rs = rsqrtf(tot / (float)C + 1e-6f);
  for (int c = threadIdx.x; c < C; c += 256)
    out[(size_t)r * C + c] = __float2bfloat16(row[c] * rs * w[c]);
}

// per row: rmsnorm(ckv[0:256]) -> bf16 ; rope(k_pe) broadcast into
// kfull[h][s][64:96] for ALL heads (via LDS); rope tables for the q path.
__global__ void kv_prep(const float* __restrict__ ckv, const float* __restrict__ w,
                        const int* __restrict__ pos, bf16* __restrict__ ckv_bf,
                        bf16* __restrict__ kfull, float* __restrict__ ropc,
                        float* __restrict__ rops) {
  const int s = blockIdx.x, t = threadIdx.x; // 64 threads
  __shared__ bf16 pe_lds[32];
  const float* row = ckv + (size_t)s * CKV_N;
  float v[4]; float ss = 0.f;
#pragma unroll
  for (int j = 0; j < 4; ++j) { v[j] = row[t + 64 * j]; ss += v[j] * v[j]; }
#pragma unroll
  for (int d = 32; d > 0; d >>= 1) ss += __shfl_xor(ss, d);
  const float rs = rsqrtf(ss / (float)KVL + 1e-6f);
#pragma unroll
  for (int j = 0; j < 4; ++j)
    ckv_bf[(size_t)s * KVL + t + 64 * j] = __float2bfloat16(v[j] * rs * w[t + 64 * j]);
  if (t < 16) {
    const float x0 = row[KVL + t], x1 = row[KVL + 16 + t];
    const float p = (float)get_pos(pos, s);
    const float invf = exp2f(-(float)t * (13.2877124f / 16.f)); // 10000^(-t/16)
    const float ang = p * invf, c = cosf(ang), sn = sinf(ang);
    ropc[s * 16 + t] = c;
    rops[s * 16 + t] = sn;
    pe_lds[t]      = __float2bfloat16(x0 * c - x1 * sn);
    pe_lds[16 + t] = __float2bfloat16(x1 * c + x0 * sn);
  }
  __syncthreads();
  // broadcast pe into every head's kfull row (coalesced 64B per 32-lane group)
  for (int idx = t; idx < NH * 32; idx += 64) {
    const int h = idx >> 5, d = idx & 31;
    kfull[((size_t)h * S_LEN + s) * QHD + ND + d] = pe_lds[d];
  }
}

// ---------------- causal flash attention (R4 structure + setprio) ----------------
// One wave per block, 32 q rows, KVBLK=64, K prefetch, SWAPPED QK^T
// (st = mfma(K,Q) -> S^T: lane-local row reduce + 2 shfl), log2-domain
// softmax (log2e folded into Q), defer-rescale, XOR-swizzled P tile.
// s_setprio(1) around MFMA clusters (T5: helps independent 1-wave blocks).
// Grid (NH, 64), q-tiles REVERSED (LPT).
__global__ __launch_bounds__(64) void attn_kernel(const bf16* __restrict__ qfull,
                                                  const bf16* __restrict__ kfull,
                                                  const bf16* __restrict__ vt,
                                                  bf16* __restrict__ ctx) {
  const int h = blockIdx.x;
  const int qw = ((int)gridDim.y - 1 - (int)blockIdx.y) * 32;
  const int l = threadIdx.x;
  const int lr = l & 15, lk = l >> 4;
  const bf16* Q  = qfull + (size_t)h * S_LEN * QHD;
  const bf16* Kf = kfull + (size_t)h * S_LEN * QHD;
  const bf16* V  = vt + (size_t)h * VD * S_LEN;
  __shared__ __bf16 plds[32][64]; // XOR-swizzled: col ^= (lr&7)<<3

  bf16x8 qf[2][3];
#pragma unroll
  for (int qg = 0; qg < 2; ++qg)
#pragma unroll
    for (int ks = 0; ks < 3; ++ks)
      qf[qg][ks] = *(const bf16x8*)(Q + (size_t)(qw + qg * 16 + lr) * QHD + ks * 32 + lk * 8);

  f32x4 o[2][4];
  float mrow[2], lrow[2];
#pragma unroll
  for (int qg = 0; qg < 2; ++qg) {
#pragma unroll
    for (int dt = 0; dt < 4; ++dt) o[qg][dt] = f32x4{0.f, 0.f, 0.f, 0.f};
    mrow[qg] = -1e30f; lrow[qg] = 0.f;
  }

  // preload K tile 0
  bf16x8 kf[4][3];
#pragma unroll
  for (int sub = 0; sub < 4; ++sub)
#pragma unroll
    for (int ks = 0; ks < 3; ++ks)
      kf[sub][ks] = *(const bf16x8*)(Kf + (size_t)(sub * 16 + lr) * QHD + ks * 32 + lk * 8);

  for (int kb = 0;; kb += 64) {
    // S^T tile: st[qg][sub][i] = S[q = qw+qg*16+lr][k = kb+sub*16+lk*4+i]
    f32x4 st[2][4];
#pragma unroll
    for (int qg = 0; qg < 2; ++qg)
#pragma unroll
      for (int sub = 0; sub < 4; ++sub) st[qg][sub] = f32x4{0.f, 0.f, 0.f, 0.f};
    __builtin_amdgcn_s_setprio(1);
#pragma unroll
    for (int qg = 0; qg < 2; ++qg)
#pragma unroll
      for (int sub = 0; sub < 4; ++sub)
#pragma unroll
        for (int ks = 0; ks < 3; ++ks)
          st[qg][sub] = MFMA16(kf[sub][ks], qf[qg][ks], st[qg][sub]);
    __builtin_amdgcn_s_setprio(0);

    // prefetch next K tile (hidden under softmax+PV)
    const int nkb = kb + 64;
    if (nkb <= qw) {
#pragma unroll
      for (int sub = 0; sub < 4; ++sub)
#pragma unroll
        for (int ks = 0; ks < 3; ++ks)
          kf[sub][ks] = *(const bf16x8*)(Kf + (size_t)(nkb + sub * 16 + lr) * QHD + ks * 32 + lk * 8);
    }

    const bool diag = (kb + 64 > qw);
    float tm[2];
#pragma unroll
    for (int qg = 0; qg < 2; ++qg) {
      const int q = qw + qg * 16 + lr;
      if (diag) {
#pragma unroll
        for (int sub = 0; sub < 4; ++sub)
#pragma unroll
          for (int i = 0; i < 4; ++i)
            if (kb + sub * 16 + lk * 4 + i > q) st[qg][sub][i] = -1e30f;
      }
      float m0 = -1e30f;
#pragma unroll
      for (int sub = 0; sub < 4; ++sub)
#pragma unroll
        for (int i = 0; i < 4; ++i) m0 = fmaxf(m0, st[qg][sub][i]);
      m0 = fmaxf(m0, __shfl_xor(m0, 16));
      m0 = fmaxf(m0, __shfl_xor(m0, 32));
      tm[qg] = m0;
    }

    // defer-rescale: if no row grew past m+8, keep old max (P <= 2^8).
    const bool noresc = __all((tm[0] <= mrow[0] + 8.f) && (tm[1] <= mrow[1] + 8.f));
    float fac[2];
#pragma unroll
    for (int qg = 0; qg < 2; ++qg) {
      const float mnew = noresc ? mrow[qg] : fmaxf(mrow[qg], tm[qg]);
      float ts = 0.f;
#pragma unroll
      for (int sub = 0; sub < 4; ++sub) {
        bf16x4 pk;
#pragma unroll
        for (int i = 0; i < 4; ++i) {
          const float p = exp2f(st[qg][sub][i] - mnew);
          ts += p;
          pk[i] = (__bf16)p;
        }
        const int swc = (sub * 16 + lk * 4) ^ ((lr & 7) << 3);
        *(bf16x4*)(&plds[qg * 16 + lr][swc]) = pk;
      }
      ts += __shfl_xor(ts, 16);
      ts += __shfl_xor(ts, 32);
      if (noresc) {
        lrow[qg] += ts;
      } else {
        fac[qg] = exp2f(mrow[qg] - mnew);
        lrow[qg] = lrow[qg] * fac[qg] + ts;
        mrow[qg] = mnew;
      }
    }
    if (!noresc) {
#pragma unroll
      for (int qg = 0; qg < 2; ++qg)
#pragma unroll
        for (int i = 0; i < 4; ++i) {
          const float fr = __shfl(fac[qg], lk * 4 + i);
#pragma unroll
          for (int dt = 0; dt < 4; ++dt) o[qg][dt][i] *= fr;
        }
    }

    // PV: A = P from LDS (swizzled read), B = V^T rows (contiguous in s)
#pragma unroll
    for (int h2 = 0; h2 < 2; ++h2) {
      const int swc = (h2 * 32 + lk * 8) ^ ((lr & 7) << 3);
      bf16x8 pa0 = *(const bf16x8*)(&plds[lr][swc]);
      bf16x8 pa1 = *(const bf16x8*)(&plds[16 + lr][swc]);
      __builtin_amdgcn_s_setprio(1);
#pragma unroll
      for (int dt = 0; dt < 4; ++dt) {
        bf16x8 vf = *(const bf16x8*)(V + (size_t)(dt * 16 + lr) * S_LEN + kb + h2 * 32 + lk * 8);
        o[0][dt] = MFMA16(pa0, vf, o[0][dt]);
        o[1][dt] = MFMA16(pa1, vf, o[1][dt]);
      }
      __builtin_amdgcn_s_setprio(0);
    }
    if (nkb > qw) break;
  }

#pragma unroll
  for (int qg = 0; qg < 2; ++qg) {
    const float linv = 1.0f / lrow[qg];
#pragma unroll
    for (int i = 0; i < 4; ++i) {
      const float inv = __shfl(linv, lk * 4 + i);
#pragma unroll
      for (int dt = 0; dt < 4; ++dt) {
        const int row = qw + qg * 16 + lk * 4 + i;
        const int col = h * VD + dt * 16 + lr;
        ctx[(size_t)row * HID + col] = __float2bfloat16(o[qg][dt][i] * inv);
      }
    }
  }
}

// ---------------- launch ----------------

extern "C" void kernel_launch(void* const* d_in, const int* in_sizes, int n_in,
                              void* d_out, int out_size, void* d_ws, size_t ws_size,
                              hipStream_t stream) {
  const float* hidden = (const float*)d_in[0];
  const int*   pos    = (const int*)d_in[1];
  const float* w_qa   = (const float*)d_in[2];
  const float* q_ln   = (const float*)d_in[3];
  const float* w_qb   = (const float*)d_in[4];
  const float* w_kva  = (const float*)d_in[5];
  const float* kv_ln  = (const float*)d_in[6];
  const float* w_kvb  = (const float*)d_in[7];
  const float* w_o    = (const float*)d_in[8];
  float* out = (float*)d_out;
  char* ws = (char*)d_ws;
  (void)in_sizes; (void)n_in; (void)out_size; (void)ws_size;

  size_t off = 0;
  auto take = [&](size_t bytes) -> char* {
    char* p = ws + off;
    off = (off + bytes + 255) & ~(size_t)255;
    return p;
  };
  bf16*  hid_bf = (bf16*)take((size_t)S_LEN * HID * 2);
  bf16*  wabT   = (bf16*)take((size_t)AB_N * HID * 2);   // wqaT | wkvaT
  bf16*  wqbT   = (bf16*)take((size_t)QB_N * QL * 2);
  bf16*  wkvbT  = (bf16*)take((size_t)KVB_N * KVL * 2);
  bf16*  woT    = (bf16*)take((size_t)HID * HID * 2);
  float* qlora  = (float*)take((size_t)S_LEN * QL * 4);
  bf16*  qa_bf  = (bf16*)take((size_t)S_LEN * QL * 2);
  bf16*  qfull  = (bf16*)take((size_t)NH * S_LEN * QHD * 2);
  float* ckv    = (float*)take((size_t)S_LEN * CKV_N * 4);
  bf16*  ckv_bf = (bf16*)take((size_t)S_LEN * KVL * 2);
  float* ropc   = (float*)take((size_t)S_LEN * 16 * 4);
  float* rops   = (float*)take((size_t)S_LEN * 16 * 4);
  bf16*  kfull  = (bf16*)take((size_t)NH * S_LEN * QHD * 2);
  bf16*  vt     = (bf16*)take((size_t)NH * VD * S_LEN * 2);
  bf16*  ctx    = (bf16*)take((size_t)S_LEN * HID * 2);

  const dim3 tb(32, 8);
  cast_f32_bf16<<<(S_LEN * HID / 4 + 255) / 256, 256, 0, stream>>>(hidden, hid_bf, S_LEN * HID / 4);
  transpose_cast<<<dim3((QL + 31) / 32, (HID + 31) / 32), tb, 0, stream>>>(w_qa, wabT, HID, QL);
  transpose_cast<<<dim3((CKV_N + 31) / 32, (HID + 31) / 32), tb, 0, stream>>>(w_kva, wabT + (size_t)QL * HID, HID, CKV_N);
  transpose_cast<<<dim3((QB_N + 31) / 32, (QL + 31) / 32), tb, 0, stream>>>(w_qb, wqbT, QL, QB_N);
  transpose_cast<<<dim3((KVB_N + 31) / 32, (KVL + 31) / 32), tb, 0, stream>>>(w_kvb, wkvbT, KVL, KVB_N);
  transpose_cast<<<dim3((HID + 31) / 32, (HID + 31) / 32), tb, 0, stream>>>(w_o, woT, HID, HID);

  // fused qa|kva GEMM (544 blocks)
  gemm_qakva<<<dim3((AB_N + 63) / 64, S_LEN / 64), 256, 0, stream>>>(hid_bf, wabT, qlora, ckv);

  // kv prep (rmsnorm, rope tables, k_pe broadcast into kfull)
  kv_prep<<<S_LEN, 64, 0, stream>>>(ckv, kv_ln, pos, ckv_bf, kfull, ropc, rops);

  // q path: rmsnorm -> qb GEMM with fused rope -> qfull (960 blocks)
  rmsnorm_rows<<<S_LEN, 256, 0, stream>>>(qlora, q_ln, qa_bf, QL);
  gemm_qb_rope<<<dim3(QB_N / 64, S_LEN / 128), 256, 0, stream>>>(qa_bf, wqbT, ropc, rops, qfull);

  // kv path: kvb GEMM writes k_nope into kfull + vt transposed
  gemm_kvb_split<<<dim3(KVB_N / 128, S_LEN / 128), 256, 0, stream>>>(ckv_bf, wkvbT, kfull, vt);

  // attention + output proj
  attn_kernel<<<dim3(NH, S_LEN / 32), 64, 0, stream>>>(qfull, kfull, vt, ctx);
  gemm_out64<<<dim3(HID / 64, S_LEN / 128), 256, 0, stream>>>(ctx, woT, out);
}

// Round 13
// 232.254 us; speedup vs baseline: 1.5713x; 1.0125x over previous
//
#include <hip/hip_runtime.h>
#include <hip/hip_bf16.h>

typedef __hip_bfloat16 bf16;
typedef __attribute__((ext_vector_type(8))) __bf16 bf16x8;
typedef __attribute__((ext_vector_type(4))) __bf16 bf16x4;
typedef __attribute__((ext_vector_type(4))) float f32x4;

constexpr int S_LEN = 2048;
constexpr int HID   = 2560;
constexpr int NH    = 40;
constexpr int QL    = 768;
constexpr int KVL   = 256;
constexpr int RD    = 32;
constexpr int ND    = 64;
constexpr int VD    = 64;
constexpr int QHD   = 96;                 // NOPE_D + ROPE_D
constexpr int QB_N  = NH * QHD;           // 3840
constexpr int KVB_N = NH * (ND + VD);     // 5120
constexpr int CKV_N = KVL + RD;           // 288
constexpr int AB_N  = QL + CKV_N;         // 1056 (fused qa|kva output cols)

#define MFMA16(a, b, c) __builtin_amdgcn_mfma_f32_16x16x32_bf16((a), (b), (c), 0, 0, 0)

// position_ids may arrive as int32 or int64; values are 0..2047 so sniff layout.
__device__ __forceinline__ int get_pos(const int* pos, int s) {
  bool is64 = (pos[1] == 0 && pos[2] == 1);
  return is64 ? pos[2 * s] : pos[s];
}

// ---------------- prep ----------------

__global__ void cast_f32_bf16(const float* __restrict__ src, bf16* __restrict__ dst, int n4) {
  int i = blockIdx.x * blockDim.x + threadIdx.x;
  if (i >= n4) return;
  float4 v = reinterpret_cast<const float4*>(src)[i];
  struct { bf16 a, b, c, d; } pk;
  pk.a = __float2bfloat16(v.x); pk.b = __float2bfloat16(v.y);
  pk.c = __float2bfloat16(v.z); pk.d = __float2bfloat16(v.w);
  reinterpret_cast<uint2*>(dst)[i] = *reinterpret_cast<uint2*>(&pk);
}

// src [K][N] f32 -> dst [N][K] bf16  (B^T layout for the GEMMs)
__global__ void transpose_cast(const float* __restrict__ src, bf16* __restrict__ dst, int K, int N) {
  __shared__ float tile[32][33];
  int nb = blockIdx.x * 32, kb = blockIdx.y * 32;
  int x = threadIdx.x, y = threadIdx.y; // (32,8)
#pragma unroll
  for (int j = 0; j < 4; ++j) {
    int k = kb + y + j * 8, n = nb + x;
    tile[y + j * 8][x] = (k < K && n < N) ? src[(size_t)k * N + n] : 0.f;
  }
  __syncthreads();
#pragma unroll
  for (int j = 0; j < 4; ++j) {
    int n = nb + y + j * 8, k = kb + x;
    if (n < N && k < K) dst[(size_t)n * K + k] = __float2bfloat16(tile[x][y + j * 8]);
  }
}

// ---------------- GEMMs ----------------

// Fused qa|kva GEMM: C[2048][1056] = hid_bf * wabT^T.
// BM=64 x BN=64 tiles -> 544 blocks (2.1/CU). 4 waves, each 16 rows x 64 cols.
__global__ __launch_bounds__(256) void gemm_qakva(const bf16* __restrict__ A,
                                                  const bf16* __restrict__ B,
                                                  float* __restrict__ q_out,
                                                  float* __restrict__ ckv_out) {
  constexpr int BM = 64, BK = 64, K = HID, N = AB_N;
  __shared__ __bf16 ldsA[BM * BK]; // 8KB
  __shared__ __bf16 ldsB[64 * BK]; // 8KB
  const int t = threadIdx.x;
  const int l = t & 63, w = t >> 6;
  const int lr = l & 15, lk = l >> 4;
  const int rowbase = blockIdx.y * BM;
  const int colbase = blockIdx.x * 64;

  f32x4 acc[4];
#pragma unroll
  for (int n = 0; n < 4; ++n) acc[n] = f32x4{0.f, 0.f, 0.f, 0.f};

  for (int kt = 0; kt < K / BK; ++kt) {
    const int kb = kt * BK;
#pragma unroll
    for (int it = 0; it < 2; ++it) {
      const int r  = it * 32 + w * 8 + (l >> 3);
      const int c8 = ((l & 7) * 8) ^ ((r & 7) << 3);
      const bf16* ga = A + (size_t)(rowbase + r) * K + kb + c8;
      __builtin_amdgcn_global_load_lds((const __attribute__((address_space(1))) void*)ga,
          (__attribute__((address_space(3))) void*)(ldsA + it * 2048 + w * 512), 16, 0, 0);
      int nrow = colbase + r;
      nrow = (nrow < N) ? nrow : (N - 1);
      const bf16* gb = B + (size_t)nrow * K + kb + c8;
      __builtin_amdgcn_global_load_lds((const __attribute__((address_space(1))) void*)gb,
          (__attribute__((address_space(3))) void*)(ldsB + it * 2048 + w * 512), 16, 0, 0);
    }
    __syncthreads();
#pragma unroll
    for (int kk = 0; kk < 2; ++kk) {
      const int arow = w * 16 + lr;
      const int ace  = (kk * 32 + lk * 8) ^ ((arow & 7) << 3);
      bf16x8 af = *(const bf16x8*)(ldsA + arow * BK + ace);
#pragma unroll
      for (int n = 0; n < 4; ++n) {
        const int row = n * 16 + lr;
        const int ce  = (kk * 32 + lk * 8) ^ ((row & 7) << 3);
        bf16x8 bfr = *(const bf16x8*)(ldsB + row * BK + ce);
        acc[n] = MFMA16(af, bfr, acc[n]);
      }
    }
    __syncthreads();
  }

#pragma unroll
  for (int n = 0; n < 4; ++n) {
    const int col = colbase + n * 16 + lr;
#pragma unroll
    for (int i = 0; i < 4; ++i) {
      const int row = rowbase + w * 16 + lk * 4 + i;
      if (col < QL)       q_out[(size_t)row * QL + col] = acc[n][i];
      else if (col < N)   ckv_out[(size_t)row * CKV_N + (col - QL)] = acc[n][i];
    }
  }
}

// Output projection: out[2048][2560] = ctx * woT^T, BM=128 x BN=64 tiles.
__global__ __launch_bounds__(256) void gemm_out64(const bf16* __restrict__ A,
                                                  const bf16* __restrict__ B,
                                                  float* __restrict__ C) {
  constexpr int BM = 128, BK = 64, K = HID, N = HID;
  __shared__ __bf16 ldsA[BM * BK];
  __shared__ __bf16 ldsB[64 * BK];
  const int t = threadIdx.x;
  const int l = t & 63, w = t >> 6;
  const int lr = l & 15, lk = l >> 4;
  const int rowbase = blockIdx.y * BM;
  const int colbase = blockIdx.x * 64;

  f32x4 acc[2][4];
#pragma unroll
  for (int m = 0; m < 2; ++m)
#pragma unroll
    for (int n = 0; n < 4; ++n) acc[m][n] = f32x4{0.f, 0.f, 0.f, 0.f};

  for (int kt = 0; kt < K / BK; ++kt) {
    const int kb = kt * BK;
#pragma unroll
    for (int it = 0; it < 4; ++it) {
      const int r  = it * 32 + w * 8 + (l >> 3);
      const int c8 = ((l & 7) * 8) ^ ((r & 7) << 3);
      const bf16* ga = A + (size_t)(rowbase + r) * K + kb + c8;
      __builtin_amdgcn_global_load_lds((const __attribute__((address_space(1))) void*)ga,
          (__attribute__((address_space(3))) void*)(ldsA + it * 2048 + w * 512), 16, 0, 0);
      if (it < 2) {
        const bf16* gb = B + (size_t)(colbase + r) * K + kb + c8;
        __builtin_amdgcn_global_load_lds((const __attribute__((address_space(1))) void*)gb,
            (__attribute__((address_space(3))) void*)(ldsB + it * 2048 + w * 512), 16, 0, 0);
      }
    }
    __syncthreads();
#pragma unroll
    for (int kk = 0; kk < 2; ++kk) {
      bf16x8 af[2], bfr[4];
#pragma unroll
      for (int m = 0; m < 2; ++m) {
        const int row = w * 32 + m * 16 + lr;
        const int ce  = (kk * 32 + lk * 8) ^ ((row & 7) << 3);
        af[m] = *(const bf16x8*)(ldsA + row * BK + ce);
      }
#pragma unroll
      for (int n = 0; n < 4; ++n) {
        const int row = n * 16 + lr;
        const int ce  = (kk * 32 + lk * 8) ^ ((row & 7) << 3);
        bfr[n] = *(const bf16x8*)(ldsB + row * BK + ce);
      }
#pragma unroll
      for (int m = 0; m < 2; ++m)
#pragma unroll
        for (int n = 0; n < 4; ++n)
          acc[m][n] = MFMA16(af[m], bfr[n], acc[m][n]);
    }
    __syncthreads();
  }

#pragma unroll
  for (int m = 0; m < 2; ++m)
#pragma unroll
    for (int n = 0; n < 4; ++n) {
      const int col = colbase + n * 16 + lr;
#pragma unroll
      for (int i = 0; i < 4; ++i) {
        const int row = rowbase + w * 32 + m * 16 + lk * 4 + i;
        C[(size_t)row * N + col] = acc[m][n][i];
      }
    }
}

// qb GEMM with fused RoPE + scale, writing qfull [NH][S][96] directly.
// BM=128 x BN=64 -> 960 blocks. Rope pair (d, d+16) is frags (n, n+1) of the
// SAME 64-col tile (head base 96h mod 64 in {0,32}).
__global__ __launch_bounds__(256) void gemm_qb_rope(const bf16* __restrict__ A,
                                                    const bf16* __restrict__ B,
                                                    const float* __restrict__ ropc,
                                                    const float* __restrict__ rops,
                                                    bf16* __restrict__ qfull) {
  constexpr int BM = 128, BK = 64, K = QL;
  __shared__ __bf16 ldsA[BM * BK];
  __shared__ __bf16 ldsB[64 * BK];
  const int t = threadIdx.x;
  const int l = t & 63, w = t >> 6;
  const int lr = l & 15, lk = l >> 4;
  const int rowbase = blockIdx.y * BM;
  const int colbase = blockIdx.x * 64;
  const float scale = 0.14724444f; // 96^-0.5 * log2(e)

  f32x4 acc[2][4];
#pragma unroll
  for (int m = 0; m < 2; ++m)
#pragma unroll
    for (int n = 0; n < 4; ++n) acc[m][n] = f32x4{0.f, 0.f, 0.f, 0.f};

  for (int kt = 0; kt < K / BK; ++kt) {
    const int kb = kt * BK;
#pragma unroll
    for (int it = 0; it < 4; ++it) {
      const int r  = it * 32 + w * 8 + (l >> 3);
      const int c8 = ((l & 7) * 8) ^ ((r & 7) << 3);
      const bf16* ga = A + (size_t)(rowbase + r) * K + kb + c8;
      __builtin_amdgcn_global_load_lds((const __attribute__((address_space(1))) void*)ga,
          (__attribute__((address_space(3))) void*)(ldsA + it * 2048 + w * 512), 16, 0, 0);
      if (it < 2) {
        const bf16* gb = B + (size_t)(colbase + r) * K + kb + c8;
        __builtin_amdgcn_global_load_lds((const __attribute__((address_space(1))) void*)gb,
            (__attribute__((address_space(3))) void*)(ldsB + it * 2048 + w * 512), 16, 0, 0);
      }
    }
    __syncthreads();
#pragma unroll
    for (int kk = 0; kk < 2; ++kk) {
      bf16x8 af[2], bfr[4];
#pragma unroll
      for (int m = 0; m < 2; ++m) {
        const int row = w * 32 + m * 16 + lr;
        const int ce  = (kk * 32 + lk * 8) ^ ((row & 7) << 3);
        af[m] = *(const bf16x8*)(ldsA + row * BK + ce);
      }
#pragma unroll
      for (int n = 0; n < 4; ++n) {
        const int row = n * 16 + lr;
        const int ce  = (kk * 32 + lk * 8) ^ ((row & 7) << 3);
        bfr[n] = *(const bf16x8*)(ldsB + row * BK + ce);
      }
#pragma unroll
      for (int m = 0; m < 2; ++m)
#pragma unroll
        for (int n = 0; n < 4; ++n)
          acc[m][n] = MFMA16(af[m], bfr[n], acc[m][n]);
    }
    __syncthreads();
  }

#pragma unroll
  for (int m = 0; m < 2; ++m) {
    const int rowtop = rowbase + w * 32 + m * 16 + lk * 4;
#pragma unroll
    for (int n = 0; n < 4; ++n) {
      const int c0 = colbase + n * 16; // frag base col
      const int h  = c0 / 96;
      const int d0 = c0 - h * 96;
      const size_t qb_ = ((size_t)h * S_LEN + rowtop) * QHD + d0 + lr;
      if (d0 < ND) {
#pragma unroll
        for (int i = 0; i < 4; ++i)
          qfull[qb_ + (size_t)i * QHD] = __float2bfloat16(acc[m][n][i] * scale);
      } else if (d0 == ND) { // rope-lo: out = x0*c - x1*s, x1 = acc[m][n+1]
#pragma unroll
        for (int i = 0; i < 4; ++i) {
          const float c = ropc[(rowtop + i) * 16 + lr];
          const float s = rops[(rowtop + i) * 16 + lr];
          const float x0 = acc[m][n][i], x1 = acc[m][n + 1][i];
          qfull[qb_ + (size_t)i * QHD] = __float2bfloat16((x0 * c - x1 * s) * scale);
        }
      } else { // d0 == 80, rope-hi: out = x1*c + x0*s, x0 = acc[m][n-1]
#pragma unroll
        for (int i = 0; i < 4; ++i) {
          const float c = ropc[(rowtop + i) * 16 + lr];
          const float s = rops[(rowtop + i) * 16 + lr];
          const float x1 = acc[m][n][i], x0 = acc[m][n - 1][i];
          qfull[qb_ + (size_t)i * QHD] = __float2bfloat16((x1 * c + x0 * s) * scale);
        }
      }
    }
  }
}

// kvb GEMM writing k_nope into kfull[h][s][0:64] (stride 96) and vt [NH][64][S].
__global__ __launch_bounds__(256) void gemm_kvb_split(const bf16* __restrict__ A,
                                                      const bf16* __restrict__ B,
                                                      bf16* __restrict__ kfull,
                                                      bf16* __restrict__ vt) {
  constexpr int BM = 128, BN = 128, BK = 64, K = KVL;
  __shared__ __bf16 ldsA[BM * BK];
  __shared__ __bf16 ldsB[BN * BK];
  const int t = threadIdx.x;
  const int l = t & 63, w = t >> 6;
  const int lr = l & 15, lk = l >> 4;
  const int wr = w >> 1, wc = w & 1;
  const int rowbase = blockIdx.y * BM;
  const int h = blockIdx.x; // head == col tile
  const int colbase = h * BN;

  f32x4 acc[4][4];
#pragma unroll
  for (int m = 0; m < 4; ++m)
#pragma unroll
    for (int n = 0; n < 4; ++n) acc[m][n] = f32x4{0.f, 0.f, 0.f, 0.f};

  for (int kt = 0; kt < K / BK; ++kt) {
    const int kb = kt * BK;
#pragma unroll
    for (int it = 0; it < 4; ++it) {
      const int r  = it * 32 + w * 8 + (l >> 3);
      const int c8 = ((l & 7) * 8) ^ ((r & 7) << 3);
      const bf16* ga = A + (size_t)(rowbase + r) * K + kb + c8;
      __builtin_amdgcn_global_load_lds((const __attribute__((address_space(1))) void*)ga,
          (__attribute__((address_space(3))) void*)(ldsA + it * 2048 + w * 512), 16, 0, 0);
      const bf16* gb = B + (size_t)(colbase + r) * K + kb + c8;
      __builtin_amdgcn_global_load_lds((const __attribute__((address_space(1))) void*)gb,
          (__attribute__((address_space(3))) void*)(ldsB + it * 2048 + w * 512), 16, 0, 0);
    }
    __syncthreads();
#pragma unroll
    for (int kk = 0; kk < 2; ++kk) {
      bf16x8 af[4], bfr[4];
#pragma unroll
      for (int m = 0; m < 4; ++m) {
        const int row = wr * 64 + m * 16 + lr;
        const int ce  = (kk * 32 + lk * 8) ^ ((row & 7) << 3);
        af[m] = *(const bf16x8*)(ldsA + row * BK + ce);
      }
#pragma unroll
      for (int n = 0; n < 4; ++n) {
        const int row = wc * 64 + n * 16 + lr;
        const int ce  = (kk * 32 + lk * 8) ^ ((row & 7) << 3);
        bfr[n] = *(const bf16x8*)(ldsB + row * BK + ce);
      }
#pragma unroll
      for (int m = 0; m < 4; ++m)
#pragma unroll
        for (int n = 0; n < 4; ++n)
          acc[m][n] = MFMA16(af[m], bfr[n], acc[m][n]);
    }
    __syncthreads();
  }

#pragma unroll
  for (int m = 0; m < 4; ++m) {
    const int rowtop = rowbase + wr * 64 + m * 16 + lk * 4;
    if (wc == 0) { // k_nope -> kfull[h][s][0:64] (stride QHD)
#pragma unroll
      for (int n = 0; n < 4; ++n) {
        const int d = n * 16 + lr;
#pragma unroll
        for (int i = 0; i < 4; ++i)
          kfull[((size_t)h * S_LEN + rowtop + i) * QHD + d] = __float2bfloat16(acc[m][n][i]);
      }
    } else {        // V -> vt[h][64][S] (8B transposed stores, L2 merges)
#pragma unroll
      for (int n = 0; n < 4; ++n) {
        const int d = n * 16 + lr;
        bf16x4 pk;
#pragma unroll
        for (int i = 0; i < 4; ++i) pk[i] = (__bf16)acc[m][n][i];
        *(bf16x4*)(vt + ((size_t)h * VD + d) * S_LEN + rowtop) = pk;
      }
    }
  }
}

// ---------------- norms / prep ----------------

__global__ void rmsnorm_rows(const float* __restrict__ in, const float* __restrict__ w,
                             bf16* __restrict__ out, int C) {
  const int r = blockIdx.x;
  const float* row = in + (size_t)r * C;
  float ss = 0.f;
  for (int c = threadIdx.x; c < C; c += 256) { float v = row[c]; ss += v * v; }
#pragma unroll
  for (int d = 32; d > 0; d >>= 1) ss += __shfl_xor(ss, d);
  __shared__ float red[4];
  if ((threadIdx.x & 63) == 0) red[threadIdx.x >> 6] = ss;
  __syncthreads();
  const float tot = red[0] + red[1] + red[2] + red[3];
  const float rs = rsqrtf(tot / (float)C + 1e-6f);
  for (int c = threadIdx.x; c < C; c += 256)
    out[(size_t)r * C + c] = __float2bfloat16(row[c] * rs * w[c]);
}

// per row: rmsnorm(ckv[0:256]) -> bf16 ; rope(k_pe) broadcast into
// kfull[h][s][64:96] for ALL heads (via LDS); rope tables for the q path.
__global__ void kv_prep(const float* __restrict__ ckv, const float* __restrict__ w,
                        const int* __restrict__ pos, bf16* __restrict__ ckv_bf,
                        bf16* __restrict__ kfull, float* __restrict__ ropc,
                        float* __restrict__ rops) {
  const int s = blockIdx.x, t = threadIdx.x; // 64 threads
  __shared__ bf16 pe_lds[32];
  const float* row = ckv + (size_t)s * CKV_N;
  float v[4]; float ss = 0.f;
#pragma unroll
  for (int j = 0; j < 4; ++j) { v[j] = row[t + 64 * j]; ss += v[j] * v[j]; }
#pragma unroll
  for (int d = 32; d > 0; d >>= 1) ss += __shfl_xor(ss, d);
  const float rs = rsqrtf(ss / (float)KVL + 1e-6f);
#pragma unroll
  for (int j = 0; j < 4; ++j)
    ckv_bf[(size_t)s * KVL + t + 64 * j] = __float2bfloat16(v[j] * rs * w[t + 64 * j]);
  if (t < 16) {
    const float x0 = row[KVL + t], x1 = row[KVL + 16 + t];
    const float p = (float)get_pos(pos, s);
    const float invf = exp2f(-(float)t * (13.2877124f / 16.f)); // 10000^(-t/16)
    const float ang = p * invf, c = cosf(ang), sn = sinf(ang);
    ropc[s * 16 + t] = c;
    rops[s * 16 + t] = sn;
    pe_lds[t]      = __float2bfloat16(x0 * c - x1 * sn);
    pe_lds[16 + t] = __float2bfloat16(x1 * c + x0 * sn);
  }
  __syncthreads();
  // broadcast pe into every head's kfull row (coalesced 64B per 32-lane group)
  for (int idx = t; idx < NH * 32; idx += 64) {
    const int h = idx >> 5, d = idx & 31;
    kfull[((size_t)h * S_LEN + s) * QHD + ND + d] = pe_lds[d];
  }
}

// ---------------- causal flash attention ----------------
// One wave per block, 32 q rows, KVBLK=64, K prefetch, SWAPPED QK^T
// (st = mfma(K,Q) -> S^T), log2-domain softmax, XOR-swizzled P tile.
// SHUFFLE-FREE STEADY STATE: defer-rescale gate uses lane-LOCAL max
// (__all over lanes == global-max check), and l is accumulated as a
// LANE-PARTIAL sum (reduced once in the epilogue). The 8 ds-swizzle
// shuffles per tile only occur on the rare rescale path.
// Grid (NH, 64), q-tiles REVERSED (LPT); h = blockIdx.x keeps XCD affinity.
__global__ __launch_bounds__(64) void attn_kernel(const bf16* __restrict__ qfull,
                                                  const bf16* __restrict__ kfull,
                                                  const bf16* __restrict__ vt,
                                                  bf16* __restrict__ ctx) {
  const int h = blockIdx.x;
  const int qw = ((int)gridDim.y - 1 - (int)blockIdx.y) * 32;
  const int l = threadIdx.x;
  const int lr = l & 15, lk = l >> 4;
  const bf16* Q  = qfull + (size_t)h * S_LEN * QHD;
  const bf16* Kf = kfull + (size_t)h * S_LEN * QHD;
  const bf16* V  = vt + (size_t)h * VD * S_LEN;
  __shared__ __bf16 plds[32][64]; // XOR-swizzled: col ^= (lr&7)<<3

  bf16x8 qf[2][3];
#pragma unroll
  for (int qg = 0; qg < 2; ++qg)
#pragma unroll
    for (int ks = 0; ks < 3; ++ks)
      qf[qg][ks] = *(const bf16x8*)(Q + (size_t)(qw + qg * 16 + lr) * QHD + ks * 32 + lk * 8);

  f32x4 o[2][4];
  float mrow[2], lrow[2]; // lrow is LANE-PARTIAL (this lane's k-slots only)
#pragma unroll
  for (int qg = 0; qg < 2; ++qg) {
#pragma unroll
    for (int dt = 0; dt < 4; ++dt) o[qg][dt] = f32x4{0.f, 0.f, 0.f, 0.f};
    mrow[qg] = -1e30f; lrow[qg] = 0.f;
  }

  // preload K tile 0
  bf16x8 kf[4][3];
#pragma unroll
  for (int sub = 0; sub < 4; ++sub)
#pragma unroll
    for (int ks = 0; ks < 3; ++ks)
      kf[sub][ks] = *(const bf16x8*)(Kf + (size_t)(sub * 16 + lr) * QHD + ks * 32 + lk * 8);

  for (int kb = 0;; kb += 64) {
    // S^T tile: st[qg][sub][i] = S[q = qw+qg*16+lr][k = kb+sub*16+lk*4+i]
    f32x4 st[2][4];
#pragma unroll
    for (int qg = 0; qg < 2; ++qg)
#pragma unroll
      for (int sub = 0; sub < 4; ++sub) st[qg][sub] = f32x4{0.f, 0.f, 0.f, 0.f};
    __builtin_amdgcn_s_setprio(1);
#pragma unroll
    for (int qg = 0; qg < 2; ++qg)
#pragma unroll
      for (int sub = 0; sub < 4; ++sub)
#pragma unroll
        for (int ks = 0; ks < 3; ++ks)
          st[qg][sub] = MFMA16(kf[sub][ks], qf[qg][ks], st[qg][sub]);
    __builtin_amdgcn_s_setprio(0);

    // prefetch next K tile (hidden under softmax+PV)
    const int nkb = kb + 64;
    if (nkb <= qw) {
#pragma unroll
      for (int sub = 0; sub < 4; ++sub)
#pragma unroll
        for (int ks = 0; ks < 3; ++ks)
          kf[sub][ks] = *(const bf16x8*)(Kf + (size_t)(nkb + sub * 16 + lr) * QHD + ks * 32 + lk * 8);
    }

    const bool diag = (kb + 64 > qw);
    float lmax[2];
#pragma unroll
    for (int qg = 0; qg < 2; ++qg) {
      const int q = qw + qg * 16 + lr;
      if (diag) {
#pragma unroll
        for (int sub = 0; sub < 4; ++sub)
#pragma unroll
          for (int i = 0; i < 4; ++i)
            if (kb + sub * 16 + lk * 4 + i > q) st[qg][sub][i] = -1e30f;
      }
      float m0 = -1e30f;
#pragma unroll
      for (int sub = 0; sub < 4; ++sub)
#pragma unroll
        for (int i = 0; i < 4; ++i) m0 = fmaxf(m0, st[qg][sub][i]);
      lmax[qg] = m0; // lane-local max (NOT reduced)
    }

    // defer-rescale gate on lane-LOCAL maxima: __all over lanes is
    // equivalent to checking the row-global max (max of lane maxima).
    const bool noresc = __all((lmax[0] <= mrow[0] + 8.f) && (lmax[1] <= mrow[1] + 8.f));
    float mnew[2], fac[2];
    if (noresc) {
      mnew[0] = mrow[0]; mnew[1] = mrow[1];
    } else { // rare path: full cross-lane reduce + rescale factors
#pragma unroll
      for (int qg = 0; qg < 2; ++qg) {
        float t0 = lmax[qg];
        t0 = fmaxf(t0, __shfl_xor(t0, 16));
        t0 = fmaxf(t0, __shfl_xor(t0, 32));
        mnew[qg] = fmaxf(mrow[qg], t0);
        fac[qg] = exp2f(mrow[qg] - mnew[qg]);
        mrow[qg] = mnew[qg];
      }
    }

#pragma unroll
    for (int qg = 0; qg < 2; ++qg) {
      float ts = 0.f;
#pragma unroll
      for (int sub = 0; sub < 4; ++sub) {
        bf16x4 pk;
#pragma unroll
        for (int i = 0; i < 4; ++i) {
          const float p = exp2f(st[qg][sub][i] - mnew[qg]);
          ts += p;
          pk[i] = (__bf16)p;
        }
        const int swc = (sub * 16 + lk * 4) ^ ((lr & 7) << 3);
        *(bf16x4*)(&plds[qg * 16 + lr][swc]) = pk;
      }
      if (noresc) lrow[qg] += ts;
      else        lrow[qg] = lrow[qg] * fac[qg] + ts;
    }
    if (!noresc) {
#pragma unroll
      for (int qg = 0; qg < 2; ++qg)
#pragma unroll
        for (int i = 0; i < 4; ++i) {
          const float fr = __shfl(fac[qg], lk * 4 + i);
#pragma unroll
          for (int dt = 0; dt < 4; ++dt) o[qg][dt][i] *= fr;
        }
    }

    // PV: A = P from LDS (swizzled read), B = V^T rows (contiguous in s)
#pragma unroll
    for (int h2 = 0; h2 < 2; ++h2) {
      const int swc = (h2 * 32 + lk * 8) ^ ((lr & 7) << 3);
      bf16x8 pa0 = *(const bf16x8*)(&plds[lr][swc]);
      bf16x8 pa1 = *(const bf16x8*)(&plds[16 + lr][swc]);
      __builtin_amdgcn_s_setprio(1);
#pragma unroll
      for (int dt = 0; dt < 4; ++dt) {
        bf16x8 vf = *(const bf16x8*)(V + (size_t)(dt * 16 + lr) * S_LEN + kb + h2 * 32 + lk * 8);
        o[0][dt] = MFMA16(pa0, vf, o[0][dt]);
        o[1][dt] = MFMA16(pa1, vf, o[1][dt]);
      }
      __builtin_amdgcn_s_setprio(0);
    }
    if (nkb > qw) break;
  }

  // epilogue: reduce lane-partial l across the 4 lanes of each row (once),
  // then broadcast 1/l to the o-row owners.
#pragma unroll
  for (int qg = 0; qg < 2; ++qg) {
    float ls = lrow[qg];
    ls += __shfl_xor(ls, 16);
    ls += __shfl_xor(ls, 32);
    const float linv = 1.0f / ls;
#pragma unroll
    for (int i = 0; i < 4; ++i) {
      const float inv = __shfl(linv, lk * 4 + i);
#pragma unroll
      for (int dt = 0; dt < 4; ++dt) {
        const int row = qw + qg * 16 + lk * 4 + i;
        const int col = h * VD + dt * 16 + lr;
        ctx[(size_t)row * HID + col] = __float2bfloat16(o[qg][dt][i] * inv);
      }
    }
  }
}

// ---------------- launch ----------------

extern "C" void kernel_launch(void* const* d_in, const int* in_sizes, int n_in,
                              void* d_out, int out_size, void* d_ws, size_t ws_size,
                              hipStream_t stream) {
  const float* hidden = (const float*)d_in[0];
  const int*   pos    = (const int*)d_in[1];
  const float* w_qa   = (const float*)d_in[2];
  const float* q_ln   = (const float*)d_in[3];
  const float* w_qb   = (const float*)d_in[4];
  const float* w_kva  = (const float*)d_in[5];
  const float* kv_ln  = (const float*)d_in[6];
  const float* w_kvb  = (const float*)d_in[7];
  const float* w_o    = (const float*)d_in[8];
  float* out = (float*)d_out;
  char* ws = (char*)d_ws;
  (void)in_sizes; (void)n_in; (void)out_size; (void)ws_size;

  size_t off = 0;
  auto take = [&](size_t bytes) -> char* {
    char* p = ws + off;
    off = (off + bytes + 255) & ~(size_t)255;
    return p;
  };
  bf16*  hid_bf = (bf16*)take((size_t)S_LEN * HID * 2);
  bf16*  wabT   = (bf16*)take((size_t)AB_N * HID * 2);   // wqaT | wkvaT
  bf16*  wqbT   = (bf16*)take((size_t)QB_N * QL * 2);
  bf16*  wkvbT  = (bf16*)take((size_t)KVB_N * KVL * 2);
  bf16*  woT    = (bf16*)take((size_t)HID * HID * 2);
  float* qlora  = (float*)take((size_t)S_LEN * QL * 4);
  bf16*  qa_bf  = (bf16*)take((size_t)S_LEN * QL * 2);
  bf16*  qfull  = (bf16*)take((size_t)NH * S_LEN * QHD * 2);
  float* ckv    = (float*)take((size_t)S_LEN * CKV_N * 4);
  bf16*  ckv_bf = (bf16*)take((size_t)S_LEN * KVL * 2);
  float* ropc   = (float*)take((size_t)S_LEN * 16 * 4);
  float* rops   = (float*)take((size_t)S_LEN * 16 * 4);
  bf16*  kfull  = (bf16*)take((size_t)NH * S_LEN * QHD * 2);
  bf16*  vt     = (bf16*)take((size_t)NH * VD * S_LEN * 2);
  bf16*  ctx    = (bf16*)take((size_t)S_LEN * HID * 2);

  const dim3 tb(32, 8);
  cast_f32_bf16<<<(S_LEN * HID / 4 + 255) / 256, 256, 0, stream>>>(hidden, hid_bf, S_LEN * HID / 4);
  transpose_cast<<<dim3((QL + 31) / 32, (HID + 31) / 32), tb, 0, stream>>>(w_qa, wabT, HID, QL);
  transpose_cast<<<dim3((CKV_N + 31) / 32, (HID + 31) / 32), tb, 0, stream>>>(w_kva, wabT + (size_t)QL * HID, HID, CKV_N);
  transpose_cast<<<dim3((QB_N + 31) / 32, (QL + 31) / 32), tb, 0, stream>>>(w_qb, wqbT, QL, QB_N);
  transpose_cast<<<dim3((KVB_N + 31) / 32, (KVL + 31) / 32), tb, 0, stream>>>(w_kvb, wkvbT, KVL, KVB_N);
  transpose_cast<<<dim3((HID + 31) / 32, (HID + 31) / 32), tb, 0, stream>>>(w_o, woT, HID, HID);

  // fused qa|kva GEMM (544 blocks)
  gemm_qakva<<<dim3((AB_N + 63) / 64, S_LEN / 64), 256, 0, stream>>>(hid_bf, wabT, qlora, ckv);

  // kv prep (rmsnorm, rope tables, k_pe broadcast into kfull)
  kv_prep<<<S_LEN, 64, 0, stream>>>(ckv, kv_ln, pos, ckv_bf, kfull, ropc, rops);

  // q path: rmsnorm -> qb GEMM with fused rope -> qfull (960 blocks)
  rmsnorm_rows<<<S_LEN, 256, 0, stream>>>(qlora, q_ln, qa_bf, QL);
  gemm_qb_rope<<<dim3(QB_N / 64, S_LEN / 128), 256, 0, stream>>>(qa_bf, wqbT, ropc, rops, qfull);

  // kv path: kvb GEMM writes k_nope into kfull + vt transposed
  gemm_kvb_split<<<dim3(KVB_N / 128, S_LEN / 128), 256, 0, stream>>>(ckv_bf, wkvbT, kfull, vt);

  // attention + output proj
  attn_kernel<<<dim3(NH, S_LEN / 32), 64, 0, stream>>>(qfull, kfull, vt, ctx);
  gemm_out64<<<dim3(HID / 64, S_LEN / 128), 256, 0, stream>>>(ctx, woT, out);
}

// Round 14
// 227.552 us; speedup vs baseline: 1.6037x; 1.0207x over previous
//
#include <hip/hip_runtime.h>
#include <hip/hip_bf16.h>

typedef __hip_bfloat16 bf16;
typedef __attribute__((ext_vector_type(8))) __bf16 bf16x8;
typedef __attribute__((ext_vector_type(4))) __bf16 bf16x4;
typedef __attribute__((ext_vector_type(4))) float f32x4;

constexpr int S_LEN = 2048;
constexpr int HID   = 2560;
constexpr int NH    = 40;
constexpr int QL    = 768;
constexpr int KVL   = 256;
constexpr int RD    = 32;
constexpr int ND    = 64;
constexpr int VD    = 64;
constexpr int QHD   = 96;                 // NOPE_D + ROPE_D
constexpr int QB_N  = NH * QHD;           // 3840
constexpr int KVB_N = NH * (ND + VD);     // 5120
constexpr int CKV_N = KVL + RD;           // 288
constexpr int AB_N  = QL + CKV_N;         // 1056 (fused qa|kva output cols)

#define MFMA16(a, b, c) __builtin_amdgcn_mfma_f32_16x16x32_bf16((a), (b), (c), 0, 0, 0)

// position_ids may arrive as int32 or int64; values are 0..2047 so sniff layout.
__device__ __forceinline__ int get_pos(const int* pos, int s) {
  bool is64 = (pos[1] == 0 && pos[2] == 1);
  return is64 ? pos[2 * s] : pos[s];
}

// ---------------- prep ----------------

__global__ void cast_f32_bf16(const float* __restrict__ src, bf16* __restrict__ dst, int n4) {
  int i = blockIdx.x * blockDim.x + threadIdx.x;
  if (i >= n4) return;
  float4 v = reinterpret_cast<const float4*>(src)[i];
  struct { bf16 a, b, c, d; } pk;
  pk.a = __float2bfloat16(v.x); pk.b = __float2bfloat16(v.y);
  pk.c = __float2bfloat16(v.z); pk.d = __float2bfloat16(v.w);
  reinterpret_cast<uint2*>(dst)[i] = *reinterpret_cast<uint2*>(&pk);
}

// src [K][N] f32 -> dst [N][K] bf16  (B^T layout for the GEMMs)
__global__ void transpose_cast(const float* __restrict__ src, bf16* __restrict__ dst, int K, int N) {
  __shared__ float tile[32][33];
  int nb = blockIdx.x * 32, kb = blockIdx.y * 32;
  int x = threadIdx.x, y = threadIdx.y; // (32,8)
#pragma unroll
  for (int j = 0; j < 4; ++j) {
    int k = kb + y + j * 8, n = nb + x;
    tile[y + j * 8][x] = (k < K && n < N) ? src[(size_t)k * N + n] : 0.f;
  }
  __syncthreads();
#pragma unroll
  for (int j = 0; j < 4; ++j) {
    int n = nb + y + j * 8, k = kb + x;
    if (n < N && k < K) dst[(size_t)n * K + k] = __float2bfloat16(tile[x][y + j * 8]);
  }
}

// ---------------- GEMMs ----------------

// Fused qa|kva GEMM: C[2048][1056] = hid_bf * wabT^T.
// BM=64 x BN=64 tiles -> 544 blocks (2.1/CU). 4 waves, each 16 rows x 64 cols.
__global__ __launch_bounds__(256) void gemm_qakva(const bf16* __restrict__ A,
                                                  const bf16* __restrict__ B,
                                                  float* __restrict__ q_out,
                                                  float* __restrict__ ckv_out) {
  constexpr int BM = 64, BK = 64, K = HID, N = AB_N;
  __shared__ __bf16 ldsA[BM * BK]; // 8KB
  __shared__ __bf16 ldsB[64 * BK]; // 8KB
  const int t = threadIdx.x;
  const int l = t & 63, w = t >> 6;
  const int lr = l & 15, lk = l >> 4;
  const int rowbase = blockIdx.y * BM;
  const int colbase = blockIdx.x * 64;

  f32x4 acc[4];
#pragma unroll
  for (int n = 0; n < 4; ++n) acc[n] = f32x4{0.f, 0.f, 0.f, 0.f};

  for (int kt = 0; kt < K / BK; ++kt) {
    const int kb = kt * BK;
#pragma unroll
    for (int it = 0; it < 2; ++it) {
      const int r  = it * 32 + w * 8 + (l >> 3);
      const int c8 = ((l & 7) * 8) ^ ((r & 7) << 3);
      const bf16* ga = A + (size_t)(rowbase + r) * K + kb + c8;
      __builtin_amdgcn_global_load_lds((const __attribute__((address_space(1))) void*)ga,
          (__attribute__((address_space(3))) void*)(ldsA + it * 2048 + w * 512), 16, 0, 0);
      int nrow = colbase + r;
      nrow = (nrow < N) ? nrow : (N - 1);
      const bf16* gb = B + (size_t)nrow * K + kb + c8;
      __builtin_amdgcn_global_load_lds((const __attribute__((address_space(1))) void*)gb,
          (__attribute__((address_space(3))) void*)(ldsB + it * 2048 + w * 512), 16, 0, 0);
    }
    __syncthreads();
#pragma unroll
    for (int kk = 0; kk < 2; ++kk) {
      const int arow = w * 16 + lr;
      const int ace  = (kk * 32 + lk * 8) ^ ((arow & 7) << 3);
      bf16x8 af = *(const bf16x8*)(ldsA + arow * BK + ace);
#pragma unroll
      for (int n = 0; n < 4; ++n) {
        const int row = n * 16 + lr;
        const int ce  = (kk * 32 + lk * 8) ^ ((row & 7) << 3);
        bf16x8 bfr = *(const bf16x8*)(ldsB + row * BK + ce);
        acc[n] = MFMA16(af, bfr, acc[n]);
      }
    }
    __syncthreads();
  }

#pragma unroll
  for (int n = 0; n < 4; ++n) {
    const int col = colbase + n * 16 + lr;
#pragma unroll
    for (int i = 0; i < 4; ++i) {
      const int row = rowbase + w * 16 + lk * 4 + i;
      if (col < QL)       q_out[(size_t)row * QL + col] = acc[n][i];
      else if (col < N)   ckv_out[(size_t)row * CKV_N + (col - QL)] = acc[n][i];
    }
  }
}

// Output projection: out[2048][2560] = ctx * woT^T, BM=128 x BN=64 tiles.
__global__ __launch_bounds__(256) void gemm_out64(const bf16* __restrict__ A,
                                                  const bf16* __restrict__ B,
                                                  float* __restrict__ C) {
  constexpr int BM = 128, BK = 64, K = HID, N = HID;
  __shared__ __bf16 ldsA[BM * BK];
  __shared__ __bf16 ldsB[64 * BK];
  const int t = threadIdx.x;
  const int l = t & 63, w = t >> 6;
  const int lr = l & 15, lk = l >> 4;
  const int rowbase = blockIdx.y * BM;
  const int colbase = blockIdx.x * 64;

  f32x4 acc[2][4];
#pragma unroll
  for (int m = 0; m < 2; ++m)
#pragma unroll
    for (int n = 0; n < 4; ++n) acc[m][n] = f32x4{0.f, 0.f, 0.f, 0.f};

  for (int kt = 0; kt < K / BK; ++kt) {
    const int kb = kt * BK;
#pragma unroll
    for (int it = 0; it < 4; ++it) {
      const int r  = it * 32 + w * 8 + (l >> 3);
      const int c8 = ((l & 7) * 8) ^ ((r & 7) << 3);
      const bf16* ga = A + (size_t)(rowbase + r) * K + kb + c8;
      __builtin_amdgcn_global_load_lds((const __attribute__((address_space(1))) void*)ga,
          (__attribute__((address_space(3))) void*)(ldsA + it * 2048 + w * 512), 16, 0, 0);
      if (it < 2) {
        const bf16* gb = B + (size_t)(colbase + r) * K + kb + c8;
        __builtin_amdgcn_global_load_lds((const __attribute__((address_space(1))) void*)gb,
            (__attribute__((address_space(3))) void*)(ldsB + it * 2048 + w * 512), 16, 0, 0);
      }
    }
    __syncthreads();
#pragma unroll
    for (int kk = 0; kk < 2; ++kk) {
      bf16x8 af[2], bfr[4];
#pragma unroll
      for (int m = 0; m < 2; ++m) {
        const int row = w * 32 + m * 16 + lr;
        const int ce  = (kk * 32 + lk * 8) ^ ((row & 7) << 3);
        af[m] = *(const bf16x8*)(ldsA + row * BK + ce);
      }
#pragma unroll
      for (int n = 0; n < 4; ++n) {
        const int row = n * 16 + lr;
        const int ce  = (kk * 32 + lk * 8) ^ ((row & 7) << 3);
        bfr[n] = *(const bf16x8*)(ldsB + row * BK + ce);
      }
#pragma unroll
      for (int m = 0; m < 2; ++m)
#pragma unroll
        for (int n = 0; n < 4; ++n)
          acc[m][n] = MFMA16(af[m], bfr[n], acc[m][n]);
    }
    __syncthreads();
  }

#pragma unroll
  for (int m = 0; m < 2; ++m)
#pragma unroll
    for (int n = 0; n < 4; ++n) {
      const int col = colbase + n * 16 + lr;
#pragma unroll
      for (int i = 0; i < 4; ++i) {
        const int row = rowbase + w * 32 + m * 16 + lk * 4 + i;
        C[(size_t)row * N + col] = acc[m][n][i];
      }
    }
}

// qb GEMM with fused RoPE + scale, writing qfull [NH][S][96] directly.
// BM=128 x BN=64 -> 960 blocks. Rope pair (d, d+16) is frags (n, n+1) of the
// SAME 64-col tile (head base 96h mod 64 in {0,32}).
__global__ __launch_bounds__(256) void gemm_qb_rope(const bf16* __restrict__ A,
                                                    const bf16* __restrict__ B,
                                                    const float* __restrict__ ropc,
                                                    const float* __restrict__ rops,
                                                    bf16* __restrict__ qfull) {
  constexpr int BM = 128, BK = 64, K = QL;
  __shared__ __bf16 ldsA[BM * BK];
  __shared__ __bf16 ldsB[64 * BK];
  const int t = threadIdx.x;
  const int l = t & 63, w = t >> 6;
  const int lr = l & 15, lk = l >> 4;
  const int rowbase = blockIdx.y * BM;
  const int colbase = blockIdx.x * 64;
  const float scale = 0.14724444f; // 96^-0.5 * log2(e)

  f32x4 acc[2][4];
#pragma unroll
  for (int m = 0; m < 2; ++m)
#pragma unroll
    for (int n = 0; n < 4; ++n) acc[m][n] = f32x4{0.f, 0.f, 0.f, 0.f};

  for (int kt = 0; kt < K / BK; ++kt) {
    const int kb = kt * BK;
#pragma unroll
    for (int it = 0; it < 4; ++it) {
      const int r  = it * 32 + w * 8 + (l >> 3);
      const int c8 = ((l & 7) * 8) ^ ((r & 7) << 3);
      const bf16* ga = A + (size_t)(rowbase + r) * K + kb + c8;
      __builtin_amdgcn_global_load_lds((const __attribute__((address_space(1))) void*)ga,
          (__attribute__((address_space(3))) void*)(ldsA + it * 2048 + w * 512), 16, 0, 0);
      if (it < 2) {
        const bf16* gb = B + (size_t)(colbase + r) * K + kb + c8;
        __builtin_amdgcn_global_load_lds((const __attribute__((address_space(1))) void*)gb,
            (__attribute__((address_space(3))) void*)(ldsB + it * 2048 + w * 512), 16, 0, 0);
      }
    }
    __syncthreads();
#pragma unroll
    for (int kk = 0; kk < 2; ++kk) {
      bf16x8 af[2], bfr[4];
#pragma unroll
      for (int m = 0; m < 2; ++m) {
        const int row = w * 32 + m * 16 + lr;
        const int ce  = (kk * 32 + lk * 8) ^ ((row & 7) << 3);
        af[m] = *(const bf16x8*)(ldsA + row * BK + ce);
      }
#pragma unroll
      for (int n = 0; n < 4; ++n) {
        const int row = n * 16 + lr;
        const int ce  = (kk * 32 + lk * 8) ^ ((row & 7) << 3);
        bfr[n] = *(const bf16x8*)(ldsB + row * BK + ce);
      }
#pragma unroll
      for (int m = 0; m < 2; ++m)
#pragma unroll
        for (int n = 0; n < 4; ++n)
          acc[m][n] = MFMA16(af[m], bfr[n], acc[m][n]);
    }
    __syncthreads();
  }

#pragma unroll
  for (int m = 0; m < 2; ++m) {
    const int rowtop = rowbase + w * 32 + m * 16 + lk * 4;
#pragma unroll
    for (int n = 0; n < 4; ++n) {
      const int c0 = colbase + n * 16; // frag base col
      const int h  = c0 / 96;
      const int d0 = c0 - h * 96;
      const size_t qb_ = ((size_t)h * S_LEN + rowtop) * QHD + d0 + lr;
      if (d0 < ND) {
#pragma unroll
        for (int i = 0; i < 4; ++i)
          qfull[qb_ + (size_t)i * QHD] = __float2bfloat16(acc[m][n][i] * scale);
      } else if (d0 == ND) { // rope-lo: out = x0*c - x1*s, x1 = acc[m][n+1]
#pragma unroll
        for (int i = 0; i < 4; ++i) {
          const float c = ropc[(rowtop + i) * 16 + lr];
          const float s = rops[(rowtop + i) * 16 + lr];
          const float x0 = acc[m][n][i], x1 = acc[m][n + 1][i];
          qfull[qb_ + (size_t)i * QHD] = __float2bfloat16((x0 * c - x1 * s) * scale);
        }
      } else { // d0 == 80, rope-hi: out = x1*c + x0*s, x0 = acc[m][n-1]
#pragma unroll
        for (int i = 0; i < 4; ++i) {
          const float c = ropc[(rowtop + i) * 16 + lr];
          const float s = rops[(rowtop + i) * 16 + lr];
          const float x1 = acc[m][n][i], x0 = acc[m][n - 1][i];
          qfull[qb_ + (size_t)i * QHD] = __float2bfloat16((x1 * c + x0 * s) * scale);
        }
      }
    }
  }
}

// kvb GEMM writing k_nope into kfull[h][s][0:64] (stride 96) and vt [NH][64][S].
__global__ __launch_bounds__(256) void gemm_kvb_split(const bf16* __restrict__ A,
                                                      const bf16* __restrict__ B,
                                                      bf16* __restrict__ kfull,
                                                      bf16* __restrict__ vt) {
  constexpr int BM = 128, BN = 128, BK = 64, K = KVL;
  __shared__ __bf16 ldsA[BM * BK];
  __shared__ __bf16 ldsB[BN * BK];
  const int t = threadIdx.x;
  const int l = t & 63, w = t >> 6;
  const int lr = l & 15, lk = l >> 4;
  const int wr = w >> 1, wc = w & 1;
  const int rowbase = blockIdx.y * BM;
  const int h = blockIdx.x; // head == col tile
  const int colbase = h * BN;

  f32x4 acc[4][4];
#pragma unroll
  for (int m = 0; m < 4; ++m)
#pragma unroll
    for (int n = 0; n < 4; ++n) acc[m][n] = f32x4{0.f, 0.f, 0.f, 0.f};

  for (int kt = 0; kt < K / BK; ++kt) {
    const int kb = kt * BK;
#pragma unroll
    for (int it = 0; it < 4; ++it) {
      const int r  = it * 32 + w * 8 + (l >> 3);
      const int c8 = ((l & 7) * 8) ^ ((r & 7) << 3);
      const bf16* ga = A + (size_t)(rowbase + r) * K + kb + c8;
      __builtin_amdgcn_global_load_lds((const __attribute__((address_space(1))) void*)ga,
          (__attribute__((address_space(3))) void*)(ldsA + it * 2048 + w * 512), 16, 0, 0);
      const bf16* gb = B + (size_t)(colbase + r) * K + kb + c8;
      __builtin_amdgcn_global_load_lds((const __attribute__((address_space(1))) void*)gb,
          (__attribute__((address_space(3))) void*)(ldsB + it * 2048 + w * 512), 16, 0, 0);
    }
    __syncthreads();
#pragma unroll
    for (int kk = 0; kk < 2; ++kk) {
      bf16x8 af[4], bfr[4];
#pragma unroll
      for (int m = 0; m < 4; ++m) {
        const int row = wr * 64 + m * 16 + lr;
        const int ce  = (kk * 32 + lk * 8) ^ ((row & 7) << 3);
        af[m] = *(const bf16x8*)(ldsA + row * BK + ce);
      }
#pragma unroll
      for (int n = 0; n < 4; ++n) {
        const int row = wc * 64 + n * 16 + lr;
        const int ce  = (kk * 32 + lk * 8) ^ ((row & 7) << 3);
        bfr[n] = *(const bf16x8*)(ldsB + row * BK + ce);
      }
#pragma unroll
      for (int m = 0; m < 4; ++m)
#pragma unroll
        for (int n = 0; n < 4; ++n)
          acc[m][n] = MFMA16(af[m], bfr[n], acc[m][n]);
    }
    __syncthreads();
  }

#pragma unroll
  for (int m = 0; m < 4; ++m) {
    const int rowtop = rowbase + wr * 64 + m * 16 + lk * 4;
    if (wc == 0) { // k_nope -> kfull[h][s][0:64] (stride QHD)
#pragma unroll
      for (int n = 0; n < 4; ++n) {
        const int d = n * 16 + lr;
#pragma unroll
        for (int i = 0; i < 4; ++i)
          kfull[((size_t)h * S_LEN + rowtop + i) * QHD + d] = __float2bfloat16(acc[m][n][i]);
      }
    } else {        // V -> vt[h][64][S] (8B transposed stores, L2 merges)
#pragma unroll
      for (int n = 0; n < 4; ++n) {
        const int d = n * 16 + lr;
        bf16x4 pk;
#pragma unroll
        for (int i = 0; i < 4; ++i) pk[i] = (__bf16)acc[m][n][i];
        *(bf16x4*)(vt + ((size_t)h * VD + d) * S_LEN + rowtop) = pk;
      }
    }
  }
}

// ---------------- norms / prep ----------------

__global__ void rmsnorm_rows(const float* __restrict__ in, const float* __restrict__ w,
                             bf16* __restrict__ out, int C) {
  const int r = blockIdx.x;
  const float* row = in + (size_t)r * C;
  float ss = 0.f;
  for (int c = threadIdx.x; c < C; c += 256) { float v = row[c]; ss += v * v; }
#pragma unroll
  for (int d = 32; d > 0; d >>= 1) ss += __shfl_xor(ss, d);
  __shared__ float red[4];
  if ((threadIdx.x & 63) == 0) red[threadIdx.x >> 6] = ss;
  __syncthreads();
  const float tot = red[0] + red[1] + red[2] + red[3];
  const float rs = rsqrtf(tot / (float)C + 1e-6f);
  for (int c = threadIdx.x; c < C; c += 256)
    out[(size_t)r * C + c] = __float2bfloat16(row[c] * rs * w[c]);
}

// per row: rmsnorm(ckv[0:256]) -> bf16 ; rope(k_pe) broadcast into
// kfull[h][s][64:96] for ALL heads (via LDS); rope tables for the q path.
__global__ void kv_prep(const float* __restrict__ ckv, const float* __restrict__ w,
                        const int* __restrict__ pos, bf16* __restrict__ ckv_bf,
                        bf16* __restrict__ kfull, float* __restrict__ ropc,
                        float* __restrict__ rops) {
  const int s = blockIdx.x, t = threadIdx.x; // 64 threads
  __shared__ bf16 pe_lds[32];
  const float* row = ckv + (size_t)s * CKV_N;
  float v[4]; float ss = 0.f;
#pragma unroll
  for (int j = 0; j < 4; ++j) { v[j] = row[t + 64 * j]; ss += v[j] * v[j]; }
#pragma unroll
  for (int d = 32; d > 0; d >>= 1) ss += __shfl_xor(ss, d);
  const float rs = rsqrtf(ss / (float)KVL + 1e-6f);
#pragma unroll
  for (int j = 0; j < 4; ++j)
    ckv_bf[(size_t)s * KVL + t + 64 * j] = __float2bfloat16(v[j] * rs * w[t + 64 * j]);
  if (t < 16) {
    const float x0 = row[KVL + t], x1 = row[KVL + 16 + t];
    const float p = (float)get_pos(pos, s);
    const float invf = exp2f(-(float)t * (13.2877124f / 16.f)); // 10000^(-t/16)
    const float ang = p * invf, c = cosf(ang), sn = sinf(ang);
    ropc[s * 16 + t] = c;
    rops[s * 16 + t] = sn;
    pe_lds[t]      = __float2bfloat16(x0 * c - x1 * sn);
    pe_lds[16 + t] = __float2bfloat16(x1 * c + x0 * sn);
  }
  __syncthreads();
  // broadcast pe into every head's kfull row (coalesced 64B per 32-lane group)
  for (int idx = t; idx < NH * 32; idx += 64) {
    const int h = idx >> 5, d = idx & 31;
    kfull[((size_t)h * S_LEN + s) * QHD + ND + d] = pe_lds[d];
  }
}

// ---------------- causal flash attention ----------------
// One wave per block, 32 q rows, KVBLK=64, SWAPPED QK^T (st = mfma(K,Q)),
// log2-domain softmax, shuffle-free steady state (lane-local defer gate +
// lane-partial l), XOR-swizzled P tile.
// V PREFETCH AT LOOP TOP: the 8 V-frag loads for the CURRENT tile are issued
// before the QK MFMAs, so their L2/L3 latency hides under QK+softmax instead
// of stalling the PV MFMAs (K is prefetched one tile ahead as before).
// Grid (NH, 64), q-tiles REVERSED (LPT).
__global__ __launch_bounds__(64) void attn_kernel(const bf16* __restrict__ qfull,
                                                  const bf16* __restrict__ kfull,
                                                  const bf16* __restrict__ vt,
                                                  bf16* __restrict__ ctx) {
  const int h = blockIdx.x;
  const int qw = ((int)gridDim.y - 1 - (int)blockIdx.y) * 32;
  const int l = threadIdx.x;
  const int lr = l & 15, lk = l >> 4;
  const bf16* Q  = qfull + (size_t)h * S_LEN * QHD;
  const bf16* Kf = kfull + (size_t)h * S_LEN * QHD;
  const bf16* V  = vt + (size_t)h * VD * S_LEN;
  __shared__ __bf16 plds[32][64]; // XOR-swizzled: col ^= (lr&7)<<3

  bf16x8 qf[2][3];
#pragma unroll
  for (int qg = 0; qg < 2; ++qg)
#pragma unroll
    for (int ks = 0; ks < 3; ++ks)
      qf[qg][ks] = *(const bf16x8*)(Q + (size_t)(qw + qg * 16 + lr) * QHD + ks * 32 + lk * 8);

  f32x4 o[2][4];
  float mrow[2], lrow[2]; // lrow is LANE-PARTIAL
#pragma unroll
  for (int qg = 0; qg < 2; ++qg) {
#pragma unroll
    for (int dt = 0; dt < 4; ++dt) o[qg][dt] = f32x4{0.f, 0.f, 0.f, 0.f};
    mrow[qg] = -1e30f; lrow[qg] = 0.f;
  }

  // preload K tile 0
  bf16x8 kf[4][3];
#pragma unroll
  for (int sub = 0; sub < 4; ++sub)
#pragma unroll
    for (int ks = 0; ks < 3; ++ks)
      kf[sub][ks] = *(const bf16x8*)(Kf + (size_t)(sub * 16 + lr) * QHD + ks * 32 + lk * 8);

  for (int kb = 0;; kb += 64) {
    // issue CURRENT tile's V loads first (consumed at PV, ~600cy later)
    bf16x8 vfr[2][4];
#pragma unroll
    for (int h2 = 0; h2 < 2; ++h2)
#pragma unroll
      for (int dt = 0; dt < 4; ++dt)
        vfr[h2][dt] = *(const bf16x8*)(V + (size_t)(dt * 16 + lr) * S_LEN + kb + h2 * 32 + lk * 8);

    // S^T tile: st[qg][sub][i] = S[q = qw+qg*16+lr][k = kb+sub*16+lk*4+i]
    f32x4 st[2][4];
#pragma unroll
    for (int qg = 0; qg < 2; ++qg)
#pragma unroll
      for (int sub = 0; sub < 4; ++sub) st[qg][sub] = f32x4{0.f, 0.f, 0.f, 0.f};
    __builtin_amdgcn_s_setprio(1);
#pragma unroll
    for (int qg = 0; qg < 2; ++qg)
#pragma unroll
      for (int sub = 0; sub < 4; ++sub)
#pragma unroll
        for (int ks = 0; ks < 3; ++ks)
          st[qg][sub] = MFMA16(kf[sub][ks], qf[qg][ks], st[qg][sub]);
    __builtin_amdgcn_s_setprio(0);

    // prefetch next K tile (hidden under softmax+PV)
    const int nkb = kb + 64;
    if (nkb <= qw) {
#pragma unroll
      for (int sub = 0; sub < 4; ++sub)
#pragma unroll
        for (int ks = 0; ks < 3; ++ks)
          kf[sub][ks] = *(const bf16x8*)(Kf + (size_t)(nkb + sub * 16 + lr) * QHD + ks * 32 + lk * 8);
    }

    const bool diag = (kb + 64 > qw);
    float lmax[2];
#pragma unroll
    for (int qg = 0; qg < 2; ++qg) {
      const int q = qw + qg * 16 + lr;
      if (diag) {
#pragma unroll
        for (int sub = 0; sub < 4; ++sub)
#pragma unroll
          for (int i = 0; i < 4; ++i)
            if (kb + sub * 16 + lk * 4 + i > q) st[qg][sub][i] = -1e30f;
      }
      float m0 = -1e30f;
#pragma unroll
      for (int sub = 0; sub < 4; ++sub)
#pragma unroll
        for (int i = 0; i < 4; ++i) m0 = fmaxf(m0, st[qg][sub][i]);
      lmax[qg] = m0; // lane-local max (NOT reduced)
    }

    // defer-rescale gate on lane-local maxima (== global-max check via __all)
    const bool noresc = __all((lmax[0] <= mrow[0] + 8.f) && (lmax[1] <= mrow[1] + 8.f));
    float mnew[2], fac[2];
    if (noresc) {
      mnew[0] = mrow[0]; mnew[1] = mrow[1];
    } else { // rare path: full cross-lane reduce + rescale factors
#pragma unroll
      for (int qg = 0; qg < 2; ++qg) {
        float t0 = lmax[qg];
        t0 = fmaxf(t0, __shfl_xor(t0, 16));
        t0 = fmaxf(t0, __shfl_xor(t0, 32));
        mnew[qg] = fmaxf(mrow[qg], t0);
        fac[qg] = exp2f(mrow[qg] - mnew[qg]);
        mrow[qg] = mnew[qg];
      }
    }

#pragma unroll
    for (int qg = 0; qg < 2; ++qg) {
      float ts = 0.f;
#pragma unroll
      for (int sub = 0; sub < 4; ++sub) {
        bf16x4 pk;
#pragma unroll
        for (int i = 0; i < 4; ++i) {
          const float p = exp2f(st[qg][sub][i] - mnew[qg]);
          ts += p;
          pk[i] = (__bf16)p;
        }
        const int swc = (sub * 16 + lk * 4) ^ ((lr & 7) << 3);
        *(bf16x4*)(&plds[qg * 16 + lr][swc]) = pk;
      }
      if (noresc) lrow[qg] += ts;
      else        lrow[qg] = lrow[qg] * fac[qg] + ts;
    }
    if (!noresc) {
#pragma unroll
      for (int qg = 0; qg < 2; ++qg)
#pragma unroll
        for (int i = 0; i < 4; ++i) {
          const float fr = __shfl(fac[qg], lk * 4 + i);
#pragma unroll
          for (int dt = 0; dt < 4; ++dt) o[qg][dt][i] *= fr;
        }
    }

    // PV: A = P from LDS (swizzled read), B = prefetched V frags
#pragma unroll
    for (int h2 = 0; h2 < 2; ++h2) {
      const int swc = (h2 * 32 + lk * 8) ^ ((lr & 7) << 3);
      bf16x8 pa0 = *(const bf16x8*)(&plds[lr][swc]);
      bf16x8 pa1 = *(const bf16x8*)(&plds[16 + lr][swc]);
      __builtin_amdgcn_s_setprio(1);
#pragma unroll
      for (int dt = 0; dt < 4; ++dt) {
        o[0][dt] = MFMA16(pa0, vfr[h2][dt], o[0][dt]);
        o[1][dt] = MFMA16(pa1, vfr[h2][dt], o[1][dt]);
      }
      __builtin_amdgcn_s_setprio(0);
    }
    if (nkb > qw) break;
  }

  // epilogue: reduce lane-partial l (once), broadcast 1/l to o-row owners
#pragma unroll
  for (int qg = 0; qg < 2; ++qg) {
    float ls = lrow[qg];
    ls += __shfl_xor(ls, 16);
    ls += __shfl_xor(ls, 32);
    const float linv = 1.0f / ls;
#pragma unroll
    for (int i = 0; i < 4; ++i) {
      const float inv = __shfl(linv, lk * 4 + i);
#pragma unroll
      for (int dt = 0; dt < 4; ++dt) {
        const int row = qw + qg * 16 + lk * 4 + i;
        const int col = h * VD + dt * 16 + lr;
        ctx[(size_t)row * HID + col] = __float2bfloat16(o[qg][dt][i] * inv);
      }
    }
  }
}

// ---------------- launch ----------------

extern "C" void kernel_launch(void* const* d_in, const int* in_sizes, int n_in,
                              void* d_out, int out_size, void* d_ws, size_t ws_size,
                              hipStream_t stream) {
  const float* hidden = (const float*)d_in[0];
  const int*   pos    = (const int*)d_in[1];
  const float* w_qa   = (const float*)d_in[2];
  const float* q_ln   = (const float*)d_in[3];
  const float* w_qb   = (const float*)d_in[4];
  const float* w_kva  = (const float*)d_in[5];
  const float* kv_ln  = (const float*)d_in[6];
  const float* w_kvb  = (const float*)d_in[7];
  const float* w_o    = (const float*)d_in[8];
  float* out = (float*)d_out;
  char* ws = (char*)d_ws;
  (void)in_sizes; (void)n_in; (void)out_size; (void)ws_size;

  size_t off = 0;
  auto take = [&](size_t bytes) -> char* {
    char* p = ws + off;
    off = (off + bytes + 255) & ~(size_t)255;
    return p;
  };
  bf16*  hid_bf = (bf16*)take((size_t)S_LEN * HID * 2);
  bf16*  wabT   = (bf16*)take((size_t)AB_N * HID * 2);   // wqaT | wkvaT
  bf16*  wqbT   = (bf16*)take((size_t)QB_N * QL * 2);
  bf16*  wkvbT  = (bf16*)take((size_t)KVB_N * KVL * 2);
  bf16*  woT    = (bf16*)take((size_t)HID * HID * 2);
  float* qlora  = (float*)take((size_t)S_LEN * QL * 4);
  bf16*  qa_bf  = (bf16*)take((size_t)S_LEN * QL * 2);
  bf16*  qfull  = (bf16*)take((size_t)NH * S_LEN * QHD * 2);
  float* ckv    = (float*)take((size_t)S_LEN * CKV_N * 4);
  bf16*  ckv_bf = (bf16*)take((size_t)S_LEN * KVL * 2);
  float* ropc   = (float*)take((size_t)S_LEN * 16 * 4);
  float* rops   = (float*)take((size_t)S_LEN * 16 * 4);
  bf16*  kfull  = (bf16*)take((size_t)NH * S_LEN * QHD * 2);
  bf16*  vt     = (bf16*)take((size_t)NH * VD * S_LEN * 2);
  bf16*  ctx    = (bf16*)take((size_t)S_LEN * HID * 2);

  const dim3 tb(32, 8);
  cast_f32_bf16<<<(S_LEN * HID / 4 + 255) / 256, 256, 0, stream>>>(hidden, hid_bf, S_LEN * HID / 4);
  transpose_cast<<<dim3((QL + 31) / 32, (HID + 31) / 32), tb, 0, stream>>>(w_qa, wabT, HID, QL);
  transpose_cast<<<dim3((CKV_N + 31) / 32, (HID + 31) / 32), tb, 0, stream>>>(w_kva, wabT + (size_t)QL * HID, HID, CKV_N);
  transpose_cast<<<dim3((QB_N + 31) / 32, (QL + 31) / 32), tb, 0, stream>>>(w_qb, wqbT, QL, QB_N);
  transpose_cast<<<dim3((KVB_N + 31) / 32, (KVL + 31) / 32), tb, 0, stream>>>(w_kvb, wkvbT, KVL, KVB_N);
  transpose_cast<<<dim3((HID + 31) / 32, (HID + 31) / 32), tb, 0, stream>>>(w_o, woT, HID, HID);

  // fused qa|kva GEMM (544 blocks)
  gemm_qakva<<<dim3((AB_N + 63) / 64, S_LEN / 64), 256, 0, stream>>>(hid_bf, wabT, qlora, ckv);

  // kv prep (rmsnorm, rope tables, k_pe broadcast into kfull)
  kv_prep<<<S_LEN, 64, 0, stream>>>(ckv, kv_ln, pos, ckv_bf, kfull, ropc, rops);

  // q path: rmsnorm -> qb GEMM with fused rope -> qfull (960 blocks)
  rmsnorm_rows<<<S_LEN, 256, 0, stream>>>(qlora, q_ln, qa_bf, QL);
  gemm_qb_rope<<<dim3(QB_N / 64, S_LEN / 128), 256, 0, stream>>>(qa_bf, wqbT, ropc, rops, qfull);

  // kv path: kvb GEMM writes k_nope into kfull + vt transposed
  gemm_kvb_split<<<dim3(KVB_N / 128, S_LEN / 128), 256, 0, stream>>>(ckv_bf, wkvbT, kfull, vt);

  // attention + output proj
  attn_kernel<<<dim3(NH, S_LEN / 32), 64, 0, stream>>>(qfull, kfull, vt, ctx);
  gemm_out64<<<dim3(HID / 64, S_LEN / 128), 256, 0, stream>>>(ctx, woT, out);
}